// Round 2
// baseline (2549.331 us; speedup 1.0000x reference)
//
#include <hip/hip_runtime.h>
#include <math.h>

constexpr int B_ = 32;
constexpr int N_ = 1024;
constexpr int D_ = 64;
constexpr int BCH = 8;   // batch chunk: 2*BCH*N^2*4B = 64 MB of workspace

__device__ __forceinline__ float sigf(float v) {
    return 1.0f / (1.0f + __expf(-v));
}

// ---------------------------------------------------------------- k_dots
// e1f/e2f/e1g/e2g[b,n] = xr[b,n,:] . w ; sa[n] = sigmoid(alpha[n])
__global__ void k_dots(const float* __restrict__ x,
                       const float* __restrict__ fw1, const float* __restrict__ fw2,
                       const float* __restrict__ gw1, const float* __restrict__ gw2,
                       const float* __restrict__ alpha,
                       float* __restrict__ e1f, float* __restrict__ e2f,
                       float* __restrict__ e1g, float* __restrict__ e2g,
                       float* __restrict__ sa)
{
    int t = blockIdx.x * blockDim.x + threadIdx.x;
    if (t < N_) sa[t] = sigf(alpha[t]);
    if (t >= B_ * N_) return;
    const float* xr = x + (size_t)t * D_;
    float s1 = 0.f, s2 = 0.f, s3 = 0.f, s4 = 0.f;
#pragma unroll 8
    for (int d = 0; d < D_; d++) {
        float v = xr[d];
        s1 += v * fw1[d];
        s2 += v * fw2[d];
        s3 += v * gw1[d];
        s4 += v * gw2[d];
    }
    e1f[t] = s1; e2f[t] = s2; e1g[t] = s3; e2g[t] = s4;
}

// ---------------------------------------------------------------- k_what
// What[i,j] = sum_q w[i,q]*clip(d[q],0,1)*w[j,q] - (i==j)
__global__ void k_what(const float* __restrict__ w, const float* __restrict__ dvec,
                       float* __restrict__ What)
{
    int t = blockIdx.x * blockDim.x + threadIdx.x;
    if (t >= D_ * D_) return;
    int i = t / D_, j = t % D_;
    float s = 0.f;
    for (int q = 0; q < D_; q++) {
        float dc = fminf(fmaxf(dvec[q], 0.0f), 1.0f);
        s += w[i * D_ + q] * dc * w[j * D_ + q];
    }
    What[t] = s - (i == j ? 1.0f : 0.0f);
}

// ---------------------------------------------------------------- k_amix
// Amix = cw0*adj0 + cw1*adj1 - (cw0+cw1)*I   (the -I of A_hat folded in)
__global__ void k_amix(const float* __restrict__ adj, const float* __restrict__ cw,
                       float* __restrict__ Amix)
{
    int t = blockIdx.x * blockDim.x + threadIdx.x;
    if (t >= N_ * N_) return;
    int i = t / N_, j = t % N_;
    float c0 = cw[0], c1 = cw[1];
    float v = c0 * adj[t] + c1 * adj[(size_t)N_ * N_ + t];
    if (i == j) v -= (c0 + c1);
    Amix[t] = v;
}

// ---------------------------------------------------------------- k_gemm_big
// ebuf[bc,i,k] = sum_j vs[i,j] * sigmoid(e1[bc,j]*e2[bc,k] + bs[j,k])
// 128x128 tile per block, 8x8 micro-tile per thread (2x2 of 4x4).
// e1/e2 pointers are pre-offset to the chunk; ebuf is chunk-local.
__launch_bounds__(256, 2)
__global__ void k_gemm_big(const float* __restrict__ vs, const float* __restrict__ bs,
                           const float* __restrict__ e1, const float* __restrict__ e2,
                           float* __restrict__ ebuf)
{
    int b = blockIdx.y;          // chunk-local batch index
    int i0 = (blockIdx.x >> 3) * 128;
    int k0 = (blockIdx.x & 7) * 128;
    int t = threadIdx.x;
    int tx = t & 15, ty = t >> 4;

    __shared__ __align__(16) float e1_l[N_];
    __shared__ __align__(16) float e2_l[128];
    __shared__ __align__(16) float vs_l[8][132];
    __shared__ __align__(16) float S_l[8][132];

#pragma unroll
    for (int p = 0; p < 4; p++) e1_l[t + p * 256] = e1[b * N_ + t + p * 256];
    if (t < 128) e2_l[t] = e2[b * N_ + k0 + t];
    __syncthreads();

    float acc[2][2][4][4] = {};
    const int ii_st = t >> 1;
    const int jq_st = (t & 1) * 4;
    const int kt4 = (t & 31) * 4;
    const int jr = t >> 5;
    float e2r[4] = {e2_l[kt4], e2_l[kt4 + 1], e2_l[kt4 + 2], e2_l[kt4 + 3]};

    for (int j0 = 0; j0 < N_; j0 += 8) {
        // stage vs^T tile: vs_l[jj][ii] = vs[i0+ii][j0+jj]
        float4 v = *(const float4*)(vs + (size_t)(i0 + ii_st) * N_ + j0 + jq_st);
        vs_l[jq_st + 0][ii_st] = v.x; vs_l[jq_st + 1][ii_st] = v.y;
        vs_l[jq_st + 2][ii_st] = v.z; vs_l[jq_st + 3][ii_st] = v.w;
        // stage S tile: S_l[jr][kk] = sigmoid(e1[j0+jr]*e2[k0+kk] + bs[j0+jr][k0+kk])
        float4 bsv = *(const float4*)(bs + (size_t)(j0 + jr) * N_ + k0 + kt4);
        float a = e1_l[j0 + jr];
        float4 s;
        s.x = sigf(fmaf(a, e2r[0], bsv.x));
        s.y = sigf(fmaf(a, e2r[1], bsv.y));
        s.z = sigf(fmaf(a, e2r[2], bsv.z));
        s.w = sigf(fmaf(a, e2r[3], bsv.w));
        *(float4*)&S_l[jr][kt4] = s;
        __syncthreads();
#pragma unroll
        for (int jj = 0; jj < 8; jj++) {
            float4 a0 = *(const float4*)&vs_l[jj][ty * 4];
            float4 a1 = *(const float4*)&vs_l[jj][64 + ty * 4];
            float4 b0 = *(const float4*)&S_l[jj][tx * 4];
            float4 b1 = *(const float4*)&S_l[jj][64 + tx * 4];
            float av[8] = {a0.x, a0.y, a0.z, a0.w, a1.x, a1.y, a1.z, a1.w};
            float bv[8] = {b0.x, b0.y, b0.z, b0.w, b1.x, b1.y, b1.z, b1.w};
#pragma unroll
            for (int ri = 0; ri < 2; ri++)
#pragma unroll
                for (int ci = 0; ci < 2; ci++)
#pragma unroll
                    for (int r = 0; r < 4; r++)
#pragma unroll
                        for (int c = 0; c < 4; c++)
                            acc[ri][ci][r][c] += av[ri * 4 + r] * bv[ci * 4 + c];
        }
        __syncthreads();
    }
#pragma unroll
    for (int ri = 0; ri < 2; ri++)
#pragma unroll
        for (int r = 0; r < 4; r++) {
            int i = i0 + ri * 64 + ty * 4 + r;
            float* rowp = ebuf + ((size_t)b * N_ + i) * N_ + k0;
            float4 o0 = {acc[ri][0][r][0], acc[ri][0][r][1], acc[ri][0][r][2], acc[ri][0][r][3]};
            float4 o1 = {acc[ri][1][r][0], acc[ri][1][r][1], acc[ri][1][r][2], acc[ri][1][r][3]};
            *(float4*)(rowp + tx * 4) = o0;
            *(float4*)(rowp + 64 + tx * 4) = o1;
        }
}

// ---------------------------------------------------------------- softmax (in place, one block per row)
__global__ void k_softmax(float* __restrict__ e)
{
    size_t row = blockIdx.x;
    float* p = e + row * N_;
    int t = threadIdx.x;
    float4 v = ((const float4*)p)[t];
    float m = fmaxf(fmaxf(v.x, v.y), fmaxf(v.z, v.w));
#pragma unroll
    for (int o = 32; o > 0; o >>= 1) m = fmaxf(m, __shfl_xor(m, o, 64));
    __shared__ float redm[4], reds[4];
    if ((t & 63) == 0) redm[t >> 6] = m;
    __syncthreads();
    m = fmaxf(fmaxf(redm[0], redm[1]), fmaxf(redm[2], redm[3]));
    float ex[4] = {__expf(v.x - m), __expf(v.y - m), __expf(v.z - m), __expf(v.w - m)};
    float s = ex[0] + ex[1] + ex[2] + ex[3];
#pragma unroll
    for (int o = 32; o > 0; o >>= 1) s += __shfl_xor(s, o, 64);
    if ((t & 63) == 0) reds[t >> 6] = s;
    __syncthreads();
    s = reds[0] + reds[1] + reds[2] + reds[3];
    float inv = 1.0f / s;
    float4 o4 = {ex[0] * inv, ex[1] * inv, ex[2] * inv, ex[3] * inv};
    ((float4*)p)[t] = o4;
}

// softmax of eg row, then divide by (ef + 1e-5), in place over eg
__global__ void k_softmax_div(float* __restrict__ eg, const float* __restrict__ ef)
{
    size_t row = blockIdx.x;
    float* p = eg + row * N_;
    int t = threadIdx.x;
    float4 v = ((const float4*)p)[t];
    float m = fmaxf(fmaxf(v.x, v.y), fmaxf(v.z, v.w));
#pragma unroll
    for (int o = 32; o > 0; o >>= 1) m = fmaxf(m, __shfl_xor(m, o, 64));
    __shared__ float redm[4], reds[4];
    if ((t & 63) == 0) redm[t >> 6] = m;
    __syncthreads();
    m = fmaxf(fmaxf(redm[0], redm[1]), fmaxf(redm[2], redm[3]));
    float ex[4] = {__expf(v.x - m), __expf(v.y - m), __expf(v.z - m), __expf(v.w - m)};
    float s = ex[0] + ex[1] + ex[2] + ex[3];
#pragma unroll
    for (int o = 32; o > 0; o >>= 1) s += __shfl_xor(s, o, 64);
    if ((t & 63) == 0) reds[t >> 6] = s;
    __syncthreads();
    s = reds[0] + reds[1] + reds[2] + reds[3];
    float inv = 1.0f / s;
    float4 f4 = ((const float4*)(ef + row * N_))[t];
    float4 o4;
    o4.x = ex[0] * inv / (f4.x + 1e-5f);
    o4.y = ex[1] * inv / (f4.y + 1e-5f);
    o4.z = ex[2] * inv / (f4.z + 1e-5f);
    o4.w = ex[3] * inv / (f4.w + 1e-5f);
    ((float4*)p)[t] = o4;
}

// ---------------------------------------------------------------- k_out_f
// out[bc,i,d] = tanh( ((E + Amix - I) @ x)[i,d] + cb + (x@What)[i,d] + x0*sa[i] )
// E is chunk-local; x/x0/out pointers pre-offset to the chunk.
__launch_bounds__(256)
__global__ void k_out_f(const float* __restrict__ E, const float* __restrict__ Amix,
                        const float* __restrict__ x, const float* __restrict__ x0,
                        const float* __restrict__ What, const float* __restrict__ sa,
                        const float* __restrict__ cb, float* __restrict__ outp)
{
    int bc = blockIdx.y;
    int i0 = blockIdx.x * 64;
    int t = threadIdx.x;
    int tx = t & 15, ty = t >> 4;
    __shared__ __align__(16) float M_l[64][68];
    __shared__ __align__(16) float X_l[64][68];
    float acc[4][4] = {};
    for (int j0 = 0; j0 < N_; j0 += 64) {
#pragma unroll
        for (int p = 0; p < 4; p++) {
            int ii = (t >> 4) + p * 16;
            int jq = (t & 15) * 4;
            float4 ev = *(const float4*)(E + ((size_t)bc * N_ + i0 + ii) * N_ + j0 + jq);
            float4 av = *(const float4*)(Amix + (size_t)(i0 + ii) * N_ + j0 + jq);
            int di = (i0 + ii) - (j0 + jq);
            M_l[jq + 0][ii] = ev.x + av.x - (di == 0 ? 1.0f : 0.0f);
            M_l[jq + 1][ii] = ev.y + av.y - (di == 1 ? 1.0f : 0.0f);
            M_l[jq + 2][ii] = ev.z + av.z - (di == 2 ? 1.0f : 0.0f);
            M_l[jq + 3][ii] = ev.w + av.w - (di == 3 ? 1.0f : 0.0f);
            int jj = ii;
            *(float4*)&X_l[jj][jq] =
                *(const float4*)(x + ((size_t)bc * N_ + j0 + jj) * D_ + jq);
        }
        __syncthreads();
#pragma unroll
        for (int jj = 0; jj < 64; jj++) {
            float4 a4 = *(const float4*)&M_l[jj][ty * 4];
            float4 b4 = *(const float4*)&X_l[jj][tx * 4];
            float av[4] = {a4.x, a4.y, a4.z, a4.w};
            float bv[4] = {b4.x, b4.y, b4.z, b4.w};
#pragma unroll
            for (int r = 0; r < 4; r++)
#pragma unroll
                for (int c = 0; c < 4; c++) acc[r][c] += av[r] * bv[c];
        }
        __syncthreads();
    }
    // epilogue: restage What and the i-rows of x for the x@What term
#pragma unroll
    for (int p = 0; p < 4; p++) {
        int q = (t >> 4) + p * 16;
        int dq = (t & 15) * 4;
        *(float4*)&M_l[q][dq] = *(const float4*)(What + q * D_ + dq);
        *(float4*)&X_l[q][dq] =
            *(const float4*)(x + ((size_t)bc * N_ + i0 + q) * D_ + dq);
    }
    __syncthreads();
    float acc2[4][4] = {};
#pragma unroll
    for (int q = 0; q < 64; q++) {
        float4 wv = *(const float4*)&M_l[q][tx * 4];
        float wa[4] = {wv.x, wv.y, wv.z, wv.w};
#pragma unroll
        for (int r = 0; r < 4; r++) {
            float a = X_l[ty * 4 + r][q];
#pragma unroll
            for (int c = 0; c < 4; c++) acc2[r][c] += a * wa[c];
        }
    }
    float cbv = cb[0];
#pragma unroll
    for (int r = 0; r < 4; r++) {
        int i = i0 + ty * 4 + r;
        float sai = sa[i];
        size_t base = ((size_t)bc * N_ + i) * D_ + tx * 4;
        float4 x0v = *(const float4*)(x0 + base);
        float x0a[4] = {x0v.x, x0v.y, x0v.z, x0v.w};
        float4 o4;
        o4.x = tanhf(acc[r][0] + acc2[r][0] + cbv + x0a[0] * sai);
        o4.y = tanhf(acc[r][1] + acc2[r][1] + cbv + x0a[1] * sai);
        o4.z = tanhf(acc[r][2] + acc2[r][2] + cbv + x0a[2] * sai);
        o4.w = tanhf(acc[r][3] + acc2[r][3] + cbv + x0a[3] * sai);
        *(float4*)(outp + base) = o4;
    }
}

// ---------------------------------------------------------------- k_out_g
// out[bc,i,d] = tanh( sum_j M[bc,i,j]*x[bc,j,d] )
__launch_bounds__(256)
__global__ void k_out_g(const float* __restrict__ M, const float* __restrict__ x,
                        float* __restrict__ outp)
{
    int bc = blockIdx.y;
    int i0 = blockIdx.x * 64;
    int t = threadIdx.x;
    int tx = t & 15, ty = t >> 4;
    __shared__ __align__(16) float M_l[64][68];
    __shared__ __align__(16) float X_l[64][68];
    float acc[4][4] = {};
    for (int j0 = 0; j0 < N_; j0 += 64) {
#pragma unroll
        for (int p = 0; p < 4; p++) {
            int ii = (t >> 4) + p * 16;
            int jq = (t & 15) * 4;
            float4 v = *(const float4*)(M + ((size_t)bc * N_ + i0 + ii) * N_ + j0 + jq);
            M_l[jq + 0][ii] = v.x; M_l[jq + 1][ii] = v.y;
            M_l[jq + 2][ii] = v.z; M_l[jq + 3][ii] = v.w;
            int jj = ii;
            *(float4*)&X_l[jj][jq] =
                *(const float4*)(x + ((size_t)bc * N_ + j0 + jj) * D_ + jq);
        }
        __syncthreads();
#pragma unroll
        for (int jj = 0; jj < 64; jj++) {
            float4 a4 = *(const float4*)&M_l[jj][ty * 4];
            float4 b4 = *(const float4*)&X_l[jj][tx * 4];
            float av[4] = {a4.x, a4.y, a4.z, a4.w};
            float bv[4] = {b4.x, b4.y, b4.z, b4.w};
#pragma unroll
            for (int r = 0; r < 4; r++)
#pragma unroll
                for (int c = 0; c < 4; c++) acc[r][c] += av[r] * bv[c];
        }
        __syncthreads();
    }
#pragma unroll
    for (int r = 0; r < 4; r++) {
        int i = i0 + ty * 4 + r;
        size_t base = ((size_t)bc * N_ + i) * D_ + tx * 4;
        float4 o4;
        o4.x = tanhf(acc[r][0]);
        o4.y = tanhf(acc[r][1]);
        o4.z = tanhf(acc[r][2]);
        o4.w = tanhf(acc[r][3]);
        *(float4*)(outp + base) = o4;
    }
}

// ---------------------------------------------------------------- host
extern "C" void kernel_launch(void* const* d_in, const int* in_sizes, int n_in,
                              void* d_out, int out_size, void* d_ws, size_t ws_size,
                              hipStream_t stream)
{
    const float* x     = (const float*)d_in[0];
    const float* x0    = (const float*)d_in[1];
    const float* w     = (const float*)d_in[2];
    const float* dvec  = (const float*)d_in[3];
    const float* alpha = (const float*)d_in[4];
    const float* fw1   = (const float*)d_in[5];
    const float* fw2   = (const float*)d_in[6];
    const float* fvs   = (const float*)d_in[7];
    const float* fbs   = (const float*)d_in[8];
    const float* gw1   = (const float*)d_in[9];
    const float* gw2   = (const float*)d_in[10];
    const float* gvs   = (const float*)d_in[11];
    const float* gbs   = (const float*)d_in[12];
    const float* cw    = (const float*)d_in[13];
    const float* cb    = (const float*)d_in[14];
    const float* adj   = (const float*)d_in[15];

    float* outf = (float*)d_out;
    float* outg = outf + (size_t)B_ * N_ * D_;

    // workspace layout (floats): total ~17.96M floats = 71.9 MB
    float* W    = (float*)d_ws;
    float* e1f  = W;
    float* e2f  = e1f + B_ * N_;
    float* e1g  = e2f + B_ * N_;
    float* e2g  = e1g + B_ * N_;
    float* sa   = e2g + B_ * N_;
    float* What = sa + N_;
    float* Amix = What + D_ * D_;
    float* ebf  = Amix + (size_t)N_ * N_;             // BCH * N * N
    float* ebg  = ebf + (size_t)BCH * N_ * N_;        // BCH * N * N
    (void)ws_size; (void)in_sizes; (void)n_in; (void)out_size;

    k_dots<<<dim3((B_ * N_) / 256), 256, 0, stream>>>(x, fw1, fw2, gw1, gw2, alpha,
                                                      e1f, e2f, e1g, e2g, sa);
    k_what<<<dim3(16), 256, 0, stream>>>(w, dvec, What);
    k_amix<<<dim3(N_ * N_ / 256), 256, 0, stream>>>(adj, cw, Amix);

    for (int c = 0; c < B_ / BCH; c++) {
        int boff = c * BCH;
        const float* xc  = x  + (size_t)boff * N_ * D_;
        const float* x0c = x0 + (size_t)boff * N_ * D_;
        k_gemm_big<<<dim3(64, BCH), 256, 0, stream>>>(fvs, fbs, e1f + boff * N_,
                                                      e2f + boff * N_, ebf);
        k_softmax<<<dim3(BCH * N_), 256, 0, stream>>>(ebf);
        k_gemm_big<<<dim3(64, BCH), 256, 0, stream>>>(gvs, gbs, e1g + boff * N_,
                                                      e2g + boff * N_, ebg);
        k_softmax_div<<<dim3(BCH * N_), 256, 0, stream>>>(ebg, ebf);
        k_out_f<<<dim3(16, BCH), 256, 0, stream>>>(ebf, Amix, xc, x0c, What, sa, cb,
                                                   outf + (size_t)boff * N_ * D_);
        k_out_g<<<dim3(16, BCH), 256, 0, stream>>>(ebg, xc,
                                                   outg + (size_t)boff * N_ * D_);
    }
}

// Round 3
// 1905.766 us; speedup vs baseline: 1.3377x; 1.3377x over previous
//
#include <hip/hip_runtime.h>
#include <math.h>

constexpr int B_ = 32;
constexpr int N_ = 1024;
constexpr int D_ = 64;
constexpr int BCH = 4;   // batch chunk (keeps workspace ~63 MB)

typedef short short8 __attribute__((ext_vector_type(8)));   // 8 bf16 (4 VGPRs)
typedef float f32x4 __attribute__((ext_vector_type(4)));    // MFMA accumulator

__device__ __forceinline__ float sigf(float v) {
    return 1.0f / (1.0f + __expf(-v));
}
__device__ __forceinline__ unsigned short f2b(float f) {   // fp32 -> bf16 RNE
    unsigned u = __float_as_uint(f);
    unsigned r = u + 0x7fffu + ((u >> 16) & 1u);
    return (unsigned short)(r >> 16);
}
__device__ __forceinline__ float b2f(unsigned short h) {
    return __uint_as_float(((unsigned)h) << 16);
}

#define GLD16(gp, lp)                                                        \
    __builtin_amdgcn_global_load_lds(                                        \
        (const __attribute__((address_space(1))) unsigned int*)(const void*)(gp), \
        (__attribute__((address_space(3))) unsigned int*)(void*)(lp), 16, 0, 0)

// ---------------------------------------------------------------- k_dots
__global__ void k_dots(const float* __restrict__ x,
                       const float* __restrict__ fw1, const float* __restrict__ fw2,
                       const float* __restrict__ gw1, const float* __restrict__ gw2,
                       const float* __restrict__ alpha,
                       float* __restrict__ e1f, float* __restrict__ e2f,
                       float* __restrict__ e1g, float* __restrict__ e2g,
                       float* __restrict__ sa)
{
    int t = blockIdx.x * blockDim.x + threadIdx.x;
    if (t < N_) sa[t] = sigf(alpha[t]);
    if (t >= B_ * N_) return;
    const float* xr = x + (size_t)t * D_;
    float s1 = 0.f, s2 = 0.f, s3 = 0.f, s4 = 0.f;
#pragma unroll 8
    for (int d = 0; d < D_; d++) {
        float v = xr[d];
        s1 += v * fw1[d];
        s2 += v * fw2[d];
        s3 += v * gw1[d];
        s4 += v * gw2[d];
    }
    e1f[t] = s1; e2f[t] = s2; e1g[t] = s3; e2g[t] = s4;
}

// ---------------------------------------------------------------- k_what
__global__ void k_what(const float* __restrict__ w, const float* __restrict__ dvec,
                       float* __restrict__ What)
{
    int t = blockIdx.x * blockDim.x + threadIdx.x;
    if (t >= D_ * D_) return;
    int i = t / D_, j = t % D_;
    float s = 0.f;
    for (int q = 0; q < D_; q++) {
        float dc = fminf(fmaxf(dvec[q], 0.0f), 1.0f);
        s += w[i * D_ + q] * dc * w[j * D_ + q];
    }
    What[t] = s - (i == j ? 1.0f : 0.0f);
}

// ---------------------------------------------------------------- k_amix
__global__ void k_amix(const float* __restrict__ adj, const float* __restrict__ cw,
                       float* __restrict__ Amix)
{
    int t = blockIdx.x * blockDim.x + threadIdx.x;
    if (t >= N_ * N_) return;
    int i = t / N_, j = t % N_;
    float c0 = cw[0], c1 = cw[1];
    float v = c0 * adj[t] + c1 * adj[(size_t)N_ * N_ + t];
    if (i == j) v -= (c0 + c1);
    Amix[t] = v;
}

// ---------------------------------------------------------------- k_asplit
// fp32 N x N matrix -> hi/lo bf16 buffers (row-major, same layout)
__global__ void k_asplit(const float* __restrict__ src,
                         unsigned short* __restrict__ hi, unsigned short* __restrict__ lo)
{
    int t = blockIdx.x * blockDim.x + threadIdx.x;     // N*N/4 threads
    size_t idx = (size_t)t * 4;
    float4 v = *(const float4*)(src + idx);
    float a[4] = {v.x, v.y, v.z, v.w};
    unsigned h[2], l[2];
    unsigned short hs[4], ls[4];
#pragma unroll
    for (int e = 0; e < 4; e++) {
        hs[e] = f2b(a[e]);
        ls[e] = f2b(a[e] - b2f(hs[e]));
    }
    h[0] = (unsigned)hs[0] | ((unsigned)hs[1] << 16);
    h[1] = (unsigned)hs[2] | ((unsigned)hs[3] << 16);
    l[0] = (unsigned)ls[0] | ((unsigned)ls[1] << 16);
    l[1] = (unsigned)ls[2] | ((unsigned)ls[3] << 16);
    *(uint2*)(hi + idx) = make_uint2(h[0], h[1]);
    *(uint2*)(lo + idx) = make_uint2(l[0], l[1]);
}

// ---------------------------------------------------------------- k_sigsplit_T
// SH/SL[b][k][j] = hi/lo bf16 of sigmoid(e1[j]*e2[k] + bs[j][k])   (transposed!)
// grid (16 j-tiles, 16 k-tiles, BCH), 256 threads. e1/e2 pre-offset to chunk.
__launch_bounds__(256)
__global__ void k_sigsplit_T(const float* __restrict__ bs,
                             const float* __restrict__ e1, const float* __restrict__ e2,
                             unsigned short* __restrict__ SH, unsigned short* __restrict__ SL)
{
    int j0 = blockIdx.x * 64;
    int k0 = blockIdx.y * 64;
    int b  = blockIdx.z;
    int t  = threadIdx.x;
    __shared__ float S_l[64][65];

    // phase 1: coalesced read of bs rows, compute sigmoid into LDS [j][k]
    {
        int j  = t >> 2;
        int kc = (t & 3) * 16;
        float e1v = e1[(size_t)b * N_ + j0 + j];
#pragma unroll
        for (int q = 0; q < 4; q++) {
            float4 bsv = *(const float4*)(bs + (size_t)(j0 + j) * N_ + k0 + kc + q * 4);
            float4 e2v = *(const float4*)(e2 + (size_t)b * N_ + k0 + kc + q * 4);
            S_l[j][kc + q * 4 + 0] = sigf(fmaf(e1v, e2v.x, bsv.x));
            S_l[j][kc + q * 4 + 1] = sigf(fmaf(e1v, e2v.y, bsv.y));
            S_l[j][kc + q * 4 + 2] = sigf(fmaf(e1v, e2v.z, bsv.z));
            S_l[j][kc + q * 4 + 3] = sigf(fmaf(e1v, e2v.w, bsv.w));
        }
    }
    __syncthreads();
    // phase 2: read transposed, split hi/lo, coalesced store of S^T rows
    {
        int k  = t >> 2;
        int jc = (t & 3) * 16;
        unsigned short hs[16], ls[16];
#pragma unroll
        for (int u = 0; u < 16; u++) {
            float v = S_l[jc + u][k];
            hs[u] = f2b(v);
            ls[u] = f2b(v - b2f(hs[u]));
        }
        uint4 hv0, hv1, lv0, lv1;
        hv0.x = hs[0] | (hs[1] << 16);  hv0.y = hs[2] | (hs[3] << 16);
        hv0.z = hs[4] | (hs[5] << 16);  hv0.w = hs[6] | (hs[7] << 16);
        hv1.x = hs[8] | (hs[9] << 16);  hv1.y = hs[10] | (hs[11] << 16);
        hv1.z = hs[12] | (hs[13] << 16); hv1.w = hs[14] | (hs[15] << 16);
        lv0.x = ls[0] | (ls[1] << 16);  lv0.y = ls[2] | (ls[3] << 16);
        lv0.z = ls[4] | (ls[5] << 16);  lv0.w = ls[6] | (ls[7] << 16);
        lv1.x = ls[8] | (ls[9] << 16);  lv1.y = ls[10] | (ls[11] << 16);
        lv1.z = ls[12] | (ls[13] << 16); lv1.w = ls[14] | (ls[15] << 16);
        size_t base = ((size_t)b * N_ + k0 + k) * N_ + j0 + jc;
        *(uint4*)(SH + base) = hv0;  *(uint4*)(SH + base + 8) = hv1;
        *(uint4*)(SL + base) = lv0;  *(uint4*)(SL + base + 8) = lv1;
    }
}

// ---------------------------------------------------------------- k_gemm_mfma
// C[b][i][k] = sum_j A[i][j] * S[j][k],  A = AH+AL (bf16 split), S^T = SH+SL.
// 3-term split: AH*SH + AH*SL + AL*SH.  128x128 tile, BK=64, 4 waves.
// MFMA 16x16x32 bf16, verified layouts: A[m=lane&15][k=quad*8+j],
// B[k=quad*8+j][n=lane&15], C/D col=lane&15 row=quad*4+reg.
__launch_bounds__(256, 1)
__global__ void k_gemm_mfma(const unsigned short* __restrict__ AH,
                            const unsigned short* __restrict__ AL,
                            const unsigned short* __restrict__ SH,
                            const unsigned short* __restrict__ SL,
                            float* __restrict__ ebuf)
{
    const int b  = blockIdx.y;
    const int i0 = (blockIdx.x >> 3) * 128;
    const int k0 = (blockIdx.x & 7) * 128;
    const int t    = threadIdx.x;
    const int lane = t & 63;
    const int wave = t >> 6;
    const int wr   = wave >> 1;          // wave row (0..1) -> 64-row strip
    const int wc   = wave & 1;           // wave col (0..1) -> 64-col strip
    const int quad = lane >> 4;
    const int l7   = lane & 7;
    const int m16  = lane & 15;

    // 4 tiles of 128 rows x 64 bf16 (128B rows, XOR-swizzled 16B chunks) = 64 KB
    __shared__ unsigned short lds[4 * 8192];
    unsigned short* AHl = lds;
    unsigned short* ALl = lds + 8192;
    unsigned short* BHl = lds + 16384;
    unsigned short* BLl = lds + 24576;

    // each wave DMA-stages one tile
    const unsigned short* gsrc;
    unsigned short* ldst;
    int rowbase;
    if (wave == 0)      { gsrc = AH; ldst = AHl; rowbase = i0; }
    else if (wave == 1) { gsrc = AL; ldst = ALl; rowbase = i0; }
    else if (wave == 2) { gsrc = SH; ldst = BHl; rowbase = b * N_ + k0; }
    else                { gsrc = SL; ldst = BLl; rowbase = b * N_ + k0; }

    f32x4 acc[4][4];
#pragma unroll
    for (int mi = 0; mi < 4; mi++)
#pragma unroll
        for (int ni = 0; ni < 4; ni++)
            acc[mi][ni] = (f32x4){0.f, 0.f, 0.f, 0.f};

    const int r_sub = lane >> 3;                 // 0..7
    const int gc    = l7 ^ (r_sub & 7);          // swizzled source chunk

    for (int step = 0; step < 16; step++) {
        const int jb = step * 64;
        __syncthreads();   // previous compute done before overwrite
        // stage this wave's tile: 16 issues x 64 lanes x 16B = 16 KB
#pragma unroll
        for (int i = 0; i < 16; i++) {
            int r = i * 8 + r_sub;
            const unsigned short* gp = gsrc + (size_t)(rowbase + r) * N_ + jb + gc * 8;
            GLD16(gp, ldst + i * 512);
        }
        __syncthreads();   // vmcnt(0) drain: staged data visible

#pragma unroll
        for (int s = 0; s < 2; s++) {
            short8 ah[4], al[4], bh[4], bl[4];
            const int ch = ((s << 2) + quad) ^ l7;   // swizzled chunk to read
#pragma unroll
            for (int mi = 0; mi < 4; mi++) {
                int row = wr * 64 + mi * 16 + m16;
                int off = row * 64 + ch * 8;
                ah[mi] = *(const short8*)(AHl + off);
                al[mi] = *(const short8*)(ALl + off);
            }
#pragma unroll
            for (int ni = 0; ni < 4; ni++) {
                int row = wc * 64 + ni * 16 + m16;
                int off = row * 64 + ch * 8;
                bh[ni] = *(const short8*)(BHl + off);
                bl[ni] = *(const short8*)(BLl + off);
            }
#pragma unroll
            for (int mi = 0; mi < 4; mi++)
#pragma unroll
                for (int ni = 0; ni < 4; ni++)
                    acc[mi][ni] = __builtin_amdgcn_mfma_f32_16x16x32_bf16(
                        ah[mi], bh[ni], acc[mi][ni], 0, 0, 0);
#pragma unroll
            for (int mi = 0; mi < 4; mi++)
#pragma unroll
                for (int ni = 0; ni < 4; ni++)
                    acc[mi][ni] = __builtin_amdgcn_mfma_f32_16x16x32_bf16(
                        ah[mi], bl[ni], acc[mi][ni], 0, 0, 0);
#pragma unroll
            for (int mi = 0; mi < 4; mi++)
#pragma unroll
                for (int ni = 0; ni < 4; ni++)
                    acc[mi][ni] = __builtin_amdgcn_mfma_f32_16x16x32_bf16(
                        al[mi], bh[ni], acc[mi][ni], 0, 0, 0);
        }
    }

    // epilogue: C/D layout col=lane&15, row=quad*4+reg
#pragma unroll
    for (int mi = 0; mi < 4; mi++)
#pragma unroll
        for (int ni = 0; ni < 4; ni++) {
            int row = i0 + wr * 64 + mi * 16 + quad * 4;
            int col = k0 + wc * 64 + ni * 16 + m16;
            float* p = ebuf + ((size_t)b * N_ + row) * N_ + col;
#pragma unroll
            for (int r = 0; r < 4; r++)
                p[(size_t)r * N_] = acc[mi][ni][r];
        }
}

// ---------------------------------------------------------------- softmax
__global__ void k_softmax(float* __restrict__ e)
{
    size_t row = blockIdx.x;
    float* p = e + row * N_;
    int t = threadIdx.x;
    float4 v = ((const float4*)p)[t];
    float m = fmaxf(fmaxf(v.x, v.y), fmaxf(v.z, v.w));
#pragma unroll
    for (int o = 32; o > 0; o >>= 1) m = fmaxf(m, __shfl_xor(m, o, 64));
    __shared__ float redm[4], reds[4];
    if ((t & 63) == 0) redm[t >> 6] = m;
    __syncthreads();
    m = fmaxf(fmaxf(redm[0], redm[1]), fmaxf(redm[2], redm[3]));
    float ex[4] = {__expf(v.x - m), __expf(v.y - m), __expf(v.z - m), __expf(v.w - m)};
    float s = ex[0] + ex[1] + ex[2] + ex[3];
#pragma unroll
    for (int o = 32; o > 0; o >>= 1) s += __shfl_xor(s, o, 64);
    if ((t & 63) == 0) reds[t >> 6] = s;
    __syncthreads();
    s = reds[0] + reds[1] + reds[2] + reds[3];
    float inv = 1.0f / s;
    float4 o4 = {ex[0] * inv, ex[1] * inv, ex[2] * inv, ex[3] * inv};
    ((float4*)p)[t] = o4;
}

__global__ void k_softmax_div(float* __restrict__ eg, const float* __restrict__ ef)
{
    size_t row = blockIdx.x;
    float* p = eg + row * N_;
    int t = threadIdx.x;
    float4 v = ((const float4*)p)[t];
    float m = fmaxf(fmaxf(v.x, v.y), fmaxf(v.z, v.w));
#pragma unroll
    for (int o = 32; o > 0; o >>= 1) m = fmaxf(m, __shfl_xor(m, o, 64));
    __shared__ float redm[4], reds[4];
    if ((t & 63) == 0) redm[t >> 6] = m;
    __syncthreads();
    m = fmaxf(fmaxf(redm[0], redm[1]), fmaxf(redm[2], redm[3]));
    float ex[4] = {__expf(v.x - m), __expf(v.y - m), __expf(v.z - m), __expf(v.w - m)};
    float s = ex[0] + ex[1] + ex[2] + ex[3];
#pragma unroll
    for (int o = 32; o > 0; o >>= 1) s += __shfl_xor(s, o, 64);
    if ((t & 63) == 0) reds[t >> 6] = s;
    __syncthreads();
    s = reds[0] + reds[1] + reds[2] + reds[3];
    float inv = 1.0f / s;
    float4 f4 = ((const float4*)(ef + row * N_))[t];
    float4 o4;
    o4.x = ex[0] * inv / (f4.x + 1e-5f);
    o4.y = ex[1] * inv / (f4.y + 1e-5f);
    o4.z = ex[2] * inv / (f4.z + 1e-5f);
    o4.w = ex[3] * inv / (f4.w + 1e-5f);
    ((float4*)p)[t] = o4;
}

// ---------------------------------------------------------------- k_out_f
__launch_bounds__(256)
__global__ void k_out_f(const float* __restrict__ E, const float* __restrict__ Amix,
                        const float* __restrict__ x, const float* __restrict__ x0,
                        const float* __restrict__ What, const float* __restrict__ sa,
                        const float* __restrict__ cb, float* __restrict__ outp)
{
    int bc = blockIdx.y;
    int i0 = blockIdx.x * 64;
    int t = threadIdx.x;
    int tx = t & 15, ty = t >> 4;
    __shared__ __align__(16) float M_l[64][68];
    __shared__ __align__(16) float X_l[64][68];
    float acc[4][4] = {};
    for (int j0 = 0; j0 < N_; j0 += 64) {
#pragma unroll
        for (int p = 0; p < 4; p++) {
            int ii = (t >> 4) + p * 16;
            int jq = (t & 15) * 4;
            float4 ev = *(const float4*)(E + ((size_t)bc * N_ + i0 + ii) * N_ + j0 + jq);
            float4 av = *(const float4*)(Amix + (size_t)(i0 + ii) * N_ + j0 + jq);
            int di = (i0 + ii) - (j0 + jq);
            M_l[jq + 0][ii] = ev.x + av.x - (di == 0 ? 1.0f : 0.0f);
            M_l[jq + 1][ii] = ev.y + av.y - (di == 1 ? 1.0f : 0.0f);
            M_l[jq + 2][ii] = ev.z + av.z - (di == 2 ? 1.0f : 0.0f);
            M_l[jq + 3][ii] = ev.w + av.w - (di == 3 ? 1.0f : 0.0f);
            int jj = ii;
            *(float4*)&X_l[jj][jq] =
                *(const float4*)(x + ((size_t)bc * N_ + j0 + jj) * D_ + jq);
        }
        __syncthreads();
#pragma unroll
        for (int jj = 0; jj < 64; jj++) {
            float4 a4 = *(const float4*)&M_l[jj][ty * 4];
            float4 b4 = *(const float4*)&X_l[jj][tx * 4];
            float av[4] = {a4.x, a4.y, a4.z, a4.w};
            float bv[4] = {b4.x, b4.y, b4.z, b4.w};
#pragma unroll
            for (int r = 0; r < 4; r++)
#pragma unroll
                for (int c = 0; c < 4; c++) acc[r][c] += av[r] * bv[c];
        }
        __syncthreads();
    }
#pragma unroll
    for (int p = 0; p < 4; p++) {
        int q = (t >> 4) + p * 16;
        int dq = (t & 15) * 4;
        *(float4*)&M_l[q][dq] = *(const float4*)(What + q * D_ + dq);
        *(float4*)&X_l[q][dq] =
            *(const float4*)(x + ((size_t)bc * N_ + i0 + q) * D_ + dq);
    }
    __syncthreads();
    float acc2[4][4] = {};
#pragma unroll
    for (int q = 0; q < 64; q++) {
        float4 wv = *(const float4*)&M_l[q][tx * 4];
        float wa[4] = {wv.x, wv.y, wv.z, wv.w};
#pragma unroll
        for (int r = 0; r < 4; r++) {
            float a = X_l[ty * 4 + r][q];
#pragma unroll
            for (int c = 0; c < 4; c++) acc2[r][c] += a * wa[c];
        }
    }
    float cbv = cb[0];
#pragma unroll
    for (int r = 0; r < 4; r++) {
        int i = i0 + ty * 4 + r;
        float sai = sa[i];
        size_t base = ((size_t)bc * N_ + i) * D_ + tx * 4;
        float4 x0v = *(const float4*)(x0 + base);
        float x0a[4] = {x0v.x, x0v.y, x0v.z, x0v.w};
        float4 o4;
        o4.x = tanhf(acc[r][0] + acc2[r][0] + cbv + x0a[0] * sai);
        o4.y = tanhf(acc[r][1] + acc2[r][1] + cbv + x0a[1] * sai);
        o4.z = tanhf(acc[r][2] + acc2[r][2] + cbv + x0a[2] * sai);
        o4.w = tanhf(acc[r][3] + acc2[r][3] + cbv + x0a[3] * sai);
        *(float4*)(outp + base) = o4;
    }
}

// ---------------------------------------------------------------- k_out_g
__launch_bounds__(256)
__global__ void k_out_g(const float* __restrict__ M, const float* __restrict__ x,
                        float* __restrict__ outp)
{
    int bc = blockIdx.y;
    int i0 = blockIdx.x * 64;
    int t = threadIdx.x;
    int tx = t & 15, ty = t >> 4;
    __shared__ __align__(16) float M_l[64][68];
    __shared__ __align__(16) float X_l[64][68];
    float acc[4][4] = {};
    for (int j0 = 0; j0 < N_; j0 += 64) {
#pragma unroll
        for (int p = 0; p < 4; p++) {
            int ii = (t >> 4) + p * 16;
            int jq = (t & 15) * 4;
            float4 v = *(const float4*)(M + ((size_t)bc * N_ + i0 + ii) * N_ + j0 + jq);
            M_l[jq + 0][ii] = v.x; M_l[jq + 1][ii] = v.y;
            M_l[jq + 2][ii] = v.z; M_l[jq + 3][ii] = v.w;
            int jj = ii;
            *(float4*)&X_l[jj][jq] =
                *(const float4*)(x + ((size_t)bc * N_ + j0 + jj) * D_ + jq);
        }
        __syncthreads();
#pragma unroll
        for (int jj = 0; jj < 64; jj++) {
            float4 a4 = *(const float4*)&M_l[jj][ty * 4];
            float4 b4 = *(const float4*)&X_l[jj][tx * 4];
            float av[4] = {a4.x, a4.y, a4.z, a4.w};
            float bv[4] = {b4.x, b4.y, b4.z, b4.w};
#pragma unroll
            for (int r = 0; r < 4; r++)
#pragma unroll
                for (int c = 0; c < 4; c++) acc[r][c] += av[r] * bv[c];
        }
        __syncthreads();
    }
#pragma unroll
    for (int r = 0; r < 4; r++) {
        int i = i0 + ty * 4 + r;
        size_t base = ((size_t)bc * N_ + i) * D_ + tx * 4;
        float4 o4;
        o4.x = tanhf(acc[r][0]);
        o4.y = tanhf(acc[r][1]);
        o4.z = tanhf(acc[r][2]);
        o4.w = tanhf(acc[r][3]);
        *(float4*)(outp + base) = o4;
    }
}

// ---------------------------------------------------------------- host
extern "C" void kernel_launch(void* const* d_in, const int* in_sizes, int n_in,
                              void* d_out, int out_size, void* d_ws, size_t ws_size,
                              hipStream_t stream)
{
    const float* x     = (const float*)d_in[0];
    const float* x0    = (const float*)d_in[1];
    const float* w     = (const float*)d_in[2];
    const float* dvec  = (const float*)d_in[3];
    const float* alpha = (const float*)d_in[4];
    const float* fw1   = (const float*)d_in[5];
    const float* fw2   = (const float*)d_in[6];
    const float* fvs   = (const float*)d_in[7];
    const float* fbs   = (const float*)d_in[8];
    const float* gw1   = (const float*)d_in[9];
    const float* gw2   = (const float*)d_in[10];
    const float* gvs   = (const float*)d_in[11];
    const float* gbs   = (const float*)d_in[12];
    const float* cw    = (const float*)d_in[13];
    const float* cb    = (const float*)d_in[14];
    const float* adj   = (const float*)d_in[15];

    float* outf = (float*)d_out;
    float* outg = outf + (size_t)B_ * N_ * D_;

    // workspace layout: ~15.86M floats = 63.5 MB
    float* W    = (float*)d_ws;
    float* e1f  = W;
    float* e2f  = e1f + B_ * N_;
    float* e1g  = e2f + B_ * N_;
    float* e2g  = e1g + B_ * N_;
    float* sa   = e2g + B_ * N_;
    float* What = sa + N_;
    float* Amix = What + D_ * D_;
    float* pA   = Amix + (size_t)N_ * N_;
    unsigned short* AHf = (unsigned short*)pA;                  // N*N ushort each
    unsigned short* ALf = AHf + (size_t)N_ * N_;
    unsigned short* AHg = ALf + (size_t)N_ * N_;
    unsigned short* ALg = AHg + (size_t)N_ * N_;
    unsigned short* SH  = ALg + (size_t)N_ * N_;                // BCH*N*N ushort
    unsigned short* SL  = SH + (size_t)BCH * N_ * N_;
    float* ebf = (float*)(SL + (size_t)BCH * N_ * N_);          // BCH*N*N floats
    float* ebg = ebf + (size_t)BCH * N_ * N_;
    (void)ws_size; (void)in_sizes; (void)n_in; (void)out_size;

    k_dots<<<dim3((B_ * N_) / 256), 256, 0, stream>>>(x, fw1, fw2, gw1, gw2, alpha,
                                                      e1f, e2f, e1g, e2g, sa);
    k_what<<<dim3(16), 256, 0, stream>>>(w, dvec, What);
    k_amix<<<dim3(N_ * N_ / 256), 256, 0, stream>>>(adj, cw, Amix);
    k_asplit<<<dim3(N_ * N_ / 1024), 256, 0, stream>>>(fvs, AHf, ALf);
    k_asplit<<<dim3(N_ * N_ / 1024), 256, 0, stream>>>(gvs, AHg, ALg);

    for (int c = 0; c < B_ / BCH; c++) {
        int boff = c * BCH;
        const float* xc  = x  + (size_t)boff * N_ * D_;
        const float* x0c = x0 + (size_t)boff * N_ * D_;
        k_sigsplit_T<<<dim3(16, 16, BCH), 256, 0, stream>>>(fbs, e1f + boff * N_,
                                                            e2f + boff * N_, SH, SL);
        k_gemm_mfma<<<dim3(64, BCH), 256, 0, stream>>>(AHf, ALf, SH, SL, ebf);
        k_softmax<<<dim3(BCH * N_), 256, 0, stream>>>(ebf);
        k_sigsplit_T<<<dim3(16, 16, BCH), 256, 0, stream>>>(gbs, e1g + boff * N_,
                                                            e2g + boff * N_, SH, SL);
        k_gemm_mfma<<<dim3(64, BCH), 256, 0, stream>>>(AHg, ALg, SH, SL, ebg);
        k_softmax_div<<<dim3(BCH * N_), 256, 0, stream>>>(ebg, ebf);
        k_out_f<<<dim3(16, BCH), 256, 0, stream>>>(ebf, Amix, xc, x0c, What, sa, cb,
                                                   outf + (size_t)boff * N_ * D_);
        k_out_g<<<dim3(16, BCH), 256, 0, stream>>>(ebg, xc,
                                                   outg + (size_t)boff * N_ * D_);
    }
}

// Round 4
// 1337.688 us; speedup vs baseline: 1.9058x; 1.4247x over previous
//
#include <hip/hip_runtime.h>
#include <math.h>

constexpr int B_ = 32;
constexpr int N_ = 1024;
constexpr int D_ = 64;
constexpr int BCH = 4;   // batch chunk; workspace ~62 MB

typedef short short8 __attribute__((ext_vector_type(8)));   // 8 bf16 (4 VGPRs)
typedef float f32x4 __attribute__((ext_vector_type(4)));    // MFMA accumulator

__device__ __forceinline__ float sigf(float v) {
    return 1.0f / (1.0f + __expf(-v));
}
__device__ __forceinline__ unsigned short f2b(float f) {   // fp32 -> bf16 RNE
    unsigned u = __float_as_uint(f);
    unsigned r = u + 0x7fffu + ((u >> 16) & 1u);
    return (unsigned short)(r >> 16);
}
__device__ __forceinline__ float b2f(unsigned int h) {
    return __uint_as_float(h << 16);
}

#define GLD16(gp, lp)                                                        \
    __builtin_amdgcn_global_load_lds(                                        \
        (const __attribute__((address_space(1))) unsigned int*)(const void*)(gp), \
        (__attribute__((address_space(3))) unsigned int*)(void*)(lp), 16, 0, 0)

// ---------------------------------------------------------------- k_dots
__global__ void k_dots(const float* __restrict__ x,
                       const float* __restrict__ fw1, const float* __restrict__ fw2,
                       const float* __restrict__ gw1, const float* __restrict__ gw2,
                       const float* __restrict__ alpha,
                       float* __restrict__ e1f, float* __restrict__ e2f,
                       float* __restrict__ e1g, float* __restrict__ e2g,
                       float* __restrict__ sa)
{
    int t = blockIdx.x * blockDim.x + threadIdx.x;
    if (t < N_) sa[t] = sigf(alpha[t]);
    if (t >= B_ * N_) return;
    const float* xr = x + (size_t)t * D_;
    float s1 = 0.f, s2 = 0.f, s3 = 0.f, s4 = 0.f;
#pragma unroll 8
    for (int d = 0; d < D_; d++) {
        float v = xr[d];
        s1 += v * fw1[d];
        s2 += v * fw2[d];
        s3 += v * gw1[d];
        s4 += v * gw2[d];
    }
    e1f[t] = s1; e2f[t] = s2; e1g[t] = s3; e2g[t] = s4;
}

// ---------------------------------------------------------------- k_what2_split
// What2 = (w*dc)@w.T - 2I  (folds W_hat's -I and the (E-I) -I), bf16 hi/lo
__global__ void k_what2_split(const float* __restrict__ w, const float* __restrict__ dvec,
                              unsigned short* __restrict__ W2h, unsigned short* __restrict__ W2l)
{
    int t = blockIdx.x * blockDim.x + threadIdx.x;
    if (t >= D_ * D_) return;
    int i = t / D_, j = t % D_;
    float s = 0.f;
    for (int q = 0; q < D_; q++) {
        float dc = fminf(fmaxf(dvec[q], 0.0f), 1.0f);
        s += w[i * D_ + q] * dc * w[j * D_ + q];
    }
    if (i == j) s -= 2.0f;
    unsigned short h = f2b(s);
    W2h[t] = h;
    W2l[t] = f2b(s - b2f(h));
}

// ---------------------------------------------------------------- k_amix_split
__global__ void k_amix_split(const float* __restrict__ adj, const float* __restrict__ cw,
                             unsigned short* __restrict__ AmixH, unsigned short* __restrict__ AmixL)
{
    int t = blockIdx.x * blockDim.x + threadIdx.x;
    if (t >= N_ * N_) return;
    int i = t >> 10, j = t & (N_ - 1);
    float c0 = cw[0], c1 = cw[1];
    float v = c0 * adj[t] + c1 * adj[(size_t)N_ * N_ + t];
    if (i == j) v -= (c0 + c1);
    unsigned short h = f2b(v);
    AmixH[t] = h;
    AmixL[t] = f2b(v - b2f(h));
}

// ---------------------------------------------------------------- k_asplit (vs)
__global__ void k_asplit(const float* __restrict__ src,
                         unsigned short* __restrict__ hi, unsigned short* __restrict__ lo)
{
    int t = blockIdx.x * blockDim.x + threadIdx.x;     // N*N/4 threads
    size_t idx = (size_t)t * 4;
    float4 v = *(const float4*)(src + idx);
    float a[4] = {v.x, v.y, v.z, v.w};
    unsigned short hs[4], ls[4];
#pragma unroll
    for (int e = 0; e < 4; e++) {
        hs[e] = f2b(a[e]);
        ls[e] = f2b(a[e] - b2f(hs[e]));
    }
    uint2 h2, l2;
    h2.x = (unsigned)hs[0] | ((unsigned)hs[1] << 16);
    h2.y = (unsigned)hs[2] | ((unsigned)hs[3] << 16);
    l2.x = (unsigned)ls[0] | ((unsigned)ls[1] << 16);
    l2.y = (unsigned)ls[2] | ((unsigned)ls[3] << 16);
    *(uint2*)(hi + idx) = h2;
    *(uint2*)(lo + idx) = l2;
}

// ---------------------------------------------------------------- k_xt_split
// XTh/XTl[bc][d][j] = bf16 hi/lo of x[bc][j][d]  (transposed, MFMA B-operand)
__launch_bounds__(256)
__global__ void k_xt_split(const float* __restrict__ xc,
                           unsigned short* __restrict__ XTh, unsigned short* __restrict__ XTl)
{
    int j0 = blockIdx.x * 64;
    int bc = blockIdx.y;
    int t  = threadIdx.x;
    __shared__ float S_l[64][65];
    {
        int j = t >> 2, dc = (t & 3) * 16;
        const float* src = xc + ((size_t)bc * N_ + j0 + j) * D_ + dc;
#pragma unroll
        for (int q = 0; q < 4; q++) {
            float4 v = *(const float4*)(src + q * 4);
            S_l[j][dc + q * 4 + 0] = v.x;
            S_l[j][dc + q * 4 + 1] = v.y;
            S_l[j][dc + q * 4 + 2] = v.z;
            S_l[j][dc + q * 4 + 3] = v.w;
        }
    }
    __syncthreads();
    {
        int d = t >> 2, jc = (t & 3) * 16;
        unsigned short hs[16], ls[16];
#pragma unroll
        for (int u = 0; u < 16; u++) {
            float v = S_l[jc + u][d];
            hs[u] = f2b(v);
            ls[u] = f2b(v - b2f(hs[u]));
        }
        uint4 hv0, hv1, lv0, lv1;
        hv0.x = hs[0] | (hs[1] << 16);  hv0.y = hs[2] | (hs[3] << 16);
        hv0.z = hs[4] | (hs[5] << 16);  hv0.w = hs[6] | (hs[7] << 16);
        hv1.x = hs[8] | (hs[9] << 16);  hv1.y = hs[10] | (hs[11] << 16);
        hv1.z = hs[12] | (hs[13] << 16); hv1.w = hs[14] | (hs[15] << 16);
        lv0.x = ls[0] | (ls[1] << 16);  lv0.y = ls[2] | (ls[3] << 16);
        lv0.z = ls[4] | (ls[5] << 16);  lv0.w = ls[6] | (ls[7] << 16);
        lv1.x = ls[8] | (ls[9] << 16);  lv1.y = ls[10] | (ls[11] << 16);
        lv1.z = ls[12] | (ls[13] << 16); lv1.w = ls[14] | (ls[15] << 16);
        size_t base = ((size_t)bc * D_ + d) * N_ + j0 + jc;
        *(uint4*)(XTh + base) = hv0;  *(uint4*)(XTh + base + 8) = hv1;
        *(uint4*)(XTl + base) = lv0;  *(uint4*)(XTl + base + 8) = lv1;
    }
}

// ---------------------------------------------------------------- k_sigsplit_T
__launch_bounds__(256)
__global__ void k_sigsplit_T(const float* __restrict__ bs,
                             const float* __restrict__ e1, const float* __restrict__ e2,
                             unsigned short* __restrict__ SH, unsigned short* __restrict__ SL)
{
    int j0 = blockIdx.x * 64;
    int k0 = blockIdx.y * 64;
    int b  = blockIdx.z;
    int t  = threadIdx.x;
    __shared__ float S_l[64][65];
    {
        int j  = t >> 2;
        int kc = (t & 3) * 16;
        float e1v = e1[(size_t)b * N_ + j0 + j];
#pragma unroll
        for (int q = 0; q < 4; q++) {
            float4 bsv = *(const float4*)(bs + (size_t)(j0 + j) * N_ + k0 + kc + q * 4);
            float4 e2v = *(const float4*)(e2 + (size_t)b * N_ + k0 + kc + q * 4);
            S_l[j][kc + q * 4 + 0] = sigf(fmaf(e1v, e2v.x, bsv.x));
            S_l[j][kc + q * 4 + 1] = sigf(fmaf(e1v, e2v.y, bsv.y));
            S_l[j][kc + q * 4 + 2] = sigf(fmaf(e1v, e2v.z, bsv.z));
            S_l[j][kc + q * 4 + 3] = sigf(fmaf(e1v, e2v.w, bsv.w));
        }
    }
    __syncthreads();
    {
        int k  = t >> 2;
        int jc = (t & 3) * 16;
        unsigned short hs[16], ls[16];
#pragma unroll
        for (int u = 0; u < 16; u++) {
            float v = S_l[jc + u][k];
            hs[u] = f2b(v);
            ls[u] = f2b(v - b2f(hs[u]));
        }
        uint4 hv0, hv1, lv0, lv1;
        hv0.x = hs[0] | (hs[1] << 16);  hv0.y = hs[2] | (hs[3] << 16);
        hv0.z = hs[4] | (hs[5] << 16);  hv0.w = hs[6] | (hs[7] << 16);
        hv1.x = hs[8] | (hs[9] << 16);  hv1.y = hs[10] | (hs[11] << 16);
        hv1.z = hs[12] | (hs[13] << 16); hv1.w = hs[14] | (hs[15] << 16);
        lv0.x = ls[0] | (ls[1] << 16);  lv0.y = ls[2] | (ls[3] << 16);
        lv0.z = ls[4] | (ls[5] << 16);  lv0.w = ls[6] | (ls[7] << 16);
        lv1.x = ls[8] | (ls[9] << 16);  lv1.y = ls[10] | (ls[11] << 16);
        lv1.z = ls[12] | (ls[13] << 16); lv1.w = ls[14] | (ls[15] << 16);
        size_t base = ((size_t)b * N_ + k0 + k) * N_ + j0 + jc;
        *(uint4*)(SH + base) = hv0;  *(uint4*)(SH + base + 8) = hv1;
        *(uint4*)(SL + base) = lv0;  *(uint4*)(SL + base + 8) = lv1;
    }
}

// ---------------------------------------------------------------- k_gemm_mfma
// logits[b][i][k] = sum_j vs[i][j] * S[j][k]; 3-term bf16 split; writes hi/lo bf16.
__launch_bounds__(256, 1)
__global__ void k_gemm_mfma(const unsigned short* __restrict__ AH,
                            const unsigned short* __restrict__ AL,
                            const unsigned short* __restrict__ SH,
                            const unsigned short* __restrict__ SL,
                            unsigned short* __restrict__ LHo,
                            unsigned short* __restrict__ LLo)
{
    const int b  = blockIdx.y;
    const int i0 = (blockIdx.x >> 3) * 128;
    const int k0 = (blockIdx.x & 7) * 128;
    const int t    = threadIdx.x;
    const int lane = t & 63;
    const int wave = t >> 6;
    const int wr   = wave >> 1;
    const int wc   = wave & 1;
    const int quad = lane >> 4;
    const int l7   = lane & 7;
    const int m16  = lane & 15;

    __shared__ unsigned short lds[4 * 8192];
    unsigned short* AHl = lds;
    unsigned short* ALl = lds + 8192;
    unsigned short* BHl = lds + 16384;
    unsigned short* BLl = lds + 24576;

    const unsigned short* gsrc;
    unsigned short* ldst;
    int rowbase;
    if (wave == 0)      { gsrc = AH; ldst = AHl; rowbase = i0; }
    else if (wave == 1) { gsrc = AL; ldst = ALl; rowbase = i0; }
    else if (wave == 2) { gsrc = SH; ldst = BHl; rowbase = b * N_ + k0; }
    else                { gsrc = SL; ldst = BLl; rowbase = b * N_ + k0; }

    f32x4 acc[4][4];
#pragma unroll
    for (int mi = 0; mi < 4; mi++)
#pragma unroll
        for (int ni = 0; ni < 4; ni++)
            acc[mi][ni] = (f32x4){0.f, 0.f, 0.f, 0.f};

    const int r_sub = lane >> 3;
    const int gc    = l7 ^ r_sub;

    for (int step = 0; step < 16; step++) {
        const int jb = step * 64;
        __syncthreads();
#pragma unroll
        for (int i = 0; i < 16; i++) {
            int r = i * 8 + r_sub;
            const unsigned short* gp = gsrc + (size_t)(rowbase + r) * N_ + jb + gc * 8;
            GLD16(gp, ldst + i * 512);
        }
        __syncthreads();

#pragma unroll
        for (int s = 0; s < 2; s++) {
            short8 ah[4], al[4], bh[4], bl[4];
            const int ch = (((s << 2) + quad) ^ l7) * 8;
#pragma unroll
            for (int mi = 0; mi < 4; mi++) {
                int row = wr * 64 + mi * 16 + m16;
                ah[mi] = *(const short8*)(AHl + row * 64 + ch);
                al[mi] = *(const short8*)(ALl + row * 64 + ch);
            }
#pragma unroll
            for (int ni = 0; ni < 4; ni++) {
                int row = wc * 64 + ni * 16 + m16;
                bh[ni] = *(const short8*)(BHl + row * 64 + ch);
                bl[ni] = *(const short8*)(BLl + row * 64 + ch);
            }
#pragma unroll
            for (int mi = 0; mi < 4; mi++)
#pragma unroll
                for (int ni = 0; ni < 4; ni++)
                    acc[mi][ni] = __builtin_amdgcn_mfma_f32_16x16x32_bf16(
                        ah[mi], bh[ni], acc[mi][ni], 0, 0, 0);
#pragma unroll
            for (int mi = 0; mi < 4; mi++)
#pragma unroll
                for (int ni = 0; ni < 4; ni++)
                    acc[mi][ni] = __builtin_amdgcn_mfma_f32_16x16x32_bf16(
                        ah[mi], bl[ni], acc[mi][ni], 0, 0, 0);
#pragma unroll
            for (int mi = 0; mi < 4; mi++)
#pragma unroll
                for (int ni = 0; ni < 4; ni++)
                    acc[mi][ni] = __builtin_amdgcn_mfma_f32_16x16x32_bf16(
                        al[mi], bh[ni], acc[mi][ni], 0, 0, 0);
        }
    }

#pragma unroll
    for (int mi = 0; mi < 4; mi++)
#pragma unroll
        for (int ni = 0; ni < 4; ni++) {
            int row = i0 + wr * 64 + mi * 16 + quad * 4;
            int col = k0 + wc * 64 + ni * 16 + m16;
            size_t base = ((size_t)b * N_ + row) * N_ + col;
#pragma unroll
            for (int r = 0; r < 4; r++) {
                float v = acc[mi][ni][r];
                unsigned short h = f2b(v);
                LHo[base + (size_t)r * N_] = h;
                LLo[base + (size_t)r * N_] = f2b(v - b2f(h));
            }
        }
}

// ---------------------------------------------------------------- k_softmax_bf
// reads logits hi/lo, softmax per row, writes E hi/lo
__global__ void k_softmax_bf(const unsigned short* __restrict__ LH,
                             const unsigned short* __restrict__ LL,
                             unsigned short* __restrict__ EH,
                             unsigned short* __restrict__ EL)
{
    size_t row = blockIdx.x;
    int t = threadIdx.x;
    size_t base = row * N_ + (size_t)t * 4;
    uint2 h2 = *(const uint2*)(LH + base);
    uint2 l2 = *(const uint2*)(LL + base);
    float v[4];
    v[0] = b2f(h2.x & 0xffff) + b2f(l2.x & 0xffff);
    v[1] = b2f(h2.x >> 16)    + b2f(l2.x >> 16);
    v[2] = b2f(h2.y & 0xffff) + b2f(l2.y & 0xffff);
    v[3] = b2f(h2.y >> 16)    + b2f(l2.y >> 16);
    float m = fmaxf(fmaxf(v[0], v[1]), fmaxf(v[2], v[3]));
#pragma unroll
    for (int o = 32; o > 0; o >>= 1) m = fmaxf(m, __shfl_xor(m, o, 64));
    __shared__ float redm[4], reds[4];
    if ((t & 63) == 0) redm[t >> 6] = m;
    __syncthreads();
    m = fmaxf(fmaxf(redm[0], redm[1]), fmaxf(redm[2], redm[3]));
    float ex[4] = {__expf(v[0] - m), __expf(v[1] - m), __expf(v[2] - m), __expf(v[3] - m)};
    float s = ex[0] + ex[1] + ex[2] + ex[3];
#pragma unroll
    for (int o = 32; o > 0; o >>= 1) s += __shfl_xor(s, o, 64);
    if ((t & 63) == 0) reds[t >> 6] = s;
    __syncthreads();
    s = reds[0] + reds[1] + reds[2] + reds[3];
    float inv = 1.0f / s;
    unsigned short hs[4], ls[4];
#pragma unroll
    for (int e = 0; e < 4; e++) {
        float p = ex[e] * inv;
        hs[e] = f2b(p);
        ls[e] = f2b(p - b2f(hs[e]));
    }
    uint2 ho, lo;
    ho.x = (unsigned)hs[0] | ((unsigned)hs[1] << 16);
    ho.y = (unsigned)hs[2] | ((unsigned)hs[3] << 16);
    lo.x = (unsigned)ls[0] | ((unsigned)ls[1] << 16);
    lo.y = (unsigned)ls[2] | ((unsigned)ls[3] << 16);
    *(uint2*)(EH + base) = ho;
    *(uint2*)(EL + base) = lo;
}

// ---------------------------------------------------------------- k_softmax_div_bf
// reads g-logits hi/lo, softmax, divide by (E+1e-5), write N_hat hi/lo IN PLACE
__global__ void k_softmax_div_bf(unsigned short* GH, unsigned short* GL,
                                 const unsigned short* __restrict__ EH,
                                 const unsigned short* __restrict__ EL)
{
    size_t row = blockIdx.x;
    int t = threadIdx.x;
    size_t base = row * N_ + (size_t)t * 4;
    uint2 h2 = *(const uint2*)(GH + base);
    uint2 l2 = *(const uint2*)(GL + base);
    float v[4];
    v[0] = b2f(h2.x & 0xffff) + b2f(l2.x & 0xffff);
    v[1] = b2f(h2.x >> 16)    + b2f(l2.x >> 16);
    v[2] = b2f(h2.y & 0xffff) + b2f(l2.y & 0xffff);
    v[3] = b2f(h2.y >> 16)    + b2f(l2.y >> 16);
    float m = fmaxf(fmaxf(v[0], v[1]), fmaxf(v[2], v[3]));
#pragma unroll
    for (int o = 32; o > 0; o >>= 1) m = fmaxf(m, __shfl_xor(m, o, 64));
    __shared__ float redm[4], reds[4];
    if ((t & 63) == 0) redm[t >> 6] = m;
    __syncthreads();
    m = fmaxf(fmaxf(redm[0], redm[1]), fmaxf(redm[2], redm[3]));
    float ex[4] = {__expf(v[0] - m), __expf(v[1] - m), __expf(v[2] - m), __expf(v[3] - m)};
    float s = ex[0] + ex[1] + ex[2] + ex[3];
#pragma unroll
    for (int o = 32; o > 0; o >>= 1) s += __shfl_xor(s, o, 64);
    if ((t & 63) == 0) reds[t >> 6] = s;
    __syncthreads();
    s = reds[0] + reds[1] + reds[2] + reds[3];
    float inv = 1.0f / s;
    uint2 eh2 = *(const uint2*)(EH + base);
    uint2 el2 = *(const uint2*)(EL + base);
    float Ev[4];
    Ev[0] = b2f(eh2.x & 0xffff) + b2f(el2.x & 0xffff);
    Ev[1] = b2f(eh2.x >> 16)    + b2f(el2.x >> 16);
    Ev[2] = b2f(eh2.y & 0xffff) + b2f(el2.y & 0xffff);
    Ev[3] = b2f(eh2.y >> 16)    + b2f(el2.y >> 16);
    unsigned short hs[4], ls[4];
#pragma unroll
    for (int e = 0; e < 4; e++) {
        float nh = ex[e] * inv / (Ev[e] + 1e-5f);
        hs[e] = f2b(nh);
        ls[e] = f2b(nh - b2f(hs[e]));
    }
    uint2 ho, lo;
    ho.x = (unsigned)hs[0] | ((unsigned)hs[1] << 16);
    ho.y = (unsigned)hs[2] | ((unsigned)hs[3] << 16);
    lo.x = (unsigned)ls[0] | ((unsigned)ls[1] << 16);
    lo.y = (unsigned)ls[2] | ((unsigned)ls[3] << 16);
    *(uint2*)(GH + base) = ho;
    *(uint2*)(GL + base) = lo;
}

// ---------------------------------------------------------------- k_out_mfma
// z=0 (f): out = tanh(E@x + Amix@x + x@What2 + x0*sa + cb)
// z=1 (g): out = tanh(Nhat@x)
// 64 rows x 64 cols per block; 4 waves = 16 rows each; 3-term bf16 split.
__launch_bounds__(256, 2)
__global__ void k_out_mfma(
    const unsigned short* __restrict__ EH, const unsigned short* __restrict__ EL,
    const unsigned short* __restrict__ NH, const unsigned short* __restrict__ NL,
    const unsigned short* __restrict__ AmixH, const unsigned short* __restrict__ AmixL,
    const unsigned short* __restrict__ XTh, const unsigned short* __restrict__ XTl,
    const unsigned short* __restrict__ W2h, const unsigned short* __restrict__ W2l,
    const float* __restrict__ xc, const float* __restrict__ x0c,
    const float* __restrict__ sa, const float* __restrict__ cb,
    float* __restrict__ outf, float* __restrict__ outg)
{
    const int i0    = blockIdx.x * 64;
    const int bc    = blockIdx.y;
    const bool modeF = (blockIdx.z == 0);
    const int t     = threadIdx.x;
    const int lane  = t & 63;
    const int wave  = t >> 6;
    const int quad  = lane >> 4;
    const int m16   = lane & 15;
    const int l7    = lane & 7;
    const int r_sub = lane >> 3;
    const int gc    = l7 ^ r_sub;

    __shared__ __align__(16) unsigned short lds[6 * 4096];   // 48 KB

    const unsigned short* Mh = modeF ? EH : NH;
    const unsigned short* Ml = modeF ? EL : NL;

    const unsigned short* sb[6];
    sb[0] = Mh + ((size_t)bc * N_ + i0) * N_;
    sb[1] = Ml + ((size_t)bc * N_ + i0) * N_;
    sb[2] = XTh + (size_t)bc * D_ * N_;
    sb[3] = XTl + (size_t)bc * D_ * N_;
    sb[4] = AmixH + (size_t)i0 * N_;
    sb[5] = AmixL + (size_t)i0 * N_;

    const int per = modeF ? 12 : 8;   // staging issues per wave (nbuf*8/4)

    f32x4 acc[4];
#pragma unroll
    for (int cg = 0; cg < 4; cg++) acc[cg] = (f32x4){0.f, 0.f, 0.f, 0.f};

    const int rowA = wave * 16 + m16;

    for (int step = 0; step < 16; step++) {
        const int jb = step * 64;
        __syncthreads();
        for (int i = 0; i < per; i++) {
            int gi  = wave * per + i;
            int buf = gi >> 3, rg = gi & 7;
            const unsigned short* gp = sb[buf] + (size_t)(rg * 8 + r_sub) * N_ + jb + gc * 8;
            GLD16(gp, lds + buf * 4096 + rg * 512);
        }
        __syncthreads();
#pragma unroll
        for (int kc = 0; kc < 2; kc++) {
            const int ch = ((kc * 4 + quad) ^ l7) * 8;
            short8 mh = *(const short8*)(lds + rowA * 64 + ch);
            short8 ml = *(const short8*)(lds + 4096 + rowA * 64 + ch);
            short8 bh[4], bl[4];
#pragma unroll
            for (int cg = 0; cg < 4; cg++) {
                int rowB = cg * 16 + m16;
                bh[cg] = *(const short8*)(lds + 2 * 4096 + rowB * 64 + ch);
                bl[cg] = *(const short8*)(lds + 3 * 4096 + rowB * 64 + ch);
            }
#pragma unroll
            for (int cg = 0; cg < 4; cg++) {
                acc[cg] = __builtin_amdgcn_mfma_f32_16x16x32_bf16(mh, bh[cg], acc[cg], 0, 0, 0);
                acc[cg] = __builtin_amdgcn_mfma_f32_16x16x32_bf16(mh, bl[cg], acc[cg], 0, 0, 0);
                acc[cg] = __builtin_amdgcn_mfma_f32_16x16x32_bf16(ml, bh[cg], acc[cg], 0, 0, 0);
            }
            if (modeF) {
                short8 ah = *(const short8*)(lds + 4 * 4096 + rowA * 64 + ch);
                short8 al = *(const short8*)(lds + 5 * 4096 + rowA * 64 + ch);
#pragma unroll
                for (int cg = 0; cg < 4; cg++) {
                    acc[cg] = __builtin_amdgcn_mfma_f32_16x16x32_bf16(ah, bh[cg], acc[cg], 0, 0, 0);
                    acc[cg] = __builtin_amdgcn_mfma_f32_16x16x32_bf16(ah, bl[cg], acc[cg], 0, 0, 0);
                    acc[cg] = __builtin_amdgcn_mfma_f32_16x16x32_bf16(al, bh[cg], acc[cg], 0, 0, 0);
                }
            }
        }
    }

    if (modeF) {
        // phase B: += x_rows @ What2  (one K=64 step; What2 symmetric)
        __syncthreads();
        if (wave < 2) {
            int r  = wave * 32 + (lane >> 1);
            int qh = (lane & 1) * 32;
            const float* xrow = xc + ((size_t)bc * N_ + i0 + r) * D_ + qh;
#pragma unroll
            for (int cc = 0; cc < 4; cc++) {
                float4 v0 = *(const float4*)(xrow + cc * 8);
                float4 v1 = *(const float4*)(xrow + cc * 8 + 4);
                float vv[8] = {v0.x, v0.y, v0.z, v0.w, v1.x, v1.y, v1.z, v1.w};
                short8 hh, ll;
#pragma unroll
                for (int e = 0; e < 8; e++) {
                    unsigned short h = f2b(vv[e]);
                    hh[e] = (short)h;
                    ll[e] = (short)f2b(vv[e] - b2f(h));
                }
                int c   = (qh >> 3) + cc;
                int pos = (c ^ (r & 7)) * 8;
                *(short8*)(lds + r * 64 + pos) = hh;
                *(short8*)(lds + 4096 + r * 64 + pos) = ll;
            }
        } else {
            const unsigned short* gsrc = (wave == 2) ? W2h : W2l;
            unsigned short* ldst = lds + wave * 4096;   // wave2->buf2, wave3->buf3
#pragma unroll
            for (int rg = 0; rg < 8; rg++) {
                const unsigned short* gp = gsrc + (size_t)(rg * 8 + r_sub) * 64 + gc * 8;
                GLD16(gp, ldst + rg * 512);
            }
        }
        __syncthreads();
#pragma unroll
        for (int kc = 0; kc < 2; kc++) {
            const int ch = ((kc * 4 + quad) ^ l7) * 8;
            short8 ah = *(const short8*)(lds + rowA * 64 + ch);
            short8 al = *(const short8*)(lds + 4096 + rowA * 64 + ch);
#pragma unroll
            for (int cg = 0; cg < 4; cg++) {
                int rowB = cg * 16 + m16;
                short8 bh = *(const short8*)(lds + 2 * 4096 + rowB * 64 + ch);
                short8 bl = *(const short8*)(lds + 3 * 4096 + rowB * 64 + ch);
                acc[cg] = __builtin_amdgcn_mfma_f32_16x16x32_bf16(ah, bh, acc[cg], 0, 0, 0);
                acc[cg] = __builtin_amdgcn_mfma_f32_16x16x32_bf16(ah, bl, acc[cg], 0, 0, 0);
                acc[cg] = __builtin_amdgcn_mfma_f32_16x16x32_bf16(al, bh, acc[cg], 0, 0, 0);
            }
        }
    }

    float cbv = modeF ? cb[0] : 0.f;
    float* outp = modeF ? outf : outg;
#pragma unroll
    for (int cg = 0; cg < 4; cg++) {
#pragma unroll
        for (int r = 0; r < 4; r++) {
            int row = i0 + wave * 16 + quad * 4 + r;
            int col = cg * 16 + m16;
            float v = acc[cg][r];
            if (modeF)
                v += x0c[((size_t)bc * N_ + row) * D_ + col] * sa[row] + cbv;
            outp[((size_t)bc * N_ + row) * D_ + col] = tanhf(v);
        }
    }
}

// ---------------------------------------------------------------- host
extern "C" void kernel_launch(void* const* d_in, const int* in_sizes, int n_in,
                              void* d_out, int out_size, void* d_ws, size_t ws_size,
                              hipStream_t stream)
{
    const float* x     = (const float*)d_in[0];
    const float* x0    = (const float*)d_in[1];
    const float* w     = (const float*)d_in[2];
    const float* dvec  = (const float*)d_in[3];
    const float* alpha = (const float*)d_in[4];
    const float* fw1   = (const float*)d_in[5];
    const float* fw2   = (const float*)d_in[6];
    const float* fvs   = (const float*)d_in[7];
    const float* fbs   = (const float*)d_in[8];
    const float* gw1   = (const float*)d_in[9];
    const float* gw2   = (const float*)d_in[10];
    const float* gvs   = (const float*)d_in[11];
    const float* gbs   = (const float*)d_in[12];
    const float* cw    = (const float*)d_in[13];
    const float* cb    = (const float*)d_in[14];
    const float* adj   = (const float*)d_in[15];

    float* outf = (float*)d_out;
    float* outg = outf + (size_t)B_ * N_ * D_;

    char* p = (char*)d_ws;
    auto alloc = [&](size_t bytes) { void* r = p; p += (bytes + 255) & ~(size_t)255; return r; };

    float* e1f = (float*)alloc(B_ * N_ * 4);
    float* e2f = (float*)alloc(B_ * N_ * 4);
    float* e1g = (float*)alloc(B_ * N_ * 4);
    float* e2g = (float*)alloc(B_ * N_ * 4);
    float* sa  = (float*)alloc(N_ * 4);
    unsigned short* W2h = (unsigned short*)alloc(D_ * D_ * 2);
    unsigned short* W2l = (unsigned short*)alloc(D_ * D_ * 2);
    unsigned short* AmixH = (unsigned short*)alloc((size_t)N_ * N_ * 2);
    unsigned short* AmixL = (unsigned short*)alloc((size_t)N_ * N_ * 2);
    unsigned short* AHf = (unsigned short*)alloc((size_t)N_ * N_ * 2);
    unsigned short* ALf = (unsigned short*)alloc((size_t)N_ * N_ * 2);
    unsigned short* AHg = (unsigned short*)alloc((size_t)N_ * N_ * 2);
    unsigned short* ALg = (unsigned short*)alloc((size_t)N_ * N_ * 2);
    unsigned short* XTh = (unsigned short*)alloc((size_t)BCH * D_ * N_ * 2);
    unsigned short* XTl = (unsigned short*)alloc((size_t)BCH * D_ * N_ * 2);
    unsigned short* SH  = (unsigned short*)alloc((size_t)BCH * N_ * N_ * 2);
    unsigned short* SL  = (unsigned short*)alloc((size_t)BCH * N_ * N_ * 2);
    unsigned short* LH  = (unsigned short*)alloc((size_t)BCH * N_ * N_ * 2);
    unsigned short* LL  = (unsigned short*)alloc((size_t)BCH * N_ * N_ * 2);
    unsigned short* EH  = (unsigned short*)alloc((size_t)BCH * N_ * N_ * 2);
    unsigned short* EL  = (unsigned short*)alloc((size_t)BCH * N_ * N_ * 2);
    (void)ws_size; (void)in_sizes; (void)n_in; (void)out_size;

    k_dots<<<dim3((B_ * N_) / 256), 256, 0, stream>>>(x, fw1, fw2, gw1, gw2, alpha,
                                                      e1f, e2f, e1g, e2g, sa);
    k_what2_split<<<dim3(16), 256, 0, stream>>>(w, dvec, W2h, W2l);
    k_amix_split<<<dim3(N_ * N_ / 256), 256, 0, stream>>>(adj, cw, AmixH, AmixL);
    k_asplit<<<dim3(N_ * N_ / 1024), 256, 0, stream>>>(fvs, AHf, ALf);
    k_asplit<<<dim3(N_ * N_ / 1024), 256, 0, stream>>>(gvs, AHg, ALg);

    for (int c = 0; c < B_ / BCH; c++) {
        int boff = c * BCH;
        const float* xc  = x  + (size_t)boff * N_ * D_;
        const float* x0c = x0 + (size_t)boff * N_ * D_;
        k_xt_split<<<dim3(16, BCH), 256, 0, stream>>>(xc, XTh, XTl);
        k_sigsplit_T<<<dim3(16, 16, BCH), 256, 0, stream>>>(fbs, e1f + boff * N_,
                                                            e2f + boff * N_, SH, SL);
        k_gemm_mfma<<<dim3(64, BCH), 256, 0, stream>>>(AHf, ALf, SH, SL, LH, LL);
        k_softmax_bf<<<dim3(BCH * N_), 256, 0, stream>>>(LH, LL, EH, EL);
        k_sigsplit_T<<<dim3(16, 16, BCH), 256, 0, stream>>>(gbs, e1g + boff * N_,
                                                            e2g + boff * N_, SH, SL);
        k_gemm_mfma<<<dim3(64, BCH), 256, 0, stream>>>(AHg, ALg, SH, SL, LH, LL);
        k_softmax_div_bf<<<dim3(BCH * N_), 256, 0, stream>>>(LH, LL, EH, EL);
        k_out_mfma<<<dim3(16, BCH, 2), 256, 0, stream>>>(
            EH, EL, LH, LL, AmixH, AmixL, XTh, XTl, W2h, W2l,
            xc, x0c, sa, cb,
            outf + (size_t)boff * N_ * D_, outg + (size_t)boff * N_ * D_);
    }
}

// Round 5
// 1033.916 us; speedup vs baseline: 2.4657x; 1.2938x over previous
//
#include <hip/hip_runtime.h>
#include <math.h>

constexpr int B_ = 32;
constexpr int N_ = 1024;
constexpr int D_ = 64;
constexpr int BCH = 4;   // batch chunk; workspace ~78 MB

typedef short short8 __attribute__((ext_vector_type(8)));   // 8 bf16 (4 VGPRs)
typedef float f32x4 __attribute__((ext_vector_type(4)));    // MFMA accumulator

__device__ __forceinline__ float sigf(float v) {
    return 1.0f / (1.0f + __expf(-v));
}
__device__ __forceinline__ unsigned short f2b(float f) {   // fp32 -> bf16 RNE
    unsigned u = __float_as_uint(f);
    unsigned r = u + 0x7fffu + ((u >> 16) & 1u);
    return (unsigned short)(r >> 16);
}
__device__ __forceinline__ float b2f(unsigned int h) {
    return __uint_as_float(h << 16);
}

#define GLD16(gp, lp)                                                        \
    __builtin_amdgcn_global_load_lds(                                        \
        (const __attribute__((address_space(1))) unsigned int*)(const void*)(gp), \
        (__attribute__((address_space(3))) unsigned int*)(void*)(lp), 16, 0, 0)

// ---------------------------------------------------------------- k_dots
__global__ void k_dots(const float* __restrict__ x,
                       const float* __restrict__ fw1, const float* __restrict__ fw2,
                       const float* __restrict__ gw1, const float* __restrict__ gw2,
                       const float* __restrict__ alpha,
                       float* __restrict__ e1f, float* __restrict__ e2f,
                       float* __restrict__ e1g, float* __restrict__ e2g,
                       float* __restrict__ sa)
{
    int t = blockIdx.x * blockDim.x + threadIdx.x;
    if (t < N_) sa[t] = sigf(alpha[t]);
    if (t >= B_ * N_) return;
    const float* xr = x + (size_t)t * D_;
    float s1 = 0.f, s2 = 0.f, s3 = 0.f, s4 = 0.f;
#pragma unroll 8
    for (int d = 0; d < D_; d++) {
        float v = xr[d];
        s1 += v * fw1[d];
        s2 += v * fw2[d];
        s3 += v * gw1[d];
        s4 += v * gw2[d];
    }
    e1f[t] = s1; e2f[t] = s2; e1g[t] = s3; e2g[t] = s4;
}

// ---------------------------------------------------------------- k_what2_split
// What2 = (w*dc)@w.T - 2I  (folds W_hat's -I and the (E-I) -I), bf16 hi/lo
__global__ void k_what2_split(const float* __restrict__ w, const float* __restrict__ dvec,
                              unsigned short* __restrict__ W2h, unsigned short* __restrict__ W2l)
{
    int t = blockIdx.x * blockDim.x + threadIdx.x;
    if (t >= D_ * D_) return;
    int i = t / D_, j = t % D_;
    float s = 0.f;
    for (int q = 0; q < D_; q++) {
        float dc = fminf(fmaxf(dvec[q], 0.0f), 1.0f);
        s += w[i * D_ + q] * dc * w[j * D_ + q];
    }
    if (i == j) s -= 2.0f;
    unsigned short h = f2b(s);
    W2h[t] = h;
    W2l[t] = f2b(s - b2f(h));
}

// ---------------------------------------------------------------- k_amix_split
__global__ void k_amix_split(const float* __restrict__ adj, const float* __restrict__ cw,
                             unsigned short* __restrict__ AmixH, unsigned short* __restrict__ AmixL)
{
    int t = blockIdx.x * blockDim.x + threadIdx.x;
    if (t >= N_ * N_) return;
    int i = t >> 10, j = t & (N_ - 1);
    float c0 = cw[0], c1 = cw[1];
    float v = c0 * adj[t] + c1 * adj[(size_t)N_ * N_ + t];
    if (i == j) v -= (c0 + c1);
    unsigned short h = f2b(v);
    AmixH[t] = h;
    AmixL[t] = f2b(v - b2f(h));
}

// ---------------------------------------------------------------- k_asplit (vs)
__global__ void k_asplit(const float* __restrict__ src,
                         unsigned short* __restrict__ hi, unsigned short* __restrict__ lo)
{
    int t = blockIdx.x * blockDim.x + threadIdx.x;     // N*N/4 threads
    size_t idx = (size_t)t * 4;
    float4 v = *(const float4*)(src + idx);
    float a[4] = {v.x, v.y, v.z, v.w};
    unsigned short hs[4], ls[4];
#pragma unroll
    for (int e = 0; e < 4; e++) {
        hs[e] = f2b(a[e]);
        ls[e] = f2b(a[e] - b2f(hs[e]));
    }
    uint2 h2, l2;
    h2.x = (unsigned)hs[0] | ((unsigned)hs[1] << 16);
    h2.y = (unsigned)hs[2] | ((unsigned)hs[3] << 16);
    l2.x = (unsigned)ls[0] | ((unsigned)ls[1] << 16);
    l2.y = (unsigned)ls[2] | ((unsigned)ls[3] << 16);
    *(uint2*)(hi + idx) = h2;
    *(uint2*)(lo + idx) = l2;
}

// ---------------------------------------------------------------- k_xt_split
// XTh/XTl[bc][d][j] = bf16 hi/lo of x[bc][j][d]  (transposed, MFMA B-operand)
__launch_bounds__(256)
__global__ void k_xt_split(const float* __restrict__ xc,
                           unsigned short* __restrict__ XTh, unsigned short* __restrict__ XTl)
{
    int j0 = blockIdx.x * 64;
    int bc = blockIdx.y;
    int t  = threadIdx.x;
    __shared__ float S_l[64][65];
    {
        int j = t >> 2, dc = (t & 3) * 16;
        const float* src = xc + ((size_t)bc * N_ + j0 + j) * D_ + dc;
#pragma unroll
        for (int q = 0; q < 4; q++) {
            float4 v = *(const float4*)(src + q * 4);
            S_l[j][dc + q * 4 + 0] = v.x;
            S_l[j][dc + q * 4 + 1] = v.y;
            S_l[j][dc + q * 4 + 2] = v.z;
            S_l[j][dc + q * 4 + 3] = v.w;
        }
    }
    __syncthreads();
    {
        int d = t >> 2, jc = (t & 3) * 16;
        unsigned short hs[16], ls[16];
#pragma unroll
        for (int u = 0; u < 16; u++) {
            float v = S_l[jc + u][d];
            hs[u] = f2b(v);
            ls[u] = f2b(v - b2f(hs[u]));
        }
        uint4 hv0, hv1, lv0, lv1;
        hv0.x = hs[0] | (hs[1] << 16);  hv0.y = hs[2] | (hs[3] << 16);
        hv0.z = hs[4] | (hs[5] << 16);  hv0.w = hs[6] | (hs[7] << 16);
        hv1.x = hs[8] | (hs[9] << 16);  hv1.y = hs[10] | (hs[11] << 16);
        hv1.z = hs[12] | (hs[13] << 16); hv1.w = hs[14] | (hs[15] << 16);
        lv0.x = ls[0] | (ls[1] << 16);  lv0.y = ls[2] | (ls[3] << 16);
        lv0.z = ls[4] | (ls[5] << 16);  lv0.w = ls[6] | (ls[7] << 16);
        lv1.x = ls[8] | (ls[9] << 16);  lv1.y = ls[10] | (ls[11] << 16);
        lv1.z = ls[12] | (ls[13] << 16); lv1.w = ls[14] | (ls[15] << 16);
        size_t base = ((size_t)bc * D_ + d) * N_ + j0 + jc;
        *(uint4*)(XTh + base) = hv0;  *(uint4*)(XTh + base + 8) = hv1;
        *(uint4*)(XTl + base) = lv0;  *(uint4*)(XTl + base + 8) = lv1;
    }
}

// ---------------------------------------------------------------- k_sigsplit2
// blockIdx.z = b + BCH*fg: computes S^T hi/lo for both f (fg=0) and g (fg=1)
__launch_bounds__(256)
__global__ void k_sigsplit2(const float* __restrict__ fbs, const float* __restrict__ gbs,
                            const float* __restrict__ e1f_, const float* __restrict__ e2f_,
                            const float* __restrict__ e1g_, const float* __restrict__ e2g_,
                            unsigned short* __restrict__ SHf, unsigned short* __restrict__ SLf,
                            unsigned short* __restrict__ SHg, unsigned short* __restrict__ SLg)
{
    int j0 = blockIdx.x * 64;
    int k0 = blockIdx.y * 64;
    int z  = blockIdx.z;
    int b  = z & (BCH - 1);
    int fg = z >> 2;                      // BCH == 4
    const float* bs = fg ? gbs : fbs;
    const float* e1 = fg ? e1g_ : e1f_;
    const float* e2 = fg ? e2g_ : e2f_;
    unsigned short* SH = fg ? SHg : SHf;
    unsigned short* SL = fg ? SLg : SLf;
    int t  = threadIdx.x;
    __shared__ float S_l[64][65];
    {
        int j  = t >> 2;
        int kc = (t & 3) * 16;
        float e1v = e1[(size_t)b * N_ + j0 + j];
#pragma unroll
        for (int q = 0; q < 4; q++) {
            float4 bsv = *(const float4*)(bs + (size_t)(j0 + j) * N_ + k0 + kc + q * 4);
            float4 e2v = *(const float4*)(e2 + (size_t)b * N_ + k0 + kc + q * 4);
            S_l[j][kc + q * 4 + 0] = sigf(fmaf(e1v, e2v.x, bsv.x));
            S_l[j][kc + q * 4 + 1] = sigf(fmaf(e1v, e2v.y, bsv.y));
            S_l[j][kc + q * 4 + 2] = sigf(fmaf(e1v, e2v.z, bsv.z));
            S_l[j][kc + q * 4 + 3] = sigf(fmaf(e1v, e2v.w, bsv.w));
        }
    }
    __syncthreads();
    {
        int k  = t >> 2;
        int jc = (t & 3) * 16;
        unsigned short hs[16], ls[16];
#pragma unroll
        for (int u = 0; u < 16; u++) {
            float v = S_l[jc + u][k];
            hs[u] = f2b(v);
            ls[u] = f2b(v - b2f(hs[u]));
        }
        uint4 hv0, hv1, lv0, lv1;
        hv0.x = hs[0] | (hs[1] << 16);  hv0.y = hs[2] | (hs[3] << 16);
        hv0.z = hs[4] | (hs[5] << 16);  hv0.w = hs[6] | (hs[7] << 16);
        hv1.x = hs[8] | (hs[9] << 16);  hv1.y = hs[10] | (hs[11] << 16);
        hv1.z = hs[12] | (hs[13] << 16); hv1.w = hs[14] | (hs[15] << 16);
        lv0.x = ls[0] | (ls[1] << 16);  lv0.y = ls[2] | (ls[3] << 16);
        lv0.z = ls[4] | (ls[5] << 16);  lv0.w = ls[6] | (ls[7] << 16);
        lv1.x = ls[8] | (ls[9] << 16);  lv1.y = ls[10] | (ls[11] << 16);
        lv1.z = ls[12] | (ls[13] << 16); lv1.w = ls[14] | (ls[15] << 16);
        size_t base = ((size_t)b * N_ + k0 + k) * N_ + j0 + jc;
        *(uint4*)(SH + base) = hv0;  *(uint4*)(SH + base + 8) = hv1;
        *(uint4*)(SL + base) = lv0;  *(uint4*)(SL + base + 8) = lv1;
    }
}

// ---------------------------------------------------------------- k_gemm2
// Merged f+g attention GEMM: blockIdx.z selects the operand/output set.
// 512 blocks -> 2 blocks/CU so one block's MFMA hides the other's barrier drain.
__launch_bounds__(256, 2)
__global__ void k_gemm2(const unsigned short* __restrict__ AHf, const unsigned short* __restrict__ ALf,
                        const unsigned short* __restrict__ AHg, const unsigned short* __restrict__ ALg,
                        const unsigned short* __restrict__ SHf, const unsigned short* __restrict__ SLf,
                        const unsigned short* __restrict__ SHg, const unsigned short* __restrict__ SLg,
                        unsigned short* __restrict__ LHf, unsigned short* __restrict__ LLf,
                        unsigned short* __restrict__ LHg, unsigned short* __restrict__ LLg)
{
    const int fg = blockIdx.z;
    const unsigned short* AH = fg ? AHg : AHf;
    const unsigned short* AL = fg ? ALg : ALf;
    const unsigned short* SH = fg ? SHg : SHf;
    const unsigned short* SL = fg ? SLg : SLf;
    unsigned short* LHo = fg ? LHg : LHf;
    unsigned short* LLo = fg ? LLg : LLf;

    const int b  = blockIdx.y;
    const int i0 = (blockIdx.x >> 3) * 128;
    const int k0 = (blockIdx.x & 7) * 128;
    const int t    = threadIdx.x;
    const int lane = t & 63;
    const int wave = t >> 6;
    const int wr   = wave >> 1;
    const int wc   = wave & 1;
    const int quad = lane >> 4;
    const int l7   = lane & 7;
    const int m16  = lane & 15;

    __shared__ unsigned short lds[4 * 8192];
    unsigned short* AHl = lds;
    unsigned short* ALl = lds + 8192;
    unsigned short* BHl = lds + 16384;
    unsigned short* BLl = lds + 24576;

    const unsigned short* gsrc;
    unsigned short* ldst;
    int rowbase;
    if (wave == 0)      { gsrc = AH; ldst = AHl; rowbase = i0; }
    else if (wave == 1) { gsrc = AL; ldst = ALl; rowbase = i0; }
    else if (wave == 2) { gsrc = SH; ldst = BHl; rowbase = b * N_ + k0; }
    else                { gsrc = SL; ldst = BLl; rowbase = b * N_ + k0; }

    f32x4 acc[4][4];
#pragma unroll
    for (int mi = 0; mi < 4; mi++)
#pragma unroll
        for (int ni = 0; ni < 4; ni++)
            acc[mi][ni] = (f32x4){0.f, 0.f, 0.f, 0.f};

    const int r_sub = lane >> 3;
    const int gc    = l7 ^ r_sub;

    for (int step = 0; step < 16; step++) {
        const int jb = step * 64;
        __syncthreads();
#pragma unroll
        for (int i = 0; i < 16; i++) {
            int r = i * 8 + r_sub;
            const unsigned short* gp = gsrc + (size_t)(rowbase + r) * N_ + jb + gc * 8;
            GLD16(gp, ldst + i * 512);
        }
        __syncthreads();

#pragma unroll
        for (int s = 0; s < 2; s++) {
            short8 ah[4], al[4], bh[4], bl[4];
            const int ch = (((s << 2) + quad) ^ l7) * 8;
#pragma unroll
            for (int mi = 0; mi < 4; mi++) {
                int row = wr * 64 + mi * 16 + m16;
                ah[mi] = *(const short8*)(AHl + row * 64 + ch);
                al[mi] = *(const short8*)(ALl + row * 64 + ch);
            }
#pragma unroll
            for (int ni = 0; ni < 4; ni++) {
                int row = wc * 64 + ni * 16 + m16;
                bh[ni] = *(const short8*)(BHl + row * 64 + ch);
                bl[ni] = *(const short8*)(BLl + row * 64 + ch);
            }
#pragma unroll
            for (int mi = 0; mi < 4; mi++)
#pragma unroll
                for (int ni = 0; ni < 4; ni++)
                    acc[mi][ni] = __builtin_amdgcn_mfma_f32_16x16x32_bf16(
                        ah[mi], bh[ni], acc[mi][ni], 0, 0, 0);
#pragma unroll
            for (int mi = 0; mi < 4; mi++)
#pragma unroll
                for (int ni = 0; ni < 4; ni++)
                    acc[mi][ni] = __builtin_amdgcn_mfma_f32_16x16x32_bf16(
                        ah[mi], bl[ni], acc[mi][ni], 0, 0, 0);
#pragma unroll
            for (int mi = 0; mi < 4; mi++)
#pragma unroll
                for (int ni = 0; ni < 4; ni++)
                    acc[mi][ni] = __builtin_amdgcn_mfma_f32_16x16x32_bf16(
                        al[mi], bh[ni], acc[mi][ni], 0, 0, 0);
        }
    }

#pragma unroll
    for (int mi = 0; mi < 4; mi++)
#pragma unroll
        for (int ni = 0; ni < 4; ni++) {
            int row = i0 + wr * 64 + mi * 16 + quad * 4;
            int col = k0 + wc * 64 + ni * 16 + m16;
            size_t base = ((size_t)b * N_ + row) * N_ + col;
#pragma unroll
            for (int r = 0; r < 4; r++) {
                float v = acc[mi][ni][r];
                unsigned short h = f2b(v);
                LHo[base + (size_t)r * N_] = h;
                LLo[base + (size_t)r * N_] = f2b(v - b2f(h));
            }
        }
}

// ---------------------------------------------------------------- k_softmax_bf
__global__ void k_softmax_bf(const unsigned short* __restrict__ LH,
                             const unsigned short* __restrict__ LL,
                             unsigned short* __restrict__ EH,
                             unsigned short* __restrict__ EL)
{
    size_t row = blockIdx.x;
    int t = threadIdx.x;
    size_t base = row * N_ + (size_t)t * 4;
    uint2 h2 = *(const uint2*)(LH + base);
    uint2 l2 = *(const uint2*)(LL + base);
    float v[4];
    v[0] = b2f(h2.x & 0xffff) + b2f(l2.x & 0xffff);
    v[1] = b2f(h2.x >> 16)    + b2f(l2.x >> 16);
    v[2] = b2f(h2.y & 0xffff) + b2f(l2.y & 0xffff);
    v[3] = b2f(h2.y >> 16)    + b2f(l2.y >> 16);
    float m = fmaxf(fmaxf(v[0], v[1]), fmaxf(v[2], v[3]));
#pragma unroll
    for (int o = 32; o > 0; o >>= 1) m = fmaxf(m, __shfl_xor(m, o, 64));
    __shared__ float redm[4], reds[4];
    if ((t & 63) == 0) redm[t >> 6] = m;
    __syncthreads();
    m = fmaxf(fmaxf(redm[0], redm[1]), fmaxf(redm[2], redm[3]));
    float ex[4] = {__expf(v[0] - m), __expf(v[1] - m), __expf(v[2] - m), __expf(v[3] - m)};
    float s = ex[0] + ex[1] + ex[2] + ex[3];
#pragma unroll
    for (int o = 32; o > 0; o >>= 1) s += __shfl_xor(s, o, 64);
    if ((t & 63) == 0) reds[t >> 6] = s;
    __syncthreads();
    s = reds[0] + reds[1] + reds[2] + reds[3];
    float inv = 1.0f / s;
    unsigned short hs[4], ls[4];
#pragma unroll
    for (int e = 0; e < 4; e++) {
        float p = ex[e] * inv;
        hs[e] = f2b(p);
        ls[e] = f2b(p - b2f(hs[e]));
    }
    uint2 ho, lo;
    ho.x = (unsigned)hs[0] | ((unsigned)hs[1] << 16);
    ho.y = (unsigned)hs[2] | ((unsigned)hs[3] << 16);
    lo.x = (unsigned)ls[0] | ((unsigned)ls[1] << 16);
    lo.y = (unsigned)ls[2] | ((unsigned)ls[3] << 16);
    *(uint2*)(EH + base) = ho;
    *(uint2*)(EL + base) = lo;
}

// ---------------------------------------------------------------- k_softmax_div_bf
__global__ void k_softmax_div_bf(unsigned short* GH, unsigned short* GL,
                                 const unsigned short* __restrict__ EH,
                                 const unsigned short* __restrict__ EL)
{
    size_t row = blockIdx.x;
    int t = threadIdx.x;
    size_t base = row * N_ + (size_t)t * 4;
    uint2 h2 = *(const uint2*)(GH + base);
    uint2 l2 = *(const uint2*)(GL + base);
    float v[4];
    v[0] = b2f(h2.x & 0xffff) + b2f(l2.x & 0xffff);
    v[1] = b2f(h2.x >> 16)    + b2f(l2.x >> 16);
    v[2] = b2f(h2.y & 0xffff) + b2f(l2.y & 0xffff);
    v[3] = b2f(h2.y >> 16)    + b2f(l2.y >> 16);
    float m = fmaxf(fmaxf(v[0], v[1]), fmaxf(v[2], v[3]));
#pragma unroll
    for (int o = 32; o > 0; o >>= 1) m = fmaxf(m, __shfl_xor(m, o, 64));
    __shared__ float redm[4], reds[4];
    if ((t & 63) == 0) redm[t >> 6] = m;
    __syncthreads();
    m = fmaxf(fmaxf(redm[0], redm[1]), fmaxf(redm[2], redm[3]));
    float ex[4] = {__expf(v[0] - m), __expf(v[1] - m), __expf(v[2] - m), __expf(v[3] - m)};
    float s = ex[0] + ex[1] + ex[2] + ex[3];
#pragma unroll
    for (int o = 32; o > 0; o >>= 1) s += __shfl_xor(s, o, 64);
    if ((t & 63) == 0) reds[t >> 6] = s;
    __syncthreads();
    s = reds[0] + reds[1] + reds[2] + reds[3];
    float inv = 1.0f / s;
    uint2 eh2 = *(const uint2*)(EH + base);
    uint2 el2 = *(const uint2*)(EL + base);
    float Ev[4];
    Ev[0] = b2f(eh2.x & 0xffff) + b2f(el2.x & 0xffff);
    Ev[1] = b2f(eh2.x >> 16)    + b2f(el2.x >> 16);
    Ev[2] = b2f(eh2.y & 0xffff) + b2f(el2.y & 0xffff);
    Ev[3] = b2f(eh2.y >> 16)    + b2f(el2.y >> 16);
    unsigned short hs[4], ls[4];
#pragma unroll
    for (int e = 0; e < 4; e++) {
        float nh = ex[e] * inv / (Ev[e] + 1e-5f);
        hs[e] = f2b(nh);
        ls[e] = f2b(nh - b2f(hs[e]));
    }
    uint2 ho, lo;
    ho.x = (unsigned)hs[0] | ((unsigned)hs[1] << 16);
    ho.y = (unsigned)hs[2] | ((unsigned)hs[3] << 16);
    lo.x = (unsigned)ls[0] | ((unsigned)ls[1] << 16);
    lo.y = (unsigned)ls[2] | ((unsigned)ls[3] << 16);
    *(uint2*)(GH + base) = ho;
    *(uint2*)(GL + base) = lo;
}

// ---------------------------------------------------------------- k_out_mfma
__launch_bounds__(256, 2)
__global__ void k_out_mfma(
    const unsigned short* __restrict__ EH, const unsigned short* __restrict__ EL,
    const unsigned short* __restrict__ NH, const unsigned short* __restrict__ NL,
    const unsigned short* __restrict__ AmixH, const unsigned short* __restrict__ AmixL,
    const unsigned short* __restrict__ XTh, const unsigned short* __restrict__ XTl,
    const unsigned short* __restrict__ W2h, const unsigned short* __restrict__ W2l,
    const float* __restrict__ xc, const float* __restrict__ x0c,
    const float* __restrict__ sa, const float* __restrict__ cb,
    float* __restrict__ outf, float* __restrict__ outg)
{
    const int i0    = blockIdx.x * 64;
    const int bc    = blockIdx.y;
    const bool modeF = (blockIdx.z == 0);
    const int t     = threadIdx.x;
    const int lane  = t & 63;
    const int wave  = t >> 6;
    const int quad  = lane >> 4;
    const int m16   = lane & 15;
    const int l7    = lane & 7;
    const int r_sub = lane >> 3;
    const int gc    = l7 ^ r_sub;

    __shared__ __align__(16) unsigned short lds[6 * 4096];   // 48 KB

    const unsigned short* Mh = modeF ? EH : NH;
    const unsigned short* Ml = modeF ? EL : NL;

    const unsigned short* sb[6];
    sb[0] = Mh + ((size_t)bc * N_ + i0) * N_;
    sb[1] = Ml + ((size_t)bc * N_ + i0) * N_;
    sb[2] = XTh + (size_t)bc * D_ * N_;
    sb[3] = XTl + (size_t)bc * D_ * N_;
    sb[4] = AmixH + (size_t)i0 * N_;
    sb[5] = AmixL + (size_t)i0 * N_;

    const int per = modeF ? 12 : 8;   // staging issues per wave (nbuf*8/4)

    f32x4 acc[4];
#pragma unroll
    for (int cg = 0; cg < 4; cg++) acc[cg] = (f32x4){0.f, 0.f, 0.f, 0.f};

    const int rowA = wave * 16 + m16;

    for (int step = 0; step < 16; step++) {
        const int jb = step * 64;
        __syncthreads();
        for (int i = 0; i < per; i++) {
            int gi  = wave * per + i;
            int buf = gi >> 3, rg = gi & 7;
            const unsigned short* gp = sb[buf] + (size_t)(rg * 8 + r_sub) * N_ + jb + gc * 8;
            GLD16(gp, lds + buf * 4096 + rg * 512);
        }
        __syncthreads();
#pragma unroll
        for (int kc = 0; kc < 2; kc++) {
            const int ch = ((kc * 4 + quad) ^ l7) * 8;
            short8 mh = *(const short8*)(lds + rowA * 64 + ch);
            short8 ml = *(const short8*)(lds + 4096 + rowA * 64 + ch);
            short8 bh[4], bl[4];
#pragma unroll
            for (int cg = 0; cg < 4; cg++) {
                int rowB = cg * 16 + m16;
                bh[cg] = *(const short8*)(lds + 2 * 4096 + rowB * 64 + ch);
                bl[cg] = *(const short8*)(lds + 3 * 4096 + rowB * 64 + ch);
            }
#pragma unroll
            for (int cg = 0; cg < 4; cg++) {
                acc[cg] = __builtin_amdgcn_mfma_f32_16x16x32_bf16(mh, bh[cg], acc[cg], 0, 0, 0);
                acc[cg] = __builtin_amdgcn_mfma_f32_16x16x32_bf16(mh, bl[cg], acc[cg], 0, 0, 0);
                acc[cg] = __builtin_amdgcn_mfma_f32_16x16x32_bf16(ml, bh[cg], acc[cg], 0, 0, 0);
            }
            if (modeF) {
                short8 ah = *(const short8*)(lds + 4 * 4096 + rowA * 64 + ch);
                short8 al = *(const short8*)(lds + 5 * 4096 + rowA * 64 + ch);
#pragma unroll
                for (int cg = 0; cg < 4; cg++) {
                    acc[cg] = __builtin_amdgcn_mfma_f32_16x16x32_bf16(ah, bh[cg], acc[cg], 0, 0, 0);
                    acc[cg] = __builtin_amdgcn_mfma_f32_16x16x32_bf16(ah, bl[cg], acc[cg], 0, 0, 0);
                    acc[cg] = __builtin_amdgcn_mfma_f32_16x16x32_bf16(al, bh[cg], acc[cg], 0, 0, 0);
                }
            }
        }
    }

    if (modeF) {
        // phase B: += x_rows @ What2  (one K=64 step; What2 symmetric)
        __syncthreads();
        if (wave < 2) {
            int r  = wave * 32 + (lane >> 1);
            int qh = (lane & 1) * 32;
            const float* xrow = xc + ((size_t)bc * N_ + i0 + r) * D_ + qh;
#pragma unroll
            for (int cc = 0; cc < 4; cc++) {
                float4 v0 = *(const float4*)(xrow + cc * 8);
                float4 v1 = *(const float4*)(xrow + cc * 8 + 4);
                float vv[8] = {v0.x, v0.y, v0.z, v0.w, v1.x, v1.y, v1.z, v1.w};
                short8 hh, ll;
#pragma unroll
                for (int e = 0; e < 8; e++) {
                    unsigned short h = f2b(vv[e]);
                    hh[e] = (short)h;
                    ll[e] = (short)f2b(vv[e] - b2f(h));
                }
                int c   = (qh >> 3) + cc;
                int pos = (c ^ (r & 7)) * 8;
                *(short8*)(lds + r * 64 + pos) = hh;
                *(short8*)(lds + 4096 + r * 64 + pos) = ll;
            }
        } else {
            const unsigned short* gsrc = (wave == 2) ? W2h : W2l;
            unsigned short* ldst = lds + wave * 4096;   // wave2->buf2, wave3->buf3
#pragma unroll
            for (int rg = 0; rg < 8; rg++) {
                const unsigned short* gp = gsrc + (size_t)(rg * 8 + r_sub) * 64 + gc * 8;
                GLD16(gp, ldst + rg * 512);
            }
        }
        __syncthreads();
#pragma unroll
        for (int kc = 0; kc < 2; kc++) {
            const int ch = ((kc * 4 + quad) ^ l7) * 8;
            short8 ah = *(const short8*)(lds + rowA * 64 + ch);
            short8 al = *(const short8*)(lds + 4096 + rowA * 64 + ch);
#pragma unroll
            for (int cg = 0; cg < 4; cg++) {
                int rowB = cg * 16 + m16;
                short8 bh = *(const short8*)(lds + 2 * 4096 + rowB * 64 + ch);
                short8 bl = *(const short8*)(lds + 3 * 4096 + rowB * 64 + ch);
                acc[cg] = __builtin_amdgcn_mfma_f32_16x16x32_bf16(ah, bh, acc[cg], 0, 0, 0);
                acc[cg] = __builtin_amdgcn_mfma_f32_16x16x32_bf16(ah, bl, acc[cg], 0, 0, 0);
                acc[cg] = __builtin_amdgcn_mfma_f32_16x16x32_bf16(al, bh, acc[cg], 0, 0, 0);
            }
        }
    }

    float cbv = modeF ? cb[0] : 0.f;
    float* outp = modeF ? outf : outg;
#pragma unroll
    for (int cg = 0; cg < 4; cg++) {
#pragma unroll
        for (int r = 0; r < 4; r++) {
            int row = i0 + wave * 16 + quad * 4 + r;
            int col = cg * 16 + m16;
            float v = acc[cg][r];
            if (modeF)
                v += x0c[((size_t)bc * N_ + row) * D_ + col] * sa[row] + cbv;
            outp[((size_t)bc * N_ + row) * D_ + col] = tanhf(v);
        }
    }
}

// ---------------------------------------------------------------- host
extern "C" void kernel_launch(void* const* d_in, const int* in_sizes, int n_in,
                              void* d_out, int out_size, void* d_ws, size_t ws_size,
                              hipStream_t stream)
{
    const float* x     = (const float*)d_in[0];
    const float* x0    = (const float*)d_in[1];
    const float* w     = (const float*)d_in[2];
    const float* dvec  = (const float*)d_in[3];
    const float* alpha = (const float*)d_in[4];
    const float* fw1   = (const float*)d_in[5];
    const float* fw2   = (const float*)d_in[6];
    const float* fvs   = (const float*)d_in[7];
    const float* fbs   = (const float*)d_in[8];
    const float* gw1   = (const float*)d_in[9];
    const float* gw2   = (const float*)d_in[10];
    const float* gvs   = (const float*)d_in[11];
    const float* gbs   = (const float*)d_in[12];
    const float* cw    = (const float*)d_in[13];
    const float* cb    = (const float*)d_in[14];
    const float* adj   = (const float*)d_in[15];

    float* outf = (float*)d_out;
    float* outg = outf + (size_t)B_ * N_ * D_;

    char* p = (char*)d_ws;
    auto alloc = [&](size_t bytes) { void* r = p; p += (bytes + 255) & ~(size_t)255; return r; };

    float* e1f = (float*)alloc(B_ * N_ * 4);
    float* e2f = (float*)alloc(B_ * N_ * 4);
    float* e1g = (float*)alloc(B_ * N_ * 4);
    float* e2g = (float*)alloc(B_ * N_ * 4);
    float* sa  = (float*)alloc(N_ * 4);
    unsigned short* W2h = (unsigned short*)alloc(D_ * D_ * 2);
    unsigned short* W2l = (unsigned short*)alloc(D_ * D_ * 2);
    unsigned short* AmixH = (unsigned short*)alloc((size_t)N_ * N_ * 2);
    unsigned short* AmixL = (unsigned short*)alloc((size_t)N_ * N_ * 2);
    unsigned short* AHf = (unsigned short*)alloc((size_t)N_ * N_ * 2);
    unsigned short* ALf = (unsigned short*)alloc((size_t)N_ * N_ * 2);
    unsigned short* AHg = (unsigned short*)alloc((size_t)N_ * N_ * 2);
    unsigned short* ALg = (unsigned short*)alloc((size_t)N_ * N_ * 2);
    unsigned short* XTh = (unsigned short*)alloc((size_t)BCH * D_ * N_ * 2);
    unsigned short* XTl = (unsigned short*)alloc((size_t)BCH * D_ * N_ * 2);
    unsigned short* SHf = (unsigned short*)alloc((size_t)BCH * N_ * N_ * 2);
    unsigned short* SLf = (unsigned short*)alloc((size_t)BCH * N_ * N_ * 2);
    unsigned short* SHg = (unsigned short*)alloc((size_t)BCH * N_ * N_ * 2);
    unsigned short* SLg = (unsigned short*)alloc((size_t)BCH * N_ * N_ * 2);
    unsigned short* LHf = (unsigned short*)alloc((size_t)BCH * N_ * N_ * 2);
    unsigned short* LLf = (unsigned short*)alloc((size_t)BCH * N_ * N_ * 2);
    unsigned short* LHg = (unsigned short*)alloc((size_t)BCH * N_ * N_ * 2);
    unsigned short* LLg = (unsigned short*)alloc((size_t)BCH * N_ * N_ * 2);
    // E aliases the (dead after gemm) f S-buffers
    unsigned short* EH = SHf;
    unsigned short* EL = SLf;
    (void)ws_size; (void)in_sizes; (void)n_in; (void)out_size;

    k_dots<<<dim3((B_ * N_) / 256), 256, 0, stream>>>(x, fw1, fw2, gw1, gw2, alpha,
                                                      e1f, e2f, e1g, e2g, sa);
    k_what2_split<<<dim3(16), 256, 0, stream>>>(w, dvec, W2h, W2l);
    k_amix_split<<<dim3(N_ * N_ / 256), 256, 0, stream>>>(adj, cw, AmixH, AmixL);
    k_asplit<<<dim3(N_ * N_ / 1024), 256, 0, stream>>>(fvs, AHf, ALf);
    k_asplit<<<dim3(N_ * N_ / 1024), 256, 0, stream>>>(gvs, AHg, ALg);

    for (int c = 0; c < B_ / BCH; c++) {
        int boff = c * BCH;
        const float* xc  = x  + (size_t)boff * N_ * D_;
        const float* x0c = x0 + (size_t)boff * N_ * D_;
        k_xt_split<<<dim3(16, BCH), 256, 0, stream>>>(xc, XTh, XTl);
        k_sigsplit2<<<dim3(16, 16, BCH * 2), 256, 0, stream>>>(
            fbs, gbs, e1f + boff * N_, e2f + boff * N_,
            e1g + boff * N_, e2g + boff * N_, SHf, SLf, SHg, SLg);
        k_gemm2<<<dim3(64, BCH, 2), 256, 0, stream>>>(
            AHf, ALf, AHg, ALg, SHf, SLf, SHg, SLg, LHf, LLf, LHg, LLg);
        k_softmax_bf<<<dim3(BCH * N_), 256, 0, stream>>>(LHf, LLf, EH, EL);
        k_softmax_div_bf<<<dim3(BCH * N_), 256, 0, stream>>>(LHg, LLg, EH, EL);
        k_out_mfma<<<dim3(16, BCH, 2), 256, 0, stream>>>(
            EH, EL, LHg, LLg, AmixH, AmixL, XTh, XTl, W2h, W2l,
            xc, x0c, sa, cb,
            outf + (size_t)boff * N_ * D_, outg + (size_t)boff * N_ * D_);
    }
}

// Round 6
// 744.389 us; speedup vs baseline: 3.4247x; 1.3889x over previous
//
#include <hip/hip_runtime.h>
#include <math.h>

constexpr int B_ = 32;
constexpr int N_ = 1024;
constexpr int D_ = 64;
constexpr int BCH = 8;   // batch chunk; workspace ~142 MB (ws is ~268 MB)

typedef short short8 __attribute__((ext_vector_type(8)));   // 8 bf16 (4 VGPRs)
typedef float f32x4 __attribute__((ext_vector_type(4)));    // MFMA accumulator

__device__ __forceinline__ float sigf(float v) {
    return 1.0f / (1.0f + __expf(-v));
}
__device__ __forceinline__ unsigned short f2b(float f) {   // fp32 -> bf16 RNE
    unsigned u = __float_as_uint(f);
    unsigned r = u + 0x7fffu + ((u >> 16) & 1u);
    return (unsigned short)(r >> 16);
}
__device__ __forceinline__ float b2f(unsigned int h) {
    return __uint_as_float(h << 16);
}

#define GLD16(gp, lp)                                                        \
    __builtin_amdgcn_global_load_lds(                                        \
        (const __attribute__((address_space(1))) unsigned int*)(const void*)(gp), \
        (__attribute__((address_space(3))) unsigned int*)(void*)(lp), 16, 0, 0)

// ---------------------------------------------------------------- k_dots
__global__ void k_dots(const float* __restrict__ x,
                       const float* __restrict__ fw1, const float* __restrict__ fw2,
                       const float* __restrict__ gw1, const float* __restrict__ gw2,
                       const float* __restrict__ alpha,
                       float* __restrict__ e1f, float* __restrict__ e2f,
                       float* __restrict__ e1g, float* __restrict__ e2g,
                       float* __restrict__ sa)
{
    int t = blockIdx.x * blockDim.x + threadIdx.x;
    if (t < N_) sa[t] = sigf(alpha[t]);
    if (t >= B_ * N_) return;
    const float* xr = x + (size_t)t * D_;
    float s1 = 0.f, s2 = 0.f, s3 = 0.f, s4 = 0.f;
#pragma unroll 8
    for (int d = 0; d < D_; d++) {
        float v = xr[d];
        s1 += v * fw1[d];
        s2 += v * fw2[d];
        s3 += v * gw1[d];
        s4 += v * gw2[d];
    }
    e1f[t] = s1; e2f[t] = s2; e1g[t] = s3; e2g[t] = s4;
}

// ---------------------------------------------------------------- k_what2_split
// What2 = (w*dc)@w.T - 2I  (folds W_hat's -I and the (E-I) -I), bf16 hi/lo
__global__ void k_what2_split(const float* __restrict__ w, const float* __restrict__ dvec,
                              unsigned short* __restrict__ W2h, unsigned short* __restrict__ W2l)
{
    int t = blockIdx.x * blockDim.x + threadIdx.x;
    if (t >= D_ * D_) return;
    int i = t / D_, j = t % D_;
    float s = 0.f;
    for (int q = 0; q < D_; q++) {
        float dc = fminf(fmaxf(dvec[q], 0.0f), 1.0f);
        s += w[i * D_ + q] * dc * w[j * D_ + q];
    }
    if (i == j) s -= 2.0f;
    unsigned short h = f2b(s);
    W2h[t] = h;
    W2l[t] = f2b(s - b2f(h));
}

// ---------------------------------------------------------------- k_amix_split
__global__ void k_amix_split(const float* __restrict__ adj, const float* __restrict__ cw,
                             unsigned short* __restrict__ AmixH, unsigned short* __restrict__ AmixL)
{
    int t = blockIdx.x * blockDim.x + threadIdx.x;
    if (t >= N_ * N_) return;
    int i = t >> 10, j = t & (N_ - 1);
    float c0 = cw[0], c1 = cw[1];
    float v = c0 * adj[t] + c1 * adj[(size_t)N_ * N_ + t];
    if (i == j) v -= (c0 + c1);
    unsigned short h = f2b(v);
    AmixH[t] = h;
    AmixL[t] = f2b(v - b2f(h));
}

// ---------------------------------------------------------------- k_asplit (vs)
__global__ void k_asplit(const float* __restrict__ src,
                         unsigned short* __restrict__ hi, unsigned short* __restrict__ lo)
{
    int t = blockIdx.x * blockDim.x + threadIdx.x;     // N*N/4 threads
    size_t idx = (size_t)t * 4;
    float4 v = *(const float4*)(src + idx);
    float a[4] = {v.x, v.y, v.z, v.w};
    unsigned short hs[4], ls[4];
#pragma unroll
    for (int e = 0; e < 4; e++) {
        hs[e] = f2b(a[e]);
        ls[e] = f2b(a[e] - b2f(hs[e]));
    }
    uint2 h2, l2;
    h2.x = (unsigned)hs[0] | ((unsigned)hs[1] << 16);
    h2.y = (unsigned)hs[2] | ((unsigned)hs[3] << 16);
    l2.x = (unsigned)ls[0] | ((unsigned)ls[1] << 16);
    l2.y = (unsigned)ls[2] | ((unsigned)ls[3] << 16);
    *(uint2*)(hi + idx) = h2;
    *(uint2*)(lo + idx) = l2;
}

// ---------------------------------------------------------------- k_xt_split
// XTh/XTl[bc][d][j] = bf16 hi/lo of x[bc][j][d]  (transposed, MFMA B-operand)
__launch_bounds__(256)
__global__ void k_xt_split(const float* __restrict__ xc,
                           unsigned short* __restrict__ XTh, unsigned short* __restrict__ XTl)
{
    int j0 = blockIdx.x * 64;
    int bc = blockIdx.y;
    int t  = threadIdx.x;
    __shared__ float S_l[64][65];
    {
        int j = t >> 2, dc = (t & 3) * 16;
        const float* src = xc + ((size_t)bc * N_ + j0 + j) * D_ + dc;
#pragma unroll
        for (int q = 0; q < 4; q++) {
            float4 v = *(const float4*)(src + q * 4);
            S_l[j][dc + q * 4 + 0] = v.x;
            S_l[j][dc + q * 4 + 1] = v.y;
            S_l[j][dc + q * 4 + 2] = v.z;
            S_l[j][dc + q * 4 + 3] = v.w;
        }
    }
    __syncthreads();
    {
        int d = t >> 2, jc = (t & 3) * 16;
        unsigned short hs[16], ls[16];
#pragma unroll
        for (int u = 0; u < 16; u++) {
            float v = S_l[jc + u][d];
            hs[u] = f2b(v);
            ls[u] = f2b(v - b2f(hs[u]));
        }
        uint4 hv0, hv1, lv0, lv1;
        hv0.x = hs[0] | (hs[1] << 16);  hv0.y = hs[2] | (hs[3] << 16);
        hv0.z = hs[4] | (hs[5] << 16);  hv0.w = hs[6] | (hs[7] << 16);
        hv1.x = hs[8] | (hs[9] << 16);  hv1.y = hs[10] | (hs[11] << 16);
        hv1.z = hs[12] | (hs[13] << 16); hv1.w = hs[14] | (hs[15] << 16);
        lv0.x = ls[0] | (ls[1] << 16);  lv0.y = ls[2] | (ls[3] << 16);
        lv0.z = ls[4] | (ls[5] << 16);  lv0.w = ls[6] | (ls[7] << 16);
        lv1.x = ls[8] | (ls[9] << 16);  lv1.y = ls[10] | (ls[11] << 16);
        lv1.z = ls[12] | (ls[13] << 16); lv1.w = ls[14] | (ls[15] << 16);
        size_t base = ((size_t)bc * D_ + d) * N_ + j0 + jc;
        *(uint4*)(XTh + base) = hv0;  *(uint4*)(XTh + base + 8) = hv1;
        *(uint4*)(XTl + base) = lv0;  *(uint4*)(XTl + base + 8) = lv1;
    }
}

// ---------------------------------------------------------------- k_sigsplit2
// blockIdx.z = b + BCH*fg: computes S^T hi/lo for both f (fg=0) and g (fg=1)
__launch_bounds__(256)
__global__ void k_sigsplit2(const float* __restrict__ fbs, const float* __restrict__ gbs,
                            const float* __restrict__ e1f_, const float* __restrict__ e2f_,
                            const float* __restrict__ e1g_, const float* __restrict__ e2g_,
                            unsigned short* __restrict__ SHf, unsigned short* __restrict__ SLf,
                            unsigned short* __restrict__ SHg, unsigned short* __restrict__ SLg)
{
    int j0 = blockIdx.x * 64;
    int k0 = blockIdx.y * 64;
    int z  = blockIdx.z;
    int b  = z & (BCH - 1);
    int fg = z >> 3;                      // BCH == 8
    const float* bs = fg ? gbs : fbs;
    const float* e1 = fg ? e1g_ : e1f_;
    const float* e2 = fg ? e2g_ : e2f_;
    unsigned short* SH = fg ? SHg : SHf;
    unsigned short* SL = fg ? SLg : SLf;
    int t  = threadIdx.x;
    __shared__ float S_l[64][65];
    {
        int j  = t >> 2;
        int kc = (t & 3) * 16;
        float e1v = e1[(size_t)b * N_ + j0 + j];
#pragma unroll
        for (int q = 0; q < 4; q++) {
            float4 bsv = *(const float4*)(bs + (size_t)(j0 + j) * N_ + k0 + kc + q * 4);
            float4 e2v = *(const float4*)(e2 + (size_t)b * N_ + k0 + kc + q * 4);
            S_l[j][kc + q * 4 + 0] = sigf(fmaf(e1v, e2v.x, bsv.x));
            S_l[j][kc + q * 4 + 1] = sigf(fmaf(e1v, e2v.y, bsv.y));
            S_l[j][kc + q * 4 + 2] = sigf(fmaf(e1v, e2v.z, bsv.z));
            S_l[j][kc + q * 4 + 3] = sigf(fmaf(e1v, e2v.w, bsv.w));
        }
    }
    __syncthreads();
    {
        int k  = t >> 2;
        int jc = (t & 3) * 16;
        unsigned short hs[16], ls[16];
#pragma unroll
        for (int u = 0; u < 16; u++) {
            float v = S_l[jc + u][k];
            hs[u] = f2b(v);
            ls[u] = f2b(v - b2f(hs[u]));
        }
        uint4 hv0, hv1, lv0, lv1;
        hv0.x = hs[0] | (hs[1] << 16);  hv0.y = hs[2] | (hs[3] << 16);
        hv0.z = hs[4] | (hs[5] << 16);  hv0.w = hs[6] | (hs[7] << 16);
        hv1.x = hs[8] | (hs[9] << 16);  hv1.y = hs[10] | (hs[11] << 16);
        hv1.z = hs[12] | (hs[13] << 16); hv1.w = hs[14] | (hs[15] << 16);
        lv0.x = ls[0] | (ls[1] << 16);  lv0.y = ls[2] | (ls[3] << 16);
        lv0.z = ls[4] | (ls[5] << 16);  lv0.w = ls[6] | (ls[7] << 16);
        lv1.x = ls[8] | (ls[9] << 16);  lv1.y = ls[10] | (ls[11] << 16);
        lv1.z = ls[12] | (ls[13] << 16); lv1.w = ls[14] | (ls[15] << 16);
        size_t base = ((size_t)b * N_ + k0 + k) * N_ + j0 + jc;
        *(uint4*)(SH + base) = hv0;  *(uint4*)(SH + base + 8) = hv1;
        *(uint4*)(SL + base) = lv0;  *(uint4*)(SL + base + 8) = lv1;
    }
}

// ---------------------------------------------------------------- k_gemm2
// Merged f+g attention GEMM: blockIdx.z selects the operand/output set.
__launch_bounds__(256, 2)
__global__ void k_gemm2(const unsigned short* __restrict__ AHf, const unsigned short* __restrict__ ALf,
                        const unsigned short* __restrict__ AHg, const unsigned short* __restrict__ ALg,
                        const unsigned short* __restrict__ SHf, const unsigned short* __restrict__ SLf,
                        const unsigned short* __restrict__ SHg, const unsigned short* __restrict__ SLg,
                        unsigned short* __restrict__ LHf, unsigned short* __restrict__ LLf,
                        unsigned short* __restrict__ LHg, unsigned short* __restrict__ LLg)
{
    const int fg = blockIdx.z;
    const unsigned short* AH = fg ? AHg : AHf;
    const unsigned short* AL = fg ? ALg : ALf;
    const unsigned short* SH = fg ? SHg : SHf;
    const unsigned short* SL = fg ? SLg : SLf;
    unsigned short* LHo = fg ? LHg : LHf;
    unsigned short* LLo = fg ? LLg : LLf;

    const int b  = blockIdx.y;
    const int i0 = (blockIdx.x >> 3) * 128;
    const int k0 = (blockIdx.x & 7) * 128;
    const int t    = threadIdx.x;
    const int lane = t & 63;
    const int wave = t >> 6;
    const int wr   = wave >> 1;
    const int wc   = wave & 1;
    const int quad = lane >> 4;
    const int l7   = lane & 7;
    const int m16  = lane & 15;

    __shared__ unsigned short lds[4 * 8192];
    unsigned short* AHl = lds;
    unsigned short* ALl = lds + 8192;
    unsigned short* BHl = lds + 16384;
    unsigned short* BLl = lds + 24576;

    const unsigned short* gsrc;
    unsigned short* ldst;
    int rowbase;
    if (wave == 0)      { gsrc = AH; ldst = AHl; rowbase = i0; }
    else if (wave == 1) { gsrc = AL; ldst = ALl; rowbase = i0; }
    else if (wave == 2) { gsrc = SH; ldst = BHl; rowbase = b * N_ + k0; }
    else                { gsrc = SL; ldst = BLl; rowbase = b * N_ + k0; }

    f32x4 acc[4][4];
#pragma unroll
    for (int mi = 0; mi < 4; mi++)
#pragma unroll
        for (int ni = 0; ni < 4; ni++)
            acc[mi][ni] = (f32x4){0.f, 0.f, 0.f, 0.f};

    const int r_sub = lane >> 3;
    const int gc    = l7 ^ r_sub;

    for (int step = 0; step < 16; step++) {
        const int jb = step * 64;
        __syncthreads();
#pragma unroll
        for (int i = 0; i < 16; i++) {
            int r = i * 8 + r_sub;
            const unsigned short* gp = gsrc + (size_t)(rowbase + r) * N_ + jb + gc * 8;
            GLD16(gp, ldst + i * 512);
        }
        __syncthreads();

#pragma unroll
        for (int s = 0; s < 2; s++) {
            short8 ah[4], al[4], bh[4], bl[4];
            const int ch = (((s << 2) + quad) ^ l7) * 8;
#pragma unroll
            for (int mi = 0; mi < 4; mi++) {
                int row = wr * 64 + mi * 16 + m16;
                ah[mi] = *(const short8*)(AHl + row * 64 + ch);
                al[mi] = *(const short8*)(ALl + row * 64 + ch);
            }
#pragma unroll
            for (int ni = 0; ni < 4; ni++) {
                int row = wc * 64 + ni * 16 + m16;
                bh[ni] = *(const short8*)(BHl + row * 64 + ch);
                bl[ni] = *(const short8*)(BLl + row * 64 + ch);
            }
#pragma unroll
            for (int mi = 0; mi < 4; mi++)
#pragma unroll
                for (int ni = 0; ni < 4; ni++)
                    acc[mi][ni] = __builtin_amdgcn_mfma_f32_16x16x32_bf16(
                        ah[mi], bh[ni], acc[mi][ni], 0, 0, 0);
#pragma unroll
            for (int mi = 0; mi < 4; mi++)
#pragma unroll
                for (int ni = 0; ni < 4; ni++)
                    acc[mi][ni] = __builtin_amdgcn_mfma_f32_16x16x32_bf16(
                        ah[mi], bl[ni], acc[mi][ni], 0, 0, 0);
#pragma unroll
            for (int mi = 0; mi < 4; mi++)
#pragma unroll
                for (int ni = 0; ni < 4; ni++)
                    acc[mi][ni] = __builtin_amdgcn_mfma_f32_16x16x32_bf16(
                        al[mi], bh[ni], acc[mi][ni], 0, 0, 0);
        }
    }

#pragma unroll
    for (int mi = 0; mi < 4; mi++)
#pragma unroll
        for (int ni = 0; ni < 4; ni++) {
            int row = i0 + wr * 64 + mi * 16 + quad * 4;
            int col = k0 + wc * 64 + ni * 16 + m16;
            size_t base = ((size_t)b * N_ + row) * N_ + col;
#pragma unroll
            for (int r = 0; r < 4; r++) {
                float v = acc[mi][ni][r];
                unsigned short h = f2b(v);
                LHo[base + (size_t)r * N_] = h;
                LLo[base + (size_t)r * N_] = f2b(v - b2f(h));
            }
        }
}

// ---------------------------------------------------------------- k_softmax2
// Fused: E = softmax(f logits) row (write EH bf16-hi only), then
// N_hat = softmax(g logits)/(E_fp32 + 1e-5) written hi/lo in place of g logits.
__launch_bounds__(256)
__global__ void k_softmax2(const unsigned short* __restrict__ LHf,
                           const unsigned short* __restrict__ LLf,
                           unsigned short* GH, unsigned short* GL,
                           unsigned short* __restrict__ EH)
{
    size_t row = blockIdx.x;
    int t = threadIdx.x;
    size_t base = row * N_ + (size_t)t * 4;
    __shared__ float red1[4], red2[4], red3[4], red4[4];

    // ---- f softmax ----
    uint2 h2 = *(const uint2*)(LHf + base);
    uint2 l2 = *(const uint2*)(LLf + base);
    float v[4];
    v[0] = b2f(h2.x & 0xffff) + b2f(l2.x & 0xffff);
    v[1] = b2f(h2.x >> 16)    + b2f(l2.x >> 16);
    v[2] = b2f(h2.y & 0xffff) + b2f(l2.y & 0xffff);
    v[3] = b2f(h2.y >> 16)    + b2f(l2.y >> 16);
    float m = fmaxf(fmaxf(v[0], v[1]), fmaxf(v[2], v[3]));
#pragma unroll
    for (int o = 32; o > 0; o >>= 1) m = fmaxf(m, __shfl_xor(m, o, 64));
    if ((t & 63) == 0) red1[t >> 6] = m;
    // ---- g logits load (overlap with f reduction latency) ----
    uint2 gh2 = *(const uint2*)(GH + base);
    uint2 gl2 = *(const uint2*)(GL + base);
    float gv[4];
    gv[0] = b2f(gh2.x & 0xffff) + b2f(gl2.x & 0xffff);
    gv[1] = b2f(gh2.x >> 16)    + b2f(gl2.x >> 16);
    gv[2] = b2f(gh2.y & 0xffff) + b2f(gl2.y & 0xffff);
    gv[3] = b2f(gh2.y >> 16)    + b2f(gl2.y >> 16);
    float gm = fmaxf(fmaxf(gv[0], gv[1]), fmaxf(gv[2], gv[3]));
#pragma unroll
    for (int o = 32; o > 0; o >>= 1) gm = fmaxf(gm, __shfl_xor(gm, o, 64));
    if ((t & 63) == 0) red2[t >> 6] = gm;
    __syncthreads();
    m  = fmaxf(fmaxf(red1[0], red1[1]), fmaxf(red1[2], red1[3]));
    gm = fmaxf(fmaxf(red2[0], red2[1]), fmaxf(red2[2], red2[3]));
    float ex[4]  = {__expf(v[0] - m),  __expf(v[1] - m),  __expf(v[2] - m),  __expf(v[3] - m)};
    float gex[4] = {__expf(gv[0] - gm), __expf(gv[1] - gm), __expf(gv[2] - gm), __expf(gv[3] - gm)};
    float s  = ex[0] + ex[1] + ex[2] + ex[3];
    float gs = gex[0] + gex[1] + gex[2] + gex[3];
#pragma unroll
    for (int o = 32; o > 0; o >>= 1) { s += __shfl_xor(s, o, 64); gs += __shfl_xor(gs, o, 64); }
    if ((t & 63) == 0) { red3[t >> 6] = s; red4[t >> 6] = gs; }
    __syncthreads();
    s  = red3[0] + red3[1] + red3[2] + red3[3];
    gs = red4[0] + red4[1] + red4[2] + red4[3];
    float inv  = 1.0f / s;
    float ginv = 1.0f / gs;

    unsigned short ehs[4], hs[4], ls[4];
#pragma unroll
    for (int e = 0; e < 4; e++) {
        float E = ex[e] * inv;
        ehs[e] = f2b(E);
        float nh = gex[e] * ginv / (E + 1e-5f);
        hs[e] = f2b(nh);
        ls[e] = f2b(nh - b2f(hs[e]));
    }
    uint2 eo, ho, lo;
    eo.x = (unsigned)ehs[0] | ((unsigned)ehs[1] << 16);
    eo.y = (unsigned)ehs[2] | ((unsigned)ehs[3] << 16);
    ho.x = (unsigned)hs[0] | ((unsigned)hs[1] << 16);
    ho.y = (unsigned)hs[2] | ((unsigned)hs[3] << 16);
    lo.x = (unsigned)ls[0] | ((unsigned)ls[1] << 16);
    lo.y = (unsigned)ls[2] | ((unsigned)ls[3] << 16);
    *(uint2*)(EH + base) = eo;
    *(uint2*)(GH + base) = ho;
    *(uint2*)(GL + base) = lo;
}

// ---------------------------------------------------------------- k_out_mfma
// z=0 (f): out = tanh(E@x + Amix@x + x@What2 + x0*sa + cb)   (E single bf16)
// z=1 (g): out = tanh(Nhat@x)                                 (Nhat hi/lo)
__launch_bounds__(256, 2)
__global__ void k_out_mfma(
    const unsigned short* __restrict__ EH,
    const unsigned short* __restrict__ NH, const unsigned short* __restrict__ NL,
    const unsigned short* __restrict__ AmixH, const unsigned short* __restrict__ AmixL,
    const unsigned short* __restrict__ XTh, const unsigned short* __restrict__ XTl,
    const unsigned short* __restrict__ W2h, const unsigned short* __restrict__ W2l,
    const float* __restrict__ xc, const float* __restrict__ x0c,
    const float* __restrict__ sa, const float* __restrict__ cb,
    float* __restrict__ outf, float* __restrict__ outg)
{
    const int i0    = blockIdx.x * 64;
    const int bc    = blockIdx.y;
    const bool modeF = (blockIdx.z == 0);
    const int t     = threadIdx.x;
    const int lane  = t & 63;
    const int wave  = t >> 6;
    const int quad  = lane >> 4;
    const int m16   = lane & 15;
    const int l7    = lane & 7;
    const int r_sub = lane >> 3;
    const int gc    = l7 ^ r_sub;

    __shared__ __align__(16) unsigned short lds[5 * 4096];   // 40 KB

    // buffer lists:
    // modeF: 0=E(row strip) 1=XTh 2=XTl 3=AmixH(row strip) 4=AmixL
    // modeG: 0=NH 1=NL 2=XTh 3=XTl
    const unsigned short* sb[5];
    int nbuf;
    if (modeF) {
        sb[0] = EH + ((size_t)bc * N_ + i0) * N_;
        sb[1] = XTh + (size_t)bc * D_ * N_;
        sb[2] = XTl + (size_t)bc * D_ * N_;
        sb[3] = AmixH + (size_t)i0 * N_;
        sb[4] = AmixL + (size_t)i0 * N_;
        nbuf = 5;
    } else {
        sb[0] = NH + ((size_t)bc * N_ + i0) * N_;
        sb[1] = NL + ((size_t)bc * N_ + i0) * N_;
        sb[2] = XTh + (size_t)bc * D_ * N_;
        sb[3] = XTl + (size_t)bc * D_ * N_;
        nbuf = 4;
    }
    const int per = nbuf * 2;   // staging issues per wave (nbuf*8/4)

    f32x4 acc[4];
#pragma unroll
    for (int cg = 0; cg < 4; cg++) acc[cg] = (f32x4){0.f, 0.f, 0.f, 0.f};

    const int rowA = wave * 16 + m16;

    for (int step = 0; step < 16; step++) {
        const int jb = step * 64;
        __syncthreads();
        for (int i = 0; i < per; i++) {
            int gi  = wave * per + i;
            int buf = gi >> 3, rg = gi & 7;
            const unsigned short* gp = sb[buf] + (size_t)(rg * 8 + r_sub) * N_ + jb + gc * 8;
            GLD16(gp, lds + buf * 4096 + rg * 512);
        }
        __syncthreads();
#pragma unroll
        for (int kc = 0; kc < 2; kc++) {
            const int ch = ((kc * 4 + quad) ^ l7) * 8;
            if (modeF) {
                short8 eh = *(const short8*)(lds + rowA * 64 + ch);
                short8 ah = *(const short8*)(lds + 3 * 4096 + rowA * 64 + ch);
                short8 al = *(const short8*)(lds + 4 * 4096 + rowA * 64 + ch);
#pragma unroll
                for (int cg = 0; cg < 4; cg++) {
                    int rowB = cg * 16 + m16;
                    short8 bh = *(const short8*)(lds + 1 * 4096 + rowB * 64 + ch);
                    short8 bl = *(const short8*)(lds + 2 * 4096 + rowB * 64 + ch);
                    acc[cg] = __builtin_amdgcn_mfma_f32_16x16x32_bf16(eh, bh, acc[cg], 0, 0, 0);
                    acc[cg] = __builtin_amdgcn_mfma_f32_16x16x32_bf16(eh, bl, acc[cg], 0, 0, 0);
                    acc[cg] = __builtin_amdgcn_mfma_f32_16x16x32_bf16(ah, bh, acc[cg], 0, 0, 0);
                    acc[cg] = __builtin_amdgcn_mfma_f32_16x16x32_bf16(ah, bl, acc[cg], 0, 0, 0);
                    acc[cg] = __builtin_amdgcn_mfma_f32_16x16x32_bf16(al, bh, acc[cg], 0, 0, 0);
                }
            } else {
                short8 mh = *(const short8*)(lds + rowA * 64 + ch);
                short8 ml = *(const short8*)(lds + 1 * 4096 + rowA * 64 + ch);
#pragma unroll
                for (int cg = 0; cg < 4; cg++) {
                    int rowB = cg * 16 + m16;
                    short8 bh = *(const short8*)(lds + 2 * 4096 + rowB * 64 + ch);
                    short8 bl = *(const short8*)(lds + 3 * 4096 + rowB * 64 + ch);
                    acc[cg] = __builtin_amdgcn_mfma_f32_16x16x32_bf16(mh, bh, acc[cg], 0, 0, 0);
                    acc[cg] = __builtin_amdgcn_mfma_f32_16x16x32_bf16(mh, bl, acc[cg], 0, 0, 0);
                    acc[cg] = __builtin_amdgcn_mfma_f32_16x16x32_bf16(ml, bh, acc[cg], 0, 0, 0);
                }
            }
        }
    }

    if (modeF) {
        // phase B: += x_rows @ What2  (one K=64 step; What2 symmetric)
        __syncthreads();
        if (wave < 2) {
            int r  = wave * 32 + (lane >> 1);
            int qh = (lane & 1) * 32;
            const float* xrow = xc + ((size_t)bc * N_ + i0 + r) * D_ + qh;
#pragma unroll
            for (int cc = 0; cc < 4; cc++) {
                float4 v0 = *(const float4*)(xrow + cc * 8);
                float4 v1 = *(const float4*)(xrow + cc * 8 + 4);
                float vv[8] = {v0.x, v0.y, v0.z, v0.w, v1.x, v1.y, v1.z, v1.w};
                short8 hh, ll;
#pragma unroll
                for (int e = 0; e < 8; e++) {
                    unsigned short h = f2b(vv[e]);
                    hh[e] = (short)h;
                    ll[e] = (short)f2b(vv[e] - b2f(h));
                }
                int c   = (qh >> 3) + cc;
                int pos = (c ^ (r & 7)) * 8;
                *(short8*)(lds + r * 64 + pos) = hh;
                *(short8*)(lds + 4096 + r * 64 + pos) = ll;
            }
        } else {
            const unsigned short* gsrc = (wave == 2) ? W2h : W2l;
            unsigned short* ldst = lds + wave * 4096;   // wave2->buf2, wave3->buf3
#pragma unroll
            for (int rg = 0; rg < 8; rg++) {
                const unsigned short* gp = gsrc + (size_t)(rg * 8 + r_sub) * 64 + gc * 8;
                GLD16(gp, ldst + rg * 512);
            }
        }
        __syncthreads();
#pragma unroll
        for (int kc = 0; kc < 2; kc++) {
            const int ch = ((kc * 4 + quad) ^ l7) * 8;
            short8 ah = *(const short8*)(lds + rowA * 64 + ch);
            short8 al = *(const short8*)(lds + 4096 + rowA * 64 + ch);
#pragma unroll
            for (int cg = 0; cg < 4; cg++) {
                int rowB = cg * 16 + m16;
                short8 bh = *(const short8*)(lds + 2 * 4096 + rowB * 64 + ch);
                short8 bl = *(const short8*)(lds + 3 * 4096 + rowB * 64 + ch);
                acc[cg] = __builtin_amdgcn_mfma_f32_16x16x32_bf16(ah, bh, acc[cg], 0, 0, 0);
                acc[cg] = __builtin_amdgcn_mfma_f32_16x16x32_bf16(ah, bl, acc[cg], 0, 0, 0);
                acc[cg] = __builtin_amdgcn_mfma_f32_16x16x32_bf16(al, bh, acc[cg], 0, 0, 0);
            }
        }
    }

    float cbv = modeF ? cb[0] : 0.f;
    float* outp = modeF ? outf : outg;
#pragma unroll
    for (int cg = 0; cg < 4; cg++) {
#pragma unroll
        for (int r = 0; r < 4; r++) {
            int row = i0 + wave * 16 + quad * 4 + r;
            int col = cg * 16 + m16;
            float v = acc[cg][r];
            if (modeF)
                v += x0c[((size_t)bc * N_ + row) * D_ + col] * sa[row] + cbv;
            outp[((size_t)bc * N_ + row) * D_ + col] = tanhf(v);
        }
    }
}

// ---------------------------------------------------------------- host
extern "C" void kernel_launch(void* const* d_in, const int* in_sizes, int n_in,
                              void* d_out, int out_size, void* d_ws, size_t ws_size,
                              hipStream_t stream)
{
    const float* x     = (const float*)d_in[0];
    const float* x0    = (const float*)d_in[1];
    const float* w     = (const float*)d_in[2];
    const float* dvec  = (const float*)d_in[3];
    const float* alpha = (const float*)d_in[4];
    const float* fw1   = (const float*)d_in[5];
    const float* fw2   = (const float*)d_in[6];
    const float* fvs   = (const float*)d_in[7];
    const float* fbs   = (const float*)d_in[8];
    const float* gw1   = (const float*)d_in[9];
    const float* gw2   = (const float*)d_in[10];
    const float* gvs   = (const float*)d_in[11];
    const float* gbs   = (const float*)d_in[12];
    const float* cw    = (const float*)d_in[13];
    const float* cb    = (const float*)d_in[14];
    const float* adj   = (const float*)d_in[15];

    float* outf = (float*)d_out;
    float* outg = outf + (size_t)B_ * N_ * D_;

    char* p = (char*)d_ws;
    auto alloc = [&](size_t bytes) { void* r = p; p += (bytes + 255) & ~(size_t)255; return r; };

    float* e1f = (float*)alloc(B_ * N_ * 4);
    float* e2f = (float*)alloc(B_ * N_ * 4);
    float* e1g = (float*)alloc(B_ * N_ * 4);
    float* e2g = (float*)alloc(B_ * N_ * 4);
    float* sa  = (float*)alloc(N_ * 4);
    unsigned short* W2h = (unsigned short*)alloc(D_ * D_ * 2);
    unsigned short* W2l = (unsigned short*)alloc(D_ * D_ * 2);
    unsigned short* AmixH = (unsigned short*)alloc((size_t)N_ * N_ * 2);
    unsigned short* AmixL = (unsigned short*)alloc((size_t)N_ * N_ * 2);
    unsigned short* AHf = (unsigned short*)alloc((size_t)N_ * N_ * 2);
    unsigned short* ALf = (unsigned short*)alloc((size_t)N_ * N_ * 2);
    unsigned short* AHg = (unsigned short*)alloc((size_t)N_ * N_ * 2);
    unsigned short* ALg = (unsigned short*)alloc((size_t)N_ * N_ * 2);
    unsigned short* XTh = (unsigned short*)alloc((size_t)BCH * D_ * N_ * 2);
    unsigned short* XTl = (unsigned short*)alloc((size_t)BCH * D_ * N_ * 2);
    unsigned short* SHf = (unsigned short*)alloc((size_t)BCH * N_ * N_ * 2);
    unsigned short* SLf = (unsigned short*)alloc((size_t)BCH * N_ * N_ * 2);
    unsigned short* SHg = (unsigned short*)alloc((size_t)BCH * N_ * N_ * 2);
    unsigned short* SLg = (unsigned short*)alloc((size_t)BCH * N_ * N_ * 2);
    unsigned short* LHf = (unsigned short*)alloc((size_t)BCH * N_ * N_ * 2);
    unsigned short* LLf = (unsigned short*)alloc((size_t)BCH * N_ * N_ * 2);
    unsigned short* LHg = (unsigned short*)alloc((size_t)BCH * N_ * N_ * 2);
    unsigned short* LLg = (unsigned short*)alloc((size_t)BCH * N_ * N_ * 2);
    // E (hi only) aliases the (dead after gemm2) f S-hi buffer
    unsigned short* EH = SHf;
    (void)ws_size; (void)in_sizes; (void)n_in; (void)out_size;

    k_dots<<<dim3((B_ * N_) / 256), 256, 0, stream>>>(x, fw1, fw2, gw1, gw2, alpha,
                                                      e1f, e2f, e1g, e2g, sa);
    k_what2_split<<<dim3(16), 256, 0, stream>>>(w, dvec, W2h, W2l);
    k_amix_split<<<dim3(N_ * N_ / 256), 256, 0, stream>>>(adj, cw, AmixH, AmixL);
    k_asplit<<<dim3(N_ * N_ / 1024), 256, 0, stream>>>(fvs, AHf, ALf);
    k_asplit<<<dim3(N_ * N_ / 1024), 256, 0, stream>>>(gvs, AHg, ALg);

    for (int c = 0; c < B_ / BCH; c++) {
        int boff = c * BCH;
        const float* xc  = x  + (size_t)boff * N_ * D_;
        const float* x0c = x0 + (size_t)boff * N_ * D_;
        k_xt_split<<<dim3(16, BCH), 256, 0, stream>>>(xc, XTh, XTl);
        k_sigsplit2<<<dim3(16, 16, BCH * 2), 256, 0, stream>>>(
            fbs, gbs, e1f + boff * N_, e2f + boff * N_,
            e1g + boff * N_, e2g + boff * N_, SHf, SLf, SHg, SLg);
        k_gemm2<<<dim3(64, BCH, 2), 256, 0, stream>>>(
            AHf, ALf, AHg, ALg, SHf, SLf, SHg, SLg, LHf, LLf, LHg, LLg);
        k_softmax2<<<dim3(BCH * N_), 256, 0, stream>>>(LHf, LLf, LHg, LLg, EH);
        k_out_mfma<<<dim3(16, BCH, 2), 256, 0, stream>>>(
            EH, LHg, LLg, AmixH, AmixL, XTh, XTl, W2h, W2l,
            xc, x0c, sa, cb,
            outf + (size_t)boff * N_ * D_, outg + (size_t)boff * N_ * D_);
    }
}

// Round 7
// 640.785 us; speedup vs baseline: 3.9785x; 1.1617x over previous
//
#include <hip/hip_runtime.h>
#include <math.h>

constexpr int B_ = 32;
constexpr int N_ = 1024;
constexpr int D_ = 64;
constexpr int BCH = 8;   // batch chunk; workspace ~125 MB

typedef short short8 __attribute__((ext_vector_type(8)));   // 8 bf16 (4 VGPRs)
typedef float f32x4 __attribute__((ext_vector_type(4)));    // f32 MFMA accumulator
typedef int   int4_ __attribute__((ext_vector_type(4)));    // 16 i8 operand / i32x4 acc

__device__ __forceinline__ float sigf(float v) {
    return 1.0f / (1.0f + __expf(-v));
}
__device__ __forceinline__ unsigned short f2b(float f) {   // fp32 -> bf16 RNE
    unsigned u = __float_as_uint(f);
    unsigned r = u + 0x7fffu + ((u >> 16) & 1u);
    return (unsigned short)(r >> 16);
}
__device__ __forceinline__ float b2f(unsigned int h) {
    return __uint_as_float(h << 16);
}
__device__ __forceinline__ unsigned pack4(int a, int b, int c, int d) {
    return (unsigned)(a & 255) | ((unsigned)(b & 255) << 8) |
           ((unsigned)(c & 255) << 16) | ((unsigned)(d & 255) << 24);
}

#define GLD16(gp, lp)                                                        \
    __builtin_amdgcn_global_load_lds(                                        \
        (const __attribute__((address_space(1))) unsigned int*)(const void*)(gp), \
        (__attribute__((address_space(3))) unsigned int*)(void*)(lp), 16, 0, 0)

// ---------------------------------------------------------------- k_dots
__global__ void k_dots(const float* __restrict__ x,
                       const float* __restrict__ fw1, const float* __restrict__ fw2,
                       const float* __restrict__ gw1, const float* __restrict__ gw2,
                       const float* __restrict__ alpha,
                       float* __restrict__ e1f, float* __restrict__ e2f,
                       float* __restrict__ e1g, float* __restrict__ e2g,
                       float* __restrict__ sa)
{
    int t = blockIdx.x * blockDim.x + threadIdx.x;
    if (t < N_) sa[t] = sigf(alpha[t]);
    if (t >= B_ * N_) return;
    const float* xr = x + (size_t)t * D_;
    float s1 = 0.f, s2 = 0.f, s3 = 0.f, s4 = 0.f;
#pragma unroll 8
    for (int d = 0; d < D_; d++) {
        float v = xr[d];
        s1 += v * fw1[d];
        s2 += v * fw2[d];
        s3 += v * gw1[d];
        s4 += v * gw2[d];
    }
    e1f[t] = s1; e2f[t] = s2; e1g[t] = s3; e2g[t] = s4;
}

// ---------------------------------------------------------------- k_what2_split
__global__ void k_what2_split(const float* __restrict__ w, const float* __restrict__ dvec,
                              unsigned short* __restrict__ W2h, unsigned short* __restrict__ W2l)
{
    int t = blockIdx.x * blockDim.x + threadIdx.x;
    if (t >= D_ * D_) return;
    int i = t / D_, j = t % D_;
    float s = 0.f;
    for (int q = 0; q < D_; q++) {
        float dc = fminf(fmaxf(dvec[q], 0.0f), 1.0f);
        s += w[i * D_ + q] * dc * w[j * D_ + q];
    }
    if (i == j) s -= 2.0f;
    unsigned short h = f2b(s);
    W2h[t] = h;
    W2l[t] = f2b(s - b2f(h));
}

// ---------------------------------------------------------------- k_amix_split
__global__ void k_amix_split(const float* __restrict__ adj, const float* __restrict__ cw,
                             unsigned short* __restrict__ AmixH, unsigned short* __restrict__ AmixL)
{
    int t = blockIdx.x * blockDim.x + threadIdx.x;
    if (t >= N_ * N_) return;
    int i = t >> 10, j = t & (N_ - 1);
    float c0 = cw[0], c1 = cw[1];
    float v = c0 * adj[t] + c1 * adj[(size_t)N_ * N_ + t];
    if (i == j) v -= (c0 + c1);
    unsigned short h = f2b(v);
    AmixH[t] = h;
    AmixL[t] = f2b(v - b2f(h));
}

// ---------------------------------------------------------------- k_zinit / k_amax / k_aquant
__global__ void k_zinit(unsigned* __restrict__ amaxbits)
{
    if (threadIdx.x < 2) amaxbits[threadIdx.x] = 0;
}

// max |vs| per fg, via atomicMax on positive-float bits
__global__ void k_amax(const float* __restrict__ fvs, const float* __restrict__ gvs,
                       unsigned* __restrict__ amaxbits)
{
    int fg = blockIdx.y;
    const float* src = fg ? gvs : fvs;
    int t = threadIdx.x;
    size_t base = ((size_t)blockIdx.x * 256 + t) * 16;
    float m = 0.f;
#pragma unroll
    for (int q = 0; q < 4; q++) {
        float4 v = *(const float4*)(src + base + q * 4);
        m = fmaxf(m, fmaxf(fmaxf(fabsf(v.x), fabsf(v.y)), fmaxf(fabsf(v.z), fabsf(v.w))));
    }
#pragma unroll
    for (int o = 32; o > 0; o >>= 1) m = fmaxf(m, __shfl_xor(m, o, 64));
    __shared__ float red[4];
    if ((t & 63) == 0) red[t >> 6] = m;
    __syncthreads();
    if (t == 0) {
        m = fmaxf(fmaxf(red[0], red[1]), fmaxf(red[2], red[3]));
        atomicMax(&amaxbits[fg], __float_as_uint(m));
    }
}

// quantize vs to 16-bit fixed point, split into i8 hi/lo planes; per-row sum of q
__launch_bounds__(256)
__global__ void k_aquant(const float* __restrict__ fvs, const float* __restrict__ gvs,
                         const float* __restrict__ amaxf,
                         signed char* __restrict__ AHf, signed char* __restrict__ ALf,
                         signed char* __restrict__ AHg, signed char* __restrict__ ALg,
                         float* __restrict__ rsumf, float* __restrict__ rsumg)
{
    int row = blockIdx.x;
    int fg  = blockIdx.y;
    const float* src = fg ? gvs : fvs;
    signed char* hp = fg ? AHg : AHf;
    signed char* lp = fg ? ALg : ALf;
    float* rs = fg ? rsumg : rsumf;
    float inv = 32512.f / amaxf[fg];
    int t = threadIdx.x;
    int j = t * 4;
    float4 v = *(const float4*)(src + (size_t)row * N_ + j);
    float a[4] = {v.x, v.y, v.z, v.w};
    int qh[4], ql[4], s = 0;
#pragma unroll
    for (int e = 0; e < 4; e++) {
        int q = __float2int_rn(a[e] * inv);
        q = min(max(q, -32512), 32512);
        int h = (q + 128) >> 8;
        qh[e] = h;
        ql[e] = q - (h << 8);
        s += q;
    }
    *(unsigned*)(hp + (size_t)row * N_ + j) = pack4(qh[0], qh[1], qh[2], qh[3]);
    *(unsigned*)(lp + (size_t)row * N_ + j) = pack4(ql[0], ql[1], ql[2], ql[3]);
#pragma unroll
    for (int o = 32; o > 0; o >>= 1) s += __shfl_xor(s, o, 64);
    __shared__ int red[4];
    if ((t & 63) == 0) red[t >> 6] = s;
    __syncthreads();
    if (t == 0) rs[row] = (float)(red[0] + red[1] + red[2] + red[3]);
}

// ---------------------------------------------------------------- k_xt_split
__launch_bounds__(256)
__global__ void k_xt_split(const float* __restrict__ xc,
                           unsigned short* __restrict__ XTh, unsigned short* __restrict__ XTl)
{
    int j0 = blockIdx.x * 64;
    int bc = blockIdx.y;
    int t  = threadIdx.x;
    __shared__ float S_l[64][65];
    {
        int j = t >> 2, dc = (t & 3) * 16;
        const float* src = xc + ((size_t)bc * N_ + j0 + j) * D_ + dc;
#pragma unroll
        for (int q = 0; q < 4; q++) {
            float4 v = *(const float4*)(src + q * 4);
            S_l[j][dc + q * 4 + 0] = v.x;
            S_l[j][dc + q * 4 + 1] = v.y;
            S_l[j][dc + q * 4 + 2] = v.z;
            S_l[j][dc + q * 4 + 3] = v.w;
        }
    }
    __syncthreads();
    {
        int d = t >> 2, jc = (t & 3) * 16;
        unsigned short hs[16], ls[16];
#pragma unroll
        for (int u = 0; u < 16; u++) {
            float v = S_l[jc + u][d];
            hs[u] = f2b(v);
            ls[u] = f2b(v - b2f(hs[u]));
        }
        uint4 hv0, hv1, lv0, lv1;
        hv0.x = hs[0] | (hs[1] << 16);  hv0.y = hs[2] | (hs[3] << 16);
        hv0.z = hs[4] | (hs[5] << 16);  hv0.w = hs[6] | (hs[7] << 16);
        hv1.x = hs[8] | (hs[9] << 16);  hv1.y = hs[10] | (hs[11] << 16);
        hv1.z = hs[12] | (hs[13] << 16); hv1.w = hs[14] | (hs[15] << 16);
        lv0.x = ls[0] | (ls[1] << 16);  lv0.y = ls[2] | (ls[3] << 16);
        lv0.z = ls[4] | (ls[5] << 16);  lv0.w = ls[6] | (ls[7] << 16);
        lv1.x = ls[8] | (ls[9] << 16);  lv1.y = ls[10] | (ls[11] << 16);
        lv1.z = ls[12] | (ls[13] << 16); lv1.w = ls[14] | (ls[15] << 16);
        size_t base = ((size_t)bc * D_ + d) * N_ + j0 + jc;
        *(uint4*)(XTh + base) = hv0;  *(uint4*)(XTh + base + 8) = hv1;
        *(uint4*)(XTl + base) = lv0;  *(uint4*)(XTl + base + 8) = lv1;
    }
}

// ---------------------------------------------------------------- k_sigsplit2
// S^T[b][k][j]: 16-bit fixed-point sigmoid, split i8 hi/lo planes.
__launch_bounds__(256)
__global__ void k_sigsplit2(const float* __restrict__ fbs, const float* __restrict__ gbs,
                            const float* __restrict__ e1f_, const float* __restrict__ e2f_,
                            const float* __restrict__ e1g_, const float* __restrict__ e2g_,
                            signed char* __restrict__ SHf, signed char* __restrict__ SLf,
                            signed char* __restrict__ SHg, signed char* __restrict__ SLg)
{
    int j0 = blockIdx.x * 64;
    int k0 = blockIdx.y * 64;
    int z  = blockIdx.z;
    int b  = z & (BCH - 1);
    int fg = z >> 3;                      // BCH == 8
    const float* bs = fg ? gbs : fbs;
    const float* e1 = fg ? e1g_ : e1f_;
    const float* e2 = fg ? e2g_ : e2f_;
    signed char* SH = fg ? SHg : SHf;
    signed char* SL = fg ? SLg : SLf;
    int t  = threadIdx.x;
    __shared__ float S_l[64][65];
    {
        int j  = t >> 2;
        int kc = (t & 3) * 16;
        float e1v = e1[(size_t)b * N_ + j0 + j];
#pragma unroll
        for (int q = 0; q < 4; q++) {
            float4 bsv = *(const float4*)(bs + (size_t)(j0 + j) * N_ + k0 + kc + q * 4);
            float4 e2v = *(const float4*)(e2 + (size_t)b * N_ + k0 + kc + q * 4);
            S_l[j][kc + q * 4 + 0] = sigf(fmaf(e1v, e2v.x, bsv.x));
            S_l[j][kc + q * 4 + 1] = sigf(fmaf(e1v, e2v.y, bsv.y));
            S_l[j][kc + q * 4 + 2] = sigf(fmaf(e1v, e2v.z, bsv.z));
            S_l[j][kc + q * 4 + 3] = sigf(fmaf(e1v, e2v.w, bsv.w));
        }
    }
    __syncthreads();
    {
        int k  = t >> 2;
        int jc = (t & 3) * 16;
        int hh[16], ll[16];
#pragma unroll
        for (int u = 0; u < 16; u++) {
            float v = S_l[jc + u][k];
            int q = __float2int_rn(v * 65024.f) - 32512;
            q = min(max(q, -32512), 32512);
            int h = (q + 128) >> 8;
            hh[u] = h;
            ll[u] = q - (h << 8);
        }
        uint4 H, L;
        H.x = pack4(hh[0], hh[1], hh[2], hh[3]);   H.y = pack4(hh[4], hh[5], hh[6], hh[7]);
        H.z = pack4(hh[8], hh[9], hh[10], hh[11]); H.w = pack4(hh[12], hh[13], hh[14], hh[15]);
        L.x = pack4(ll[0], ll[1], ll[2], ll[3]);   L.y = pack4(ll[4], ll[5], ll[6], ll[7]);
        L.z = pack4(ll[8], ll[9], ll[10], ll[11]); L.w = pack4(ll[12], ll[13], ll[14], ll[15]);
        size_t base = (size_t)(b * N_ + k0 + k) * N_ + j0 + jc;
        *(uint4*)(SH + base) = H;
        *(uint4*)(SL + base) = L;
    }
}

// ---------------------------------------------------------------- k_gemm2i
// logit[b][i][k] = sA/65024 * (65536*M + 256*C + 32512*rsumA[i])
// M = sum ah*sh, C = sum (ah*sl + al*sh) via i8 MFMA (i32 exact accumulation).
__launch_bounds__(256, 2)
__global__ void k_gemm2i(const signed char* __restrict__ AHf, const signed char* __restrict__ ALf,
                         const signed char* __restrict__ AHg, const signed char* __restrict__ ALg,
                         const signed char* __restrict__ SHf, const signed char* __restrict__ SLf,
                         const signed char* __restrict__ SHg, const signed char* __restrict__ SLg,
                         const float* __restrict__ rsumf, const float* __restrict__ rsumg,
                         const float* __restrict__ amaxf,
                         unsigned short* __restrict__ LHf, unsigned short* __restrict__ LLf,
                         unsigned short* __restrict__ LHg, unsigned short* __restrict__ LLg)
{
    const int fg = blockIdx.z;
    const signed char* AH = fg ? AHg : AHf;
    const signed char* AL = fg ? ALg : ALf;
    const signed char* SH = fg ? SHg : SHf;
    const signed char* SL = fg ? SLg : SLf;
    const float* rsum = fg ? rsumg : rsumf;
    unsigned short* LHo = fg ? LHg : LHf;
    unsigned short* LLo = fg ? LLg : LLf;
    const float scale = amaxf[fg] * (1.0f / (32512.f * 65024.f));

    const int b  = blockIdx.y;
    const int i0 = (blockIdx.x >> 3) * 128;
    const int k0 = (blockIdx.x & 7) * 128;
    const int t    = threadIdx.x;
    const int lane = t & 63;
    const int wave = t >> 6;
    const int wr   = wave >> 1;
    const int wc   = wave & 1;
    const int quad = lane >> 4;
    const int m16  = lane & 15;

    __shared__ __align__(16) signed char lds[32768];   // 4 tiles x 128 rows x 64 i8
    signed char* AHl = lds;
    signed char* ALl = lds + 8192;
    signed char* BHl = lds + 16384;
    signed char* BLl = lds + 24576;

    const signed char* gsrc;
    signed char* ldst;
    int rowbase;
    if (wave == 0)      { gsrc = AH; ldst = AHl; rowbase = i0; }
    else if (wave == 1) { gsrc = AL; ldst = ALl; rowbase = i0; }
    else if (wave == 2) { gsrc = SH; ldst = BHl; rowbase = b * N_ + k0; }
    else                { gsrc = SL; ldst = BLl; rowbase = b * N_ + k0; }

    int4_ accm[4][4], accc[4][4];
#pragma unroll
    for (int mi = 0; mi < 4; mi++)
#pragma unroll
        for (int ni = 0; ni < 4; ni++) {
            accm[mi][ni] = (int4_){0, 0, 0, 0};
            accc[mi][ni] = (int4_){0, 0, 0, 0};
        }

    // staging decomposition: lane = rr*4 + cc over a 16-row group; global chunk
    // swizzled by (rr>>1)&3 so reads spread over bank groups.
    const int rr = lane >> 2;
    const int cc = lane & 3;
    const int gcq = cc ^ ((rr >> 1) & 3);
    const int rpos = (quad ^ ((m16 >> 1) & 3)) * 16;   // reader chunk position

    for (int step = 0; step < 16; step++) {
        const int jb = step * 64;
        __syncthreads();
#pragma unroll
        for (int it = 0; it < 8; it++) {
            int r = it * 16 + rr;
            const signed char* gp = gsrc + (size_t)(rowbase + r) * N_ + jb + gcq * 16;
            GLD16(gp, ldst + it * 1024);
        }
        __syncthreads();

        int4_ ah[4], al[4];
#pragma unroll
        for (int mi = 0; mi < 4; mi++) {
            int row = wr * 64 + mi * 16 + m16;
            ah[mi] = *(const int4_*)(AHl + row * 64 + rpos);
            al[mi] = *(const int4_*)(ALl + row * 64 + rpos);
        }
#pragma unroll
        for (int ni = 0; ni < 4; ni++) {
            int row = wc * 64 + ni * 16 + m16;
            int4_ bh = *(const int4_*)(BHl + row * 64 + rpos);
            int4_ bl = *(const int4_*)(BLl + row * 64 + rpos);
#pragma unroll
            for (int mi = 0; mi < 4; mi++) {
                accm[mi][ni] = __builtin_amdgcn_mfma_i32_16x16x64_i8(
                    ah[mi], bh, accm[mi][ni], 0, 0, 0);
                accc[mi][ni] = __builtin_amdgcn_mfma_i32_16x16x64_i8(
                    ah[mi], bl, accc[mi][ni], 0, 0, 0);
                accc[mi][ni] = __builtin_amdgcn_mfma_i32_16x16x64_i8(
                    al[mi], bh, accc[mi][ni], 0, 0, 0);
            }
        }
    }

#pragma unroll
    for (int mi = 0; mi < 4; mi++)
#pragma unroll
        for (int ni = 0; ni < 4; ni++) {
            int row = i0 + wr * 64 + mi * 16 + quad * 4;
            int col = k0 + wc * 64 + ni * 16 + m16;
            size_t base = ((size_t)b * N_ + row) * N_ + col;
#pragma unroll
            for (int r = 0; r < 4; r++) {
                float v = (65536.f * (float)accm[mi][ni][r] +
                           256.f * (float)accc[mi][ni][r] +
                           32512.f * rsum[row + r]) * scale;
                unsigned short h = f2b(v);
                LHo[base + (size_t)r * N_] = h;
                LLo[base + (size_t)r * N_] = f2b(v - b2f(h));
            }
        }
}

// ---------------------------------------------------------------- k_softmax2
__launch_bounds__(256)
__global__ void k_softmax2(const unsigned short* __restrict__ LHf,
                           const unsigned short* __restrict__ LLf,
                           unsigned short* GH, unsigned short* GL,
                           unsigned short* __restrict__ EH)
{
    size_t row = blockIdx.x;
    int t = threadIdx.x;
    size_t base = row * N_ + (size_t)t * 4;
    __shared__ float red1[4], red2[4], red3[4], red4[4];

    uint2 h2 = *(const uint2*)(LHf + base);
    uint2 l2 = *(const uint2*)(LLf + base);
    float v[4];
    v[0] = b2f(h2.x & 0xffff) + b2f(l2.x & 0xffff);
    v[1] = b2f(h2.x >> 16)    + b2f(l2.x >> 16);
    v[2] = b2f(h2.y & 0xffff) + b2f(l2.y & 0xffff);
    v[3] = b2f(h2.y >> 16)    + b2f(l2.y >> 16);
    float m = fmaxf(fmaxf(v[0], v[1]), fmaxf(v[2], v[3]));
#pragma unroll
    for (int o = 32; o > 0; o >>= 1) m = fmaxf(m, __shfl_xor(m, o, 64));
    if ((t & 63) == 0) red1[t >> 6] = m;
    uint2 gh2 = *(const uint2*)(GH + base);
    uint2 gl2 = *(const uint2*)(GL + base);
    float gv[4];
    gv[0] = b2f(gh2.x & 0xffff) + b2f(gl2.x & 0xffff);
    gv[1] = b2f(gh2.x >> 16)    + b2f(gl2.x >> 16);
    gv[2] = b2f(gh2.y & 0xffff) + b2f(gl2.y & 0xffff);
    gv[3] = b2f(gh2.y >> 16)    + b2f(gl2.y >> 16);
    float gm = fmaxf(fmaxf(gv[0], gv[1]), fmaxf(gv[2], gv[3]));
#pragma unroll
    for (int o = 32; o > 0; o >>= 1) gm = fmaxf(gm, __shfl_xor(gm, o, 64));
    if ((t & 63) == 0) red2[t >> 6] = gm;
    __syncthreads();
    m  = fmaxf(fmaxf(red1[0], red1[1]), fmaxf(red1[2], red1[3]));
    gm = fmaxf(fmaxf(red2[0], red2[1]), fmaxf(red2[2], red2[3]));
    float ex[4]  = {__expf(v[0] - m),  __expf(v[1] - m),  __expf(v[2] - m),  __expf(v[3] - m)};
    float gex[4] = {__expf(gv[0] - gm), __expf(gv[1] - gm), __expf(gv[2] - gm), __expf(gv[3] - gm)};
    float s  = ex[0] + ex[1] + ex[2] + ex[3];
    float gs = gex[0] + gex[1] + gex[2] + gex[3];
#pragma unroll
    for (int o = 32; o > 0; o >>= 1) { s += __shfl_xor(s, o, 64); gs += __shfl_xor(gs, o, 64); }
    if ((t & 63) == 0) { red3[t >> 6] = s; red4[t >> 6] = gs; }
    __syncthreads();
    s  = red3[0] + red3[1] + red3[2] + red3[3];
    gs = red4[0] + red4[1] + red4[2] + red4[3];
    float inv  = 1.0f / s;
    float ginv = 1.0f / gs;

    unsigned short ehs[4], hs[4], ls[4];
#pragma unroll
    for (int e = 0; e < 4; e++) {
        float E = ex[e] * inv;
        ehs[e] = f2b(E);
        float nh = gex[e] * ginv / (E + 1e-5f);
        hs[e] = f2b(nh);
        ls[e] = f2b(nh - b2f(hs[e]));
    }
    uint2 eo, ho, lo;
    eo.x = (unsigned)ehs[0] | ((unsigned)ehs[1] << 16);
    eo.y = (unsigned)ehs[2] | ((unsigned)ehs[3] << 16);
    ho.x = (unsigned)hs[0] | ((unsigned)hs[1] << 16);
    ho.y = (unsigned)hs[2] | ((unsigned)hs[3] << 16);
    lo.x = (unsigned)ls[0] | ((unsigned)ls[1] << 16);
    lo.y = (unsigned)ls[2] | ((unsigned)ls[3] << 16);
    *(uint2*)(EH + base) = eo;
    *(uint2*)(GH + base) = ho;
    *(uint2*)(GL + base) = lo;
}

// ---------------------------------------------------------------- k_out_mfma
__launch_bounds__(256, 2)
__global__ void k_out_mfma(
    const unsigned short* __restrict__ EH,
    const unsigned short* __restrict__ NH, const unsigned short* __restrict__ NL,
    const unsigned short* __restrict__ AmixH, const unsigned short* __restrict__ AmixL,
    const unsigned short* __restrict__ XTh, const unsigned short* __restrict__ XTl,
    const unsigned short* __restrict__ W2h, const unsigned short* __restrict__ W2l,
    const float* __restrict__ xc, const float* __restrict__ x0c,
    const float* __restrict__ sa, const float* __restrict__ cb,
    float* __restrict__ outf, float* __restrict__ outg)
{
    const int i0    = blockIdx.x * 64;
    const int bc    = blockIdx.y;
    const bool modeF = (blockIdx.z == 0);
    const int t     = threadIdx.x;
    const int lane  = t & 63;
    const int wave  = t >> 6;
    const int quad  = lane >> 4;
    const int m16   = lane & 15;
    const int l7    = lane & 7;
    const int r_sub = lane >> 3;
    const int gc    = l7 ^ r_sub;

    __shared__ __align__(16) unsigned short lds[5 * 4096];   // 40 KB

    const unsigned short* sb[5];
    int nbuf;
    if (modeF) {
        sb[0] = EH + ((size_t)bc * N_ + i0) * N_;
        sb[1] = XTh + (size_t)bc * D_ * N_;
        sb[2] = XTl + (size_t)bc * D_ * N_;
        sb[3] = AmixH + (size_t)i0 * N_;
        sb[4] = AmixL + (size_t)i0 * N_;
        nbuf = 5;
    } else {
        sb[0] = NH + ((size_t)bc * N_ + i0) * N_;
        sb[1] = NL + ((size_t)bc * N_ + i0) * N_;
        sb[2] = XTh + (size_t)bc * D_ * N_;
        sb[3] = XTl + (size_t)bc * D_ * N_;
        nbuf = 4;
    }
    const int per = nbuf * 2;

    f32x4 acc[4];
#pragma unroll
    for (int cg = 0; cg < 4; cg++) acc[cg] = (f32x4){0.f, 0.f, 0.f, 0.f};

    const int rowA = wave * 16 + m16;

    for (int step = 0; step < 16; step++) {
        const int jb = step * 64;
        __syncthreads();
        for (int i = 0; i < per; i++) {
            int gi  = wave * per + i;
            int buf = gi >> 3, rg = gi & 7;
            const unsigned short* gp = sb[buf] + (size_t)(rg * 8 + r_sub) * N_ + jb + gc * 8;
            GLD16(gp, lds + buf * 4096 + rg * 512);
        }
        __syncthreads();
#pragma unroll
        for (int kc = 0; kc < 2; kc++) {
            const int ch = ((kc * 4 + quad) ^ l7) * 8;
            if (modeF) {
                short8 eh = *(const short8*)(lds + rowA * 64 + ch);
                short8 ah = *(const short8*)(lds + 3 * 4096 + rowA * 64 + ch);
                short8 al = *(const short8*)(lds + 4 * 4096 + rowA * 64 + ch);
#pragma unroll
                for (int cg = 0; cg < 4; cg++) {
                    int rowB = cg * 16 + m16;
                    short8 bh = *(const short8*)(lds + 1 * 4096 + rowB * 64 + ch);
                    short8 bl = *(const short8*)(lds + 2 * 4096 + rowB * 64 + ch);
                    acc[cg] = __builtin_amdgcn_mfma_f32_16x16x32_bf16(eh, bh, acc[cg], 0, 0, 0);
                    acc[cg] = __builtin_amdgcn_mfma_f32_16x16x32_bf16(eh, bl, acc[cg], 0, 0, 0);
                    acc[cg] = __builtin_amdgcn_mfma_f32_16x16x32_bf16(ah, bh, acc[cg], 0, 0, 0);
                    acc[cg] = __builtin_amdgcn_mfma_f32_16x16x32_bf16(ah, bl, acc[cg], 0, 0, 0);
                    acc[cg] = __builtin_amdgcn_mfma_f32_16x16x32_bf16(al, bh, acc[cg], 0, 0, 0);
                }
            } else {
                short8 mh = *(const short8*)(lds + rowA * 64 + ch);
                short8 ml = *(const short8*)(lds + 1 * 4096 + rowA * 64 + ch);
#pragma unroll
                for (int cg = 0; cg < 4; cg++) {
                    int rowB = cg * 16 + m16;
                    short8 bh = *(const short8*)(lds + 2 * 4096 + rowB * 64 + ch);
                    short8 bl = *(const short8*)(lds + 3 * 4096 + rowB * 64 + ch);
                    acc[cg] = __builtin_amdgcn_mfma_f32_16x16x32_bf16(mh, bh, acc[cg], 0, 0, 0);
                    acc[cg] = __builtin_amdgcn_mfma_f32_16x16x32_bf16(mh, bl, acc[cg], 0, 0, 0);
                    acc[cg] = __builtin_amdgcn_mfma_f32_16x16x32_bf16(ml, bh, acc[cg], 0, 0, 0);
                }
            }
        }
    }

    if (modeF) {
        __syncthreads();
        if (wave < 2) {
            int r  = wave * 32 + (lane >> 1);
            int qh = (lane & 1) * 32;
            const float* xrow = xc + ((size_t)bc * N_ + i0 + r) * D_ + qh;
#pragma unroll
            for (int cc = 0; cc < 4; cc++) {
                float4 v0 = *(const float4*)(xrow + cc * 8);
                float4 v1 = *(const float4*)(xrow + cc * 8 + 4);
                float vv[8] = {v0.x, v0.y, v0.z, v0.w, v1.x, v1.y, v1.z, v1.w};
                short8 hh, ll;
#pragma unroll
                for (int e = 0; e < 8; e++) {
                    unsigned short h = f2b(vv[e]);
                    hh[e] = (short)h;
                    ll[e] = (short)f2b(vv[e] - b2f(h));
                }
                int c   = (qh >> 3) + cc;
                int pos = (c ^ (r & 7)) * 8;
                *(short8*)(lds + r * 64 + pos) = hh;
                *(short8*)(lds + 4096 + r * 64 + pos) = ll;
            }
        } else {
            const unsigned short* gsrc = (wave == 2) ? W2h : W2l;
            unsigned short* ldst = lds + wave * 4096;
#pragma unroll
            for (int rg = 0; rg < 8; rg++) {
                const unsigned short* gp = gsrc + (size_t)(rg * 8 + r_sub) * 64 + gc * 8;
                GLD16(gp, ldst + rg * 512);
            }
        }
        __syncthreads();
#pragma unroll
        for (int kc = 0; kc < 2; kc++) {
            const int ch = ((kc * 4 + quad) ^ l7) * 8;
            short8 ah = *(const short8*)(lds + rowA * 64 + ch);
            short8 al = *(const short8*)(lds + 4096 + rowA * 64 + ch);
#pragma unroll
            for (int cg = 0; cg < 4; cg++) {
                int rowB = cg * 16 + m16;
                short8 bh = *(const short8*)(lds + 2 * 4096 + rowB * 64 + ch);
                short8 bl = *(const short8*)(lds + 3 * 4096 + rowB * 64 + ch);
                acc[cg] = __builtin_amdgcn_mfma_f32_16x16x32_bf16(ah, bh, acc[cg], 0, 0, 0);
                acc[cg] = __builtin_amdgcn_mfma_f32_16x16x32_bf16(ah, bl, acc[cg], 0, 0, 0);
                acc[cg] = __builtin_amdgcn_mfma_f32_16x16x32_bf16(al, bh, acc[cg], 0, 0, 0);
            }
        }
    }

    float cbv = modeF ? cb[0] : 0.f;
    float* outp = modeF ? outf : outg;
#pragma unroll
    for (int cg = 0; cg < 4; cg++) {
#pragma unroll
        for (int r = 0; r < 4; r++) {
            int row = i0 + wave * 16 + quad * 4 + r;
            int col = cg * 16 + m16;
            float v = acc[cg][r];
            if (modeF)
                v += x0c[((size_t)bc * N_ + row) * D_ + col] * sa[row] + cbv;
            outp[((size_t)bc * N_ + row) * D_ + col] = tanhf(v);
        }
    }
}

// ---------------------------------------------------------------- host
extern "C" void kernel_launch(void* const* d_in, const int* in_sizes, int n_in,
                              void* d_out, int out_size, void* d_ws, size_t ws_size,
                              hipStream_t stream)
{
    const float* x     = (const float*)d_in[0];
    const float* x0    = (const float*)d_in[1];
    const float* w     = (const float*)d_in[2];
    const float* dvec  = (const float*)d_in[3];
    const float* alpha = (const float*)d_in[4];
    const float* fw1   = (const float*)d_in[5];
    const float* fw2   = (const float*)d_in[6];
    const float* fvs   = (const float*)d_in[7];
    const float* fbs   = (const float*)d_in[8];
    const float* gw1   = (const float*)d_in[9];
    const float* gw2   = (const float*)d_in[10];
    const float* gvs   = (const float*)d_in[11];
    const float* gbs   = (const float*)d_in[12];
    const float* cw    = (const float*)d_in[13];
    const float* cb    = (const float*)d_in[14];
    const float* adj   = (const float*)d_in[15];

    float* outf = (float*)d_out;
    float* outg = outf + (size_t)B_ * N_ * D_;

    char* p = (char*)d_ws;
    auto alloc = [&](size_t bytes) { void* r = p; p += (bytes + 255) & ~(size_t)255; return r; };

    float* e1f = (float*)alloc(B_ * N_ * 4);
    float* e2f = (float*)alloc(B_ * N_ * 4);
    float* e1g = (float*)alloc(B_ * N_ * 4);
    float* e2g = (float*)alloc(B_ * N_ * 4);
    float* sa  = (float*)alloc(N_ * 4);
    unsigned short* W2h = (unsigned short*)alloc(D_ * D_ * 2);
    unsigned short* W2l = (unsigned short*)alloc(D_ * D_ * 2);
    float* amaxf = (float*)alloc(2 * 4);
    float* rsumf = (float*)alloc(N_ * 4);
    float* rsumg = (float*)alloc(N_ * 4);
    unsigned short* AmixH = (unsigned short*)alloc((size_t)N_ * N_ * 2);
    unsigned short* AmixL = (unsigned short*)alloc((size_t)N_ * N_ * 2);
    signed char* AHf = (signed char*)alloc((size_t)N_ * N_);
    signed char* ALf = (signed char*)alloc((size_t)N_ * N_);
    signed char* AHg = (signed char*)alloc((size_t)N_ * N_);
    signed char* ALg = (signed char*)alloc((size_t)N_ * N_);
    unsigned short* XTh = (unsigned short*)alloc((size_t)BCH * D_ * N_ * 2);
    unsigned short* XTl = (unsigned short*)alloc((size_t)BCH * D_ * N_ * 2);
    signed char* SHf = (signed char*)alloc((size_t)BCH * N_ * N_);
    signed char* SLf = (signed char*)alloc((size_t)BCH * N_ * N_);
    signed char* SHg = (signed char*)alloc((size_t)BCH * N_ * N_);
    signed char* SLg = (signed char*)alloc((size_t)BCH * N_ * N_);
    unsigned short* LHf = (unsigned short*)alloc((size_t)BCH * N_ * N_ * 2);
    unsigned short* LLf = (unsigned short*)alloc((size_t)BCH * N_ * N_ * 2);
    unsigned short* LHg = (unsigned short*)alloc((size_t)BCH * N_ * N_ * 2);
    unsigned short* LLg = (unsigned short*)alloc((size_t)BCH * N_ * N_ * 2);
    unsigned short* EH  = (unsigned short*)alloc((size_t)BCH * N_ * N_ * 2);
    (void)ws_size; (void)in_sizes; (void)n_in; (void)out_size;

    k_zinit<<<dim3(1), 64, 0, stream>>>((unsigned*)amaxf);
    k_amax<<<dim3(256, 2), 256, 0, stream>>>(fvs, gvs, (unsigned*)amaxf);
    k_aquant<<<dim3(1024, 2), 256, 0, stream>>>(fvs, gvs, amaxf,
                                                AHf, ALf, AHg, ALg, rsumf, rsumg);
    k_dots<<<dim3((B_ * N_) / 256), 256, 0, stream>>>(x, fw1, fw2, gw1, gw2, alpha,
                                                      e1f, e2f, e1g, e2g, sa);
    k_what2_split<<<dim3(16), 256, 0, stream>>>(w, dvec, W2h, W2l);
    k_amix_split<<<dim3(N_ * N_ / 256), 256, 0, stream>>>(adj, cw, AmixH, AmixL);

    for (int c = 0; c < B_ / BCH; c++) {
        int boff = c * BCH;
        const float* xc  = x  + (size_t)boff * N_ * D_;
        const float* x0c = x0 + (size_t)boff * N_ * D_;
        k_xt_split<<<dim3(16, BCH), 256, 0, stream>>>(xc, XTh, XTl);
        k_sigsplit2<<<dim3(16, 16, BCH * 2), 256, 0, stream>>>(
            fbs, gbs, e1f + boff * N_, e2f + boff * N_,
            e1g + boff * N_, e2g + boff * N_, SHf, SLf, SHg, SLg);
        k_gemm2i<<<dim3(64, BCH, 2), 256, 0, stream>>>(
            AHf, ALf, AHg, ALg, SHf, SLf, SHg, SLg, rsumf, rsumg, amaxf,
            LHf, LLf, LHg, LLg);
        k_softmax2<<<dim3(BCH * N_), 256, 0, stream>>>(LHf, LLf, LHg, LLg, EH);
        k_out_mfma<<<dim3(16, BCH, 2), 256, 0, stream>>>(
            EH, LHg, LLg, AmixH, AmixL, XTh, XTl, W2h, W2l,
            xc, x0c, sa, cb,
            outf + (size_t)boff * N_ * D_, outg + (size_t)boff * N_ * D_);
    }
}

// Round 8
// 494.147 us; speedup vs baseline: 5.1591x; 1.2967x over previous
//
#include <hip/hip_runtime.h>
#include <math.h>

constexpr int B_ = 32;
constexpr int N_ = 1024;
constexpr int D_ = 64;
constexpr int BCH = 16;   // batch chunk; workspace ~211 MB (ws is ~268 MB)

typedef short short8 __attribute__((ext_vector_type(8)));   // 8 bf16 (4 VGPRs)
typedef float f32x4 __attribute__((ext_vector_type(4)));    // f32 MFMA accumulator
typedef int   int4_ __attribute__((ext_vector_type(4)));    // 16 i8 operand / i32x4 acc

__device__ __forceinline__ float sigf(float v) {
    return 1.0f / (1.0f + __expf(-v));
}
__device__ __forceinline__ unsigned short f2b(float f) {   // fp32 -> bf16 RNE
    unsigned u = __float_as_uint(f);
    unsigned r = u + 0x7fffu + ((u >> 16) & 1u);
    return (unsigned short)(r >> 16);
}
__device__ __forceinline__ float b2f(unsigned int h) {
    return __uint_as_float(h << 16);
}
__device__ __forceinline__ unsigned pack4(int a, int b, int c, int d) {
    return (unsigned)(a & 255) | ((unsigned)(b & 255) << 8) |
           ((unsigned)(c & 255) << 16) | ((unsigned)(d & 255) << 24);
}

#define GLD16(gp, lp)                                                        \
    __builtin_amdgcn_global_load_lds(                                        \
        (const __attribute__((address_space(1))) unsigned int*)(const void*)(gp), \
        (__attribute__((address_space(3))) unsigned int*)(void*)(lp), 16, 0, 0)

// ---------------------------------------------------------------- k_dots
__global__ void k_dots(const float* __restrict__ x,
                       const float* __restrict__ fw1, const float* __restrict__ fw2,
                       const float* __restrict__ gw1, const float* __restrict__ gw2,
                       const float* __restrict__ alpha,
                       float* __restrict__ e1f, float* __restrict__ e2f,
                       float* __restrict__ e1g, float* __restrict__ e2g,
                       float* __restrict__ sa)
{
    int t = blockIdx.x * blockDim.x + threadIdx.x;
    if (t < N_) sa[t] = sigf(alpha[t]);
    if (t >= B_ * N_) return;
    const float* xr = x + (size_t)t * D_;
    float s1 = 0.f, s2 = 0.f, s3 = 0.f, s4 = 0.f;
#pragma unroll 8
    for (int d = 0; d < D_; d++) {
        float v = xr[d];
        s1 += v * fw1[d];
        s2 += v * fw2[d];
        s3 += v * gw1[d];
        s4 += v * gw2[d];
    }
    e1f[t] = s1; e2f[t] = s2; e1g[t] = s3; e2g[t] = s4;
}

// ---------------------------------------------------------------- k_what2_split
__global__ void k_what2_split(const float* __restrict__ w, const float* __restrict__ dvec,
                              unsigned short* __restrict__ W2h, unsigned short* __restrict__ W2l)
{
    int t = blockIdx.x * blockDim.x + threadIdx.x;
    if (t >= D_ * D_) return;
    int i = t / D_, j = t % D_;
    float s = 0.f;
    for (int q = 0; q < D_; q++) {
        float dc = fminf(fmaxf(dvec[q], 0.0f), 1.0f);
        s += w[i * D_ + q] * dc * w[j * D_ + q];
    }
    if (i == j) s -= 2.0f;
    unsigned short h = f2b(s);
    W2h[t] = h;
    W2l[t] = f2b(s - b2f(h));
}

// ---------------------------------------------------------------- k_amix_split
__global__ void k_amix_split(const float* __restrict__ adj, const float* __restrict__ cw,
                             unsigned short* __restrict__ AmixH, unsigned short* __restrict__ AmixL)
{
    int t = blockIdx.x * blockDim.x + threadIdx.x;
    if (t >= N_ * N_) return;
    int i = t >> 10, j = t & (N_ - 1);
    float c0 = cw[0], c1 = cw[1];
    float v = c0 * adj[t] + c1 * adj[(size_t)N_ * N_ + t];
    if (i == j) v -= (c0 + c1);
    unsigned short h = f2b(v);
    AmixH[t] = h;
    AmixL[t] = f2b(v - b2f(h));
}

// ---------------------------------------------------------------- k_zinit / k_amax / k_aquant
__global__ void k_zinit(unsigned* __restrict__ amaxbits)
{
    if (threadIdx.x < 2) amaxbits[threadIdx.x] = 0;
}

__global__ void k_amax(const float* __restrict__ fvs, const float* __restrict__ gvs,
                       unsigned* __restrict__ amaxbits)
{
    int fg = blockIdx.y;
    const float* src = fg ? gvs : fvs;
    int t = threadIdx.x;
    size_t base = ((size_t)blockIdx.x * 256 + t) * 16;
    float m = 0.f;
#pragma unroll
    for (int q = 0; q < 4; q++) {
        float4 v = *(const float4*)(src + base + q * 4);
        m = fmaxf(m, fmaxf(fmaxf(fabsf(v.x), fabsf(v.y)), fmaxf(fabsf(v.z), fabsf(v.w))));
    }
#pragma unroll
    for (int o = 32; o > 0; o >>= 1) m = fmaxf(m, __shfl_xor(m, o, 64));
    __shared__ float red[4];
    if ((t & 63) == 0) red[t >> 6] = m;
    __syncthreads();
    if (t == 0) {
        m = fmaxf(fmaxf(red[0], red[1]), fmaxf(red[2], red[3]));
        atomicMax(&amaxbits[fg], __float_as_uint(m));
    }
}

__launch_bounds__(256)
__global__ void k_aquant(const float* __restrict__ fvs, const float* __restrict__ gvs,
                         const float* __restrict__ amaxf,
                         signed char* __restrict__ AHf, signed char* __restrict__ ALf,
                         signed char* __restrict__ AHg, signed char* __restrict__ ALg,
                         float* __restrict__ rsumf, float* __restrict__ rsumg)
{
    int row = blockIdx.x;
    int fg  = blockIdx.y;
    const float* src = fg ? gvs : fvs;
    signed char* hp = fg ? AHg : AHf;
    signed char* lp = fg ? ALg : ALf;
    float* rs = fg ? rsumg : rsumf;
    float inv = 32512.f / amaxf[fg];
    int t = threadIdx.x;
    int j = t * 4;
    float4 v = *(const float4*)(src + (size_t)row * N_ + j);
    float a[4] = {v.x, v.y, v.z, v.w};
    int qh[4], ql[4], s = 0;
#pragma unroll
    for (int e = 0; e < 4; e++) {
        int q = __float2int_rn(a[e] * inv);
        q = min(max(q, -32512), 32512);
        int h = (q + 128) >> 8;
        qh[e] = h;
        ql[e] = q - (h << 8);
        s += q;
    }
    *(unsigned*)(hp + (size_t)row * N_ + j) = pack4(qh[0], qh[1], qh[2], qh[3]);
    *(unsigned*)(lp + (size_t)row * N_ + j) = pack4(ql[0], ql[1], ql[2], ql[3]);
#pragma unroll
    for (int o = 32; o > 0; o >>= 1) s += __shfl_xor(s, o, 64);
    __shared__ int red[4];
    if ((t & 63) == 0) red[t >> 6] = s;
    __syncthreads();
    if (t == 0) rs[row] = (float)(red[0] + red[1] + red[2] + red[3]);
}

// ---------------------------------------------------------------- k_xt_split
__launch_bounds__(256)
__global__ void k_xt_split(const float* __restrict__ xc,
                           unsigned short* __restrict__ XTh, unsigned short* __restrict__ XTl)
{
    int j0 = blockIdx.x * 64;
    int bc = blockIdx.y;
    int t  = threadIdx.x;
    __shared__ float S_l[64][65];
    {
        int j = t >> 2, dc = (t & 3) * 16;
        const float* src = xc + ((size_t)bc * N_ + j0 + j) * D_ + dc;
#pragma unroll
        for (int q = 0; q < 4; q++) {
            float4 v = *(const float4*)(src + q * 4);
            S_l[j][dc + q * 4 + 0] = v.x;
            S_l[j][dc + q * 4 + 1] = v.y;
            S_l[j][dc + q * 4 + 2] = v.z;
            S_l[j][dc + q * 4 + 3] = v.w;
        }
    }
    __syncthreads();
    {
        int d = t >> 2, jc = (t & 3) * 16;
        unsigned short hs[16], ls[16];
#pragma unroll
        for (int u = 0; u < 16; u++) {
            float v = S_l[jc + u][d];
            hs[u] = f2b(v);
            ls[u] = f2b(v - b2f(hs[u]));
        }
        uint4 hv0, hv1, lv0, lv1;
        hv0.x = hs[0] | (hs[1] << 16);  hv0.y = hs[2] | (hs[3] << 16);
        hv0.z = hs[4] | (hs[5] << 16);  hv0.w = hs[6] | (hs[7] << 16);
        hv1.x = hs[8] | (hs[9] << 16);  hv1.y = hs[10] | (hs[11] << 16);
        hv1.z = hs[12] | (hs[13] << 16); hv1.w = hs[14] | (hs[15] << 16);
        lv0.x = ls[0] | (ls[1] << 16);  lv0.y = ls[2] | (ls[3] << 16);
        lv0.z = ls[4] | (ls[5] << 16);  lv0.w = ls[6] | (ls[7] << 16);
        lv1.x = ls[8] | (ls[9] << 16);  lv1.y = ls[10] | (ls[11] << 16);
        lv1.z = ls[12] | (ls[13] << 16); lv1.w = ls[14] | (ls[15] << 16);
        size_t base = ((size_t)bc * D_ + d) * N_ + j0 + jc;
        *(uint4*)(XTh + base) = hv0;  *(uint4*)(XTh + base + 8) = hv1;
        *(uint4*)(XTl + base) = lv0;  *(uint4*)(XTl + base + 8) = lv1;
    }
}

// ---------------------------------------------------------------- k_sigsplit2
__launch_bounds__(256)
__global__ void k_sigsplit2(const float* __restrict__ fbs, const float* __restrict__ gbs,
                            const float* __restrict__ e1f_, const float* __restrict__ e2f_,
                            const float* __restrict__ e1g_, const float* __restrict__ e2g_,
                            signed char* __restrict__ SHf, signed char* __restrict__ SLf,
                            signed char* __restrict__ SHg, signed char* __restrict__ SLg)
{
    int j0 = blockIdx.x * 64;
    int k0 = blockIdx.y * 64;
    int z  = blockIdx.z;
    int b  = z & (BCH - 1);
    int fg = z / BCH;
    const float* bs = fg ? gbs : fbs;
    const float* e1 = fg ? e1g_ : e1f_;
    const float* e2 = fg ? e2g_ : e2f_;
    signed char* SH = fg ? SHg : SHf;
    signed char* SL = fg ? SLg : SLf;
    int t  = threadIdx.x;
    __shared__ float S_l[64][65];
    {
        int j  = t >> 2;
        int kc = (t & 3) * 16;
        float e1v = e1[(size_t)b * N_ + j0 + j];
#pragma unroll
        for (int q = 0; q < 4; q++) {
            float4 bsv = *(const float4*)(bs + (size_t)(j0 + j) * N_ + k0 + kc + q * 4);
            float4 e2v = *(const float4*)(e2 + (size_t)b * N_ + k0 + kc + q * 4);
            S_l[j][kc + q * 4 + 0] = sigf(fmaf(e1v, e2v.x, bsv.x));
            S_l[j][kc + q * 4 + 1] = sigf(fmaf(e1v, e2v.y, bsv.y));
            S_l[j][kc + q * 4 + 2] = sigf(fmaf(e1v, e2v.z, bsv.z));
            S_l[j][kc + q * 4 + 3] = sigf(fmaf(e1v, e2v.w, bsv.w));
        }
    }
    __syncthreads();
    {
        int k  = t >> 2;
        int jc = (t & 3) * 16;
        int hh[16], ll[16];
#pragma unroll
        for (int u = 0; u < 16; u++) {
            float v = S_l[jc + u][k];
            int q = __float2int_rn(v * 65024.f) - 32512;
            q = min(max(q, -32512), 32512);
            int h = (q + 128) >> 8;
            hh[u] = h;
            ll[u] = q - (h << 8);
        }
        uint4 H, L;
        H.x = pack4(hh[0], hh[1], hh[2], hh[3]);   H.y = pack4(hh[4], hh[5], hh[6], hh[7]);
        H.z = pack4(hh[8], hh[9], hh[10], hh[11]); H.w = pack4(hh[12], hh[13], hh[14], hh[15]);
        L.x = pack4(ll[0], ll[1], ll[2], ll[3]);   L.y = pack4(ll[4], ll[5], ll[6], ll[7]);
        L.z = pack4(ll[8], ll[9], ll[10], ll[11]); L.w = pack4(ll[12], ll[13], ll[14], ll[15]);
        size_t base = (size_t)(b * N_ + k0 + k) * N_ + j0 + jc;
        *(uint4*)(SH + base) = H;
        *(uint4*)(SL + base) = L;
    }
}

// ---------------------------------------------------------------- k_gemm2i
// logit (fp32) = sA/65024 * (65536*M + 256*C + 32512*rsumA[i])
__launch_bounds__(256, 2)
__global__ void k_gemm2i(const signed char* __restrict__ AHf, const signed char* __restrict__ ALf,
                         const signed char* __restrict__ AHg, const signed char* __restrict__ ALg,
                         const signed char* __restrict__ SHf, const signed char* __restrict__ SLf,
                         const signed char* __restrict__ SHg, const signed char* __restrict__ SLg,
                         const float* __restrict__ rsumf, const float* __restrict__ rsumg,
                         const float* __restrict__ amaxf,
                         float* __restrict__ LF, float* __restrict__ LG)
{
    const int fg = blockIdx.z;
    const signed char* AH = fg ? AHg : AHf;
    const signed char* AL = fg ? ALg : ALf;
    const signed char* SH = fg ? SHg : SHf;
    const signed char* SL = fg ? SLg : SLf;
    const float* rsum = fg ? rsumg : rsumf;
    float* Lo = fg ? LG : LF;
    const float scale = amaxf[fg] * (1.0f / (32512.f * 65024.f));

    const int b  = blockIdx.y;
    const int i0 = (blockIdx.x >> 3) * 128;
    const int k0 = (blockIdx.x & 7) * 128;
    const int t    = threadIdx.x;
    const int lane = t & 63;
    const int wave = t >> 6;
    const int wr   = wave >> 1;
    const int wc   = wave & 1;
    const int quad = lane >> 4;
    const int m16  = lane & 15;

    __shared__ __align__(16) signed char lds[32768];
    signed char* AHl = lds;
    signed char* ALl = lds + 8192;
    signed char* BHl = lds + 16384;
    signed char* BLl = lds + 24576;

    const signed char* gsrc;
    signed char* ldst;
    int rowbase;
    if (wave == 0)      { gsrc = AH; ldst = AHl; rowbase = i0; }
    else if (wave == 1) { gsrc = AL; ldst = ALl; rowbase = i0; }
    else if (wave == 2) { gsrc = SH; ldst = BHl; rowbase = b * N_ + k0; }
    else                { gsrc = SL; ldst = BLl; rowbase = b * N_ + k0; }

    int4_ accm[4][4], accc[4][4];
#pragma unroll
    for (int mi = 0; mi < 4; mi++)
#pragma unroll
        for (int ni = 0; ni < 4; ni++) {
            accm[mi][ni] = (int4_){0, 0, 0, 0};
            accc[mi][ni] = (int4_){0, 0, 0, 0};
        }

    const int rr = lane >> 2;
    const int cc = lane & 3;
    const int gcq = cc ^ ((rr >> 1) & 3);
    const int rpos = (quad ^ ((m16 >> 1) & 3)) * 16;

    for (int step = 0; step < 16; step++) {
        const int jb = step * 64;
        __syncthreads();
#pragma unroll
        for (int it = 0; it < 8; it++) {
            int r = it * 16 + rr;
            const signed char* gp = gsrc + (size_t)(rowbase + r) * N_ + jb + gcq * 16;
            GLD16(gp, ldst + it * 1024);
        }
        __syncthreads();

        int4_ ah[4], al[4];
#pragma unroll
        for (int mi = 0; mi < 4; mi++) {
            int row = wr * 64 + mi * 16 + m16;
            ah[mi] = *(const int4_*)(AHl + row * 64 + rpos);
            al[mi] = *(const int4_*)(ALl + row * 64 + rpos);
        }
#pragma unroll
        for (int ni = 0; ni < 4; ni++) {
            int row = wc * 64 + ni * 16 + m16;
            int4_ bh = *(const int4_*)(BHl + row * 64 + rpos);
            int4_ bl = *(const int4_*)(BLl + row * 64 + rpos);
#pragma unroll
            for (int mi = 0; mi < 4; mi++) {
                accm[mi][ni] = __builtin_amdgcn_mfma_i32_16x16x64_i8(
                    ah[mi], bh, accm[mi][ni], 0, 0, 0);
                accc[mi][ni] = __builtin_amdgcn_mfma_i32_16x16x64_i8(
                    ah[mi], bl, accc[mi][ni], 0, 0, 0);
                accc[mi][ni] = __builtin_amdgcn_mfma_i32_16x16x64_i8(
                    al[mi], bh, accc[mi][ni], 0, 0, 0);
            }
        }
    }

#pragma unroll
    for (int mi = 0; mi < 4; mi++)
#pragma unroll
        for (int ni = 0; ni < 4; ni++) {
            int row = i0 + wr * 64 + mi * 16 + quad * 4;
            int col = k0 + wc * 64 + ni * 16 + m16;
            size_t base = ((size_t)b * N_ + row) * N_ + col;
#pragma unroll
            for (int r = 0; r < 4; r++) {
                float v = (65536.f * (float)accm[mi][ni][r] +
                           256.f * (float)accc[mi][ni][r] +
                           32512.f * rsum[row + r]) * scale;
                Lo[base + (size_t)r * N_] = v;
            }
        }
}

// ---------------------------------------------------------------- k_fused
// Per block: 32-row strip, both outputs.
// Pre-pass: rowwise sum of exp (no max-subtract: |logit| <= sum|vs| ~ 25).
// K-loop: E = exp(Lf)*invf (bf16), Nhat = exp(Lg)*invg/(E+1e-5) (bf16 hi/lo),
// staged to LDS + MFMA:  f += E@x + Amix@x (+ x@What2 in phase B); g = Nhat@x.
__launch_bounds__(256, 2)
__global__ void k_fused(const float* __restrict__ LF, const float* __restrict__ LG,
                        const unsigned short* __restrict__ AmixH, const unsigned short* __restrict__ AmixL,
                        const unsigned short* __restrict__ XTh, const unsigned short* __restrict__ XTl,
                        const unsigned short* __restrict__ W2h, const unsigned short* __restrict__ W2l,
                        const float* __restrict__ xc, const float* __restrict__ x0c,
                        const float* __restrict__ sa, const float* __restrict__ cb,
                        float* __restrict__ outf, float* __restrict__ outg)
{
    const int i0 = blockIdx.x * 32;
    const int bc = blockIdx.y;
    const int t    = threadIdx.x;
    const int lane = t & 63;
    const int wave = t >> 6;
    const int quad = lane >> 4;
    const int m16  = lane & 15;
    const int l7   = lane & 7;
    const int r_sub = lane >> 3;
    const int gc    = l7 ^ r_sub;

    __shared__ __align__(16) unsigned short lds[18432];   // 36 KB
    unsigned short* E_l  = lds;            // 32x64
    unsigned short* Nh_l = lds + 2048;
    unsigned short* Nl_l = lds + 4096;
    unsigned short* Xh_l = lds + 6144;     // 64x64
    unsigned short* Xl_l = lds + 10240;
    unsigned short* Ah_l = lds + 14336;    // 32x64
    unsigned short* Al_l = lds + 16384;
    __shared__ float invf_l[32], invg_l[32];

    // ---- pre-pass: row sums of exp over all 1024 columns ----
    {
        int r  = t >> 3;
        int c0 = (t & 7) * 4;
        const float* lf = LF + ((size_t)bc * N_ + i0 + r) * N_;
        const float* lg = LG + ((size_t)bc * N_ + i0 + r) * N_;
        float sf = 0.f, sg = 0.f;
        for (int k = 0; k < 32; k++) {
            float4 a = *(const float4*)(lf + c0 + k * 32);
            float4 b = *(const float4*)(lg + c0 + k * 32);
            sf += __expf(a.x) + __expf(a.y) + __expf(a.z) + __expf(a.w);
            sg += __expf(b.x) + __expf(b.y) + __expf(b.z) + __expf(b.w);
        }
        sf += __shfl_xor(sf, 1, 64); sf += __shfl_xor(sf, 2, 64); sf += __shfl_xor(sf, 4, 64);
        sg += __shfl_xor(sg, 1, 64); sg += __shfl_xor(sg, 2, 64); sg += __shfl_xor(sg, 4, 64);
        if ((t & 7) == 0) { invf_l[r] = 1.f / sf; invg_l[r] = 1.f / sg; }
    }
    __syncthreads();

    f32x4 accf[2], accg[2];
#pragma unroll
    for (int u = 0; u < 2; u++) {
        accf[u] = (f32x4){0.f, 0.f, 0.f, 0.f};
        accg[u] = (f32x4){0.f, 0.f, 0.f, 0.f};
    }
    const int rowA = (wave & 1) * 16 + m16;   // 0..31
    const int cg0  = (wave >> 1) * 2;         // 0 or 2

    for (int step = 0; step < 16; step++) {
        const int jb = step * 64;
        __syncthreads();
        // GLD16: XTh(8) XTl(8) AmH(4) AmL(4) = 24 issues, 6 per wave
        for (int i = 0; i < 6; i++) {
            int gi = wave * 6 + i;
            const unsigned short* gp;
            unsigned short* lp;
            if (gi < 8) {
                gp = XTh + ((size_t)bc * D_ + gi * 8 + r_sub) * N_ + jb + gc * 8;
                lp = Xh_l + gi * 512;
            } else if (gi < 16) {
                int g2 = gi - 8;
                gp = XTl + ((size_t)bc * D_ + g2 * 8 + r_sub) * N_ + jb + gc * 8;
                lp = Xl_l + g2 * 512;
            } else if (gi < 20) {
                int g2 = gi - 16;
                gp = AmixH + (size_t)(i0 + g2 * 8 + r_sub) * N_ + jb + gc * 8;
                lp = Ah_l + g2 * 512;
            } else {
                int g2 = gi - 20;
                gp = AmixL + (size_t)(i0 + g2 * 8 + r_sub) * N_ + jb + gc * 8;
                lp = Al_l + g2 * 512;
            }
            GLD16(gp, lp);
        }
        // VALU staging: E / Nhat tiles
        {
            int r  = t >> 3;
            int jc = (t & 7) * 8;
            const float* lf = LF + ((size_t)bc * N_ + i0 + r) * N_ + jb + jc;
            const float* lg = LG + ((size_t)bc * N_ + i0 + r) * N_ + jb + jc;
            float4 f0 = *(const float4*)lf;
            float4 f1 = *(const float4*)(lf + 4);
            float4 g0 = *(const float4*)lg;
            float4 g1 = *(const float4*)(lg + 4);
            float fa[8] = {f0.x, f0.y, f0.z, f0.w, f1.x, f1.y, f1.z, f1.w};
            float ga[8] = {g0.x, g0.y, g0.z, g0.w, g1.x, g1.y, g1.z, g1.w};
            float fi = invf_l[r], gi2 = invg_l[r];
            short8 ev, nhv, nlv;
#pragma unroll
            for (int e = 0; e < 8; e++) {
                float E = __expf(fa[e]) * fi;
                float nh = __expf(ga[e]) * gi2 / (E + 1e-5f);
                ev[e] = (short)f2b(E);
                unsigned short h = f2b(nh);
                nhv[e] = (short)h;
                nlv[e] = (short)f2b(nh - b2f(h));
            }
            int pos = (((jc >> 3) ^ (r & 7))) * 8;
            *(short8*)(E_l  + r * 64 + pos) = ev;
            *(short8*)(Nh_l + r * 64 + pos) = nhv;
            *(short8*)(Nl_l + r * 64 + pos) = nlv;
        }
        __syncthreads();
#pragma unroll
        for (int kc = 0; kc < 2; kc++) {
            const int ch = ((kc * 4 + quad) ^ l7) * 8;
            short8 e  = *(const short8*)(E_l  + rowA * 64 + ch);
            short8 ah = *(const short8*)(Ah_l + rowA * 64 + ch);
            short8 al = *(const short8*)(Al_l + rowA * 64 + ch);
            short8 nh = *(const short8*)(Nh_l + rowA * 64 + ch);
            short8 nl = *(const short8*)(Nl_l + rowA * 64 + ch);
#pragma unroll
            for (int u = 0; u < 2; u++) {
                int rowB = (cg0 + u) * 16 + m16;
                short8 bh = *(const short8*)(Xh_l + rowB * 64 + ch);
                short8 bl = *(const short8*)(Xl_l + rowB * 64 + ch);
                accf[u] = __builtin_amdgcn_mfma_f32_16x16x32_bf16(e,  bh, accf[u], 0, 0, 0);
                accf[u] = __builtin_amdgcn_mfma_f32_16x16x32_bf16(e,  bl, accf[u], 0, 0, 0);
                accf[u] = __builtin_amdgcn_mfma_f32_16x16x32_bf16(ah, bh, accf[u], 0, 0, 0);
                accf[u] = __builtin_amdgcn_mfma_f32_16x16x32_bf16(ah, bl, accf[u], 0, 0, 0);
                accf[u] = __builtin_amdgcn_mfma_f32_16x16x32_bf16(al, bh, accf[u], 0, 0, 0);
                accg[u] = __builtin_amdgcn_mfma_f32_16x16x32_bf16(nh, bh, accg[u], 0, 0, 0);
                accg[u] = __builtin_amdgcn_mfma_f32_16x16x32_bf16(nh, bl, accg[u], 0, 0, 0);
                accg[u] = __builtin_amdgcn_mfma_f32_16x16x32_bf16(nl, bh, accg[u], 0, 0, 0);
            }
        }
    }

    // ---- phase B: f += x_rows @ What2 (one K=64 step; What2 symmetric) ----
    __syncthreads();
    {
        for (int i = 0; i < 4; i++) {
            int gi = wave * 4 + i;
            const unsigned short* gsrc2 = (gi < 8) ? W2h : W2l;
            int g2 = gi & 7;
            unsigned short* lp = ((gi < 8) ? Xh_l : Xl_l) + g2 * 512;
            GLD16(gsrc2 + (size_t)(g2 * 8 + r_sub) * 64 + gc * 8, lp);
        }
        int r  = t >> 3;
        int dc = (t & 7) * 8;
        const float* xrow = xc + ((size_t)bc * N_ + i0 + r) * D_ + dc;
        float4 v0 = *(const float4*)xrow;
        float4 v1 = *(const float4*)(xrow + 4);
        float vv[8] = {v0.x, v0.y, v0.z, v0.w, v1.x, v1.y, v1.z, v1.w};
        short8 hh, ll;
#pragma unroll
        for (int e = 0; e < 8; e++) {
            unsigned short h = f2b(vv[e]);
            hh[e] = (short)h;
            ll[e] = (short)f2b(vv[e] - b2f(h));
        }
        int pos = (((dc >> 3) ^ (r & 7))) * 8;
        *(short8*)(E_l  + r * 64 + pos) = hh;
        *(short8*)(Nh_l + r * 64 + pos) = ll;
    }
    __syncthreads();
#pragma unroll
    for (int kc = 0; kc < 2; kc++) {
        const int ch = ((kc * 4 + quad) ^ l7) * 8;
        short8 xh = *(const short8*)(E_l  + rowA * 64 + ch);
        short8 xl = *(const short8*)(Nh_l + rowA * 64 + ch);
#pragma unroll
        for (int u = 0; u < 2; u++) {
            int rowB = (cg0 + u) * 16 + m16;
            short8 bh = *(const short8*)(Xh_l + rowB * 64 + ch);
            short8 bl = *(const short8*)(Xl_l + rowB * 64 + ch);
            accf[u] = __builtin_amdgcn_mfma_f32_16x16x32_bf16(xh, bh, accf[u], 0, 0, 0);
            accf[u] = __builtin_amdgcn_mfma_f32_16x16x32_bf16(xh, bl, accf[u], 0, 0, 0);
            accf[u] = __builtin_amdgcn_mfma_f32_16x16x32_bf16(xl, bh, accf[u], 0, 0, 0);
        }
    }

    float cbv = cb[0];
#pragma unroll
    for (int u = 0; u < 2; u++) {
#pragma unroll
        for (int r = 0; r < 4; r++) {
            int row = i0 + (wave & 1) * 16 + quad * 4 + r;
            int col = (cg0 + u) * 16 + m16;
            size_t o = ((size_t)bc * N_ + row) * D_ + col;
            outf[o] = tanhf(accf[u][r] + x0c[o] * sa[row] + cbv);
            outg[o] = tanhf(accg[u][r]);
        }
    }
}

// ---------------------------------------------------------------- host
extern "C" void kernel_launch(void* const* d_in, const int* in_sizes, int n_in,
                              void* d_out, int out_size, void* d_ws, size_t ws_size,
                              hipStream_t stream)
{
    const float* x     = (const float*)d_in[0];
    const float* x0    = (const float*)d_in[1];
    const float* w     = (const float*)d_in[2];
    const float* dvec  = (const float*)d_in[3];
    const float* alpha = (const float*)d_in[4];
    const float* fw1   = (const float*)d_in[5];
    const float* fw2   = (const float*)d_in[6];
    const float* fvs   = (const float*)d_in[7];
    const float* fbs   = (const float*)d_in[8];
    const float* gw1   = (const float*)d_in[9];
    const float* gw2   = (const float*)d_in[10];
    const float* gvs   = (const float*)d_in[11];
    const float* gbs   = (const float*)d_in[12];
    const float* cw    = (const float*)d_in[13];
    const float* cb    = (const float*)d_in[14];
    const float* adj   = (const float*)d_in[15];

    float* outf = (float*)d_out;
    float* outg = outf + (size_t)B_ * N_ * D_;

    char* p = (char*)d_ws;
    auto alloc = [&](size_t bytes) { void* r = p; p += (bytes + 255) & ~(size_t)255; return r; };

    float* e1f = (float*)alloc(B_ * N_ * 4);
    float* e2f = (float*)alloc(B_ * N_ * 4);
    float* e1g = (float*)alloc(B_ * N_ * 4);
    float* e2g = (float*)alloc(B_ * N_ * 4);
    float* sa  = (float*)alloc(N_ * 4);
    unsigned short* W2h = (unsigned short*)alloc(D_ * D_ * 2);
    unsigned short* W2l = (unsigned short*)alloc(D_ * D_ * 2);
    float* amaxf = (float*)alloc(2 * 4);
    float* rsumf = (float*)alloc(N_ * 4);
    float* rsumg = (float*)alloc(N_ * 4);
    unsigned short* AmixH = (unsigned short*)alloc((size_t)N_ * N_ * 2);
    unsigned short* AmixL = (unsigned short*)alloc((size_t)N_ * N_ * 2);
    signed char* AHf = (signed char*)alloc((size_t)N_ * N_);
    signed char* ALf = (signed char*)alloc((size_t)N_ * N_);
    signed char* AHg = (signed char*)alloc((size_t)N_ * N_);
    signed char* ALg = (signed char*)alloc((size_t)N_ * N_);
    unsigned short* XTh = (unsigned short*)alloc((size_t)BCH * D_ * N_ * 2);
    unsigned short* XTl = (unsigned short*)alloc((size_t)BCH * D_ * N_ * 2);
    signed char* SHf = (signed char*)alloc((size_t)BCH * N_ * N_);
    signed char* SLf = (signed char*)alloc((size_t)BCH * N_ * N_);
    signed char* SHg = (signed char*)alloc((size_t)BCH * N_ * N_);
    signed char* SLg = (signed char*)alloc((size_t)BCH * N_ * N_);
    float* LF = (float*)alloc((size_t)BCH * N_ * N_ * 4);
    float* LG = (float*)alloc((size_t)BCH * N_ * N_ * 4);
    (void)ws_size; (void)in_sizes; (void)n_in; (void)out_size;

    k_zinit<<<dim3(1), 64, 0, stream>>>((unsigned*)amaxf);
    k_amax<<<dim3(256, 2), 256, 0, stream>>>(fvs, gvs, (unsigned*)amaxf);
    k_aquant<<<dim3(1024, 2), 256, 0, stream>>>(fvs, gvs, amaxf,
                                                AHf, ALf, AHg, ALg, rsumf, rsumg);
    k_dots<<<dim3((B_ * N_) / 256), 256, 0, stream>>>(x, fw1, fw2, gw1, gw2, alpha,
                                                      e1f, e2f, e1g, e2g, sa);
    k_what2_split<<<dim3(16), 256, 0, stream>>>(w, dvec, W2h, W2l);
    k_amix_split<<<dim3(N_ * N_ / 256), 256, 0, stream>>>(adj, cw, AmixH, AmixL);

    for (int c = 0; c < B_ / BCH; c++) {
        int boff = c * BCH;
        const float* xc  = x  + (size_t)boff * N_ * D_;
        const float* x0c = x0 + (size_t)boff * N_ * D_;
        k_xt_split<<<dim3(16, BCH), 256, 0, stream>>>(xc, XTh, XTl);
        k_sigsplit2<<<dim3(16, 16, BCH * 2), 256, 0, stream>>>(
            fbs, gbs, e1f + boff * N_, e2f + boff * N_,
            e1g + boff * N_, e2g + boff * N_, SHf, SLf, SHg, SLg);
        k_gemm2i<<<dim3(64, BCH, 2), 256, 0, stream>>>(
            AHf, ALf, AHg, ALg, SHf, SLf, SHg, SLg, rsumf, rsumg, amaxf, LF, LG);
        k_fused<<<dim3(32, BCH), 256, 0, stream>>>(
            LF, LG, AmixH, AmixL, XTh, XTl, W2h, W2l,
            xc, x0c, sa, cb,
            outf + (size_t)boff * N_ * D_, outg + (size_t)boff * N_ * D_);
    }
}